// Round 1
// baseline (2364.360 us; speedup 1.0000x reference)
//
#include <hip/hip_runtime.h>
#include <cstdint>
#include <cstddef>

#define Bq  16
#define Sq  512
#define Dq  768
#define Hq  12
#define DHq 64
#define Fq  3072
#define SWq 128
#define NTq 8192

typedef float        f32x4  __attribute__((ext_vector_type(4)));
typedef unsigned int u32x4  __attribute__((ext_vector_type(4)));
typedef __bf16       bf16x8 __attribute__((ext_vector_type(8)));

__device__ __forceinline__ unsigned short f2bf(float f){
  unsigned int u = __builtin_bit_cast(unsigned int, f);
  u = (u + 0x7fffu + ((u >> 16) & 1u)) >> 16;
  return (unsigned short)u;
}
__device__ __forceinline__ unsigned int pk2(float a, float b){
  return (unsigned int)f2bf(a) | ((unsigned int)f2bf(b) << 16);
}

// ---------------- pooled partial sums (seq router input) ----------------
__global__ void pooled_partial_k(const float* __restrict__ x, float* __restrict__ part){
  const int b = blockIdx.x, dc = blockIdx.y, z = blockIdx.z;
  const int d = dc*256 + threadIdx.x;
  const float* p = x + (size_t)b*Sq*Dq + (size_t)z*128*Dq + d;
  float s = 0.f;
  #pragma unroll 4
  for (int i = 0; i < 128; i++) s += p[(size_t)i*Dq];
  part[((size_t)z*Bq + b)*Dq + d] = s;
}

// ---------------- sequence-level router (exact f32) ----------------
__global__ void router_seq_k(const float* __restrict__ part,
    const float* __restrict__ ew, const float* __restrict__ eb,
    const float* __restrict__ sw, const float* __restrict__ sb,
    int* __restrict__ sel, float* __restrict__ pm)
{
  const int b = blockIdx.x, j = threadIdx.x;   // 128 threads
  __shared__ float h[SWq];
  __shared__ float pl[Dq];
  #pragma unroll
  for (int i = 0; i < 6; i++){
    int d = j + i*128;
    float s = part[(size_t)(0*Bq+b)*Dq + d] + part[(size_t)(1*Bq+b)*Dq + d]
            + part[(size_t)(2*Bq+b)*Dq + d] + part[(size_t)(3*Bq+b)*Dq + d];
    pl[d] = s * (1.0f/512.0f);
  }
  __syncthreads();
  float a = eb[j];
  for (int d = 0; d < Dq; d++) a += pl[d] * ew[d*SWq + j];
  h[j] = a;
  __syncthreads();
  if (j == 0){
    float lg[4];
    for (int e = 0; e < 4; e++){
      float t = sb[e];
      for (int k = 0; k < SWq; k++) t += h[k] * sw[k*4 + e];
      lg[e] = t;
    }
    float mx = fmaxf(fmaxf(lg[0],lg[1]), fmaxf(lg[2],lg[3]));
    float p[4], ssum = 0.f;
    for (int e = 0; e < 4; e++){ p[e] = expf(lg[e]-mx); ssum += p[e]; }
    int am = 0; float bv = p[0];
    for (int e = 1; e < 4; e++) if (p[e] > bv){ bv = p[e]; am = e; }
    sel[b] = am; pm[b] = bv/ssum;
  }
}

// ---------------- f32 VALU GEMM: C = A@B + bias  (attention path, exact) ----
// BMODE: 0 shared B; 1 per-sequence expert B (sel).  OMODE: 0 write; 1 C += pm*(res)
template<int BMODE, int OMODE>
__global__ __launch_bounds__(256,4) void gemm_f32_k(
    const float* __restrict__ A, const float* __restrict__ Bw,
    const float* __restrict__ bias, float* __restrict__ C,
    int M, int N, int K, const int* __restrict__ sel, const float* __restrict__ pm)
{
  __shared__ float AsT[8][132];
  __shared__ float Bs [8][132];
  const int tid = threadIdx.x;
  const int tx = tid & 15, ty = tid >> 4;
  const int row0 = blockIdx.y * 128, col0 = blockIdx.x * 128;
  const float* Bp = Bw; const float* bp = bias;
  if constexpr (BMODE == 1){
    const int e = sel[row0 >> 9];
    Bp += (size_t)e * K * N;
    bp += (size_t)e * N;
  }
  float cs = 1.0f;
  if constexpr (OMODE == 1) cs = pm[row0 >> 9];

  float acc[2][2][4][4];
  #pragma unroll
  for (int p=0;p<2;p++)
    #pragma unroll
    for (int q=0;q<2;q++)
      #pragma unroll
      for (int i=0;i<4;i++)
        #pragma unroll
        for (int j=0;j<4;j++) acc[p][q][i][j] = 0.f;

  const int ar = tid >> 3;         // 0..31
  const int ak = tid & 7;
  const int bk = tid >> 5;         // 0..7
  const int bn = (tid & 31) * 4;
  const float* Aptr = A + (size_t)(row0 + ar) * K + ak;
  const float* Bptr = Bp + (size_t)bk * N + col0 + bn;

  for (int k0 = 0; k0 < K; k0 += 8){
    float av[4];
    #pragma unroll
    for (int i = 0; i < 4; i++) av[i] = Aptr[(size_t)(32*i)*K + k0];
    f32x4 bv = *(const f32x4*)(Bptr + (size_t)k0 * N);
    __syncthreads();
    #pragma unroll
    for (int i = 0; i < 4; i++) AsT[ak][ar + 32*i] = av[i];
    *(f32x4*)&Bs[bk][bn] = bv;
    __syncthreads();
    #pragma unroll
    for (int kk = 0; kk < 8; kk++){
      f32x4 a0 = *(const f32x4*)&AsT[kk][ty*4];
      f32x4 a1 = *(const f32x4*)&AsT[kk][64 + ty*4];
      f32x4 b0 = *(const f32x4*)&Bs [kk][tx*4];
      f32x4 b1 = *(const f32x4*)&Bs [kk][64 + tx*4];
      float aa[8], bb[8];
      #pragma unroll
      for (int i=0;i<4;i++){ aa[i]=a0[i]; aa[4+i]=a1[i]; bb[i]=b0[i]; bb[4+i]=b1[i]; }
      #pragma unroll
      for (int i = 0; i < 8; i++)
        #pragma unroll
        for (int j = 0; j < 8; j++)
          acc[i>>2][j>>2][i&3][j&3] += aa[i]*bb[j];
    }
  }
  #pragma unroll
  for (int p=0;p<2;p++)
    #pragma unroll
    for (int q=0;q<2;q++){
      const int cb = col0 + q*64 + tx*4;
      f32x4 bv = *(const f32x4*)(bp + cb);
      #pragma unroll
      for (int i=0;i<4;i++){
        const int r = row0 + p*64 + ty*4 + i;
        float* cp = C + (size_t)r*N + cb;
        f32x4 o;
        #pragma unroll
        for (int j=0;j<4;j++) o[j] = acc[p][q][i][j] + bv[j];
        if constexpr (OMODE == 0){
          *(f32x4*)cp = o;
        } else {
          f32x4 old = *(const f32x4*)cp;
          #pragma unroll
          for (int j=0;j<4;j++) old[j] += cs*o[j];
          *(f32x4*)cp = old;
        }
      }
    }
}

// ---------------- f32 attention (exact; no-max-sub softmax, scores are O(1)) ----
__global__ __launch_bounds__(256,2) void attn_f32_k(
    const float* __restrict__ Qp, const float* __restrict__ Kp, const float* __restrict__ Vp,
    const float* __restrict__ mask, float* __restrict__ ctx)
{
  __shared__ float QsT[64][72];
  __shared__ float KsT[64][72];
  __shared__ float Vs [64][68];
  __shared__ float PsT[64][64];   // xor-swizzled rows
  const int qt = blockIdx.x, h = blockIdx.y, b = blockIdx.z;
  const int tid = threadIdx.x;
  const int tx = tid & 15, ty = tid >> 4;
  const int sr = tid >> 2, sc = (tid & 3) * 16;
  {
    const float* qp = Qp + (size_t)(b*Sq + qt*64 + sr)*Dq + h*DHq + sc;
    #pragma unroll
    for (int c = 0; c < 16; c += 4){
      f32x4 v = *(const f32x4*)(qp + c);
      QsT[sc+c  ][sr] = v[0]; QsT[sc+c+1][sr] = v[1];
      QsT[sc+c+2][sr] = v[2]; QsT[sc+c+3][sr] = v[3];
    }
  }
  float accp[4][4];
  float rs[4];
  #pragma unroll
  for (int i=0;i<4;i++){ rs[i]=0.f; for (int j=0;j<4;j++) accp[i][j]=0.f; }
  const float* mrow = mask + b*Sq;

  for (int kt = 0; kt < 8; kt++){
    __syncthreads();
    {
      const float* kp = Kp + (size_t)(b*Sq + kt*64 + sr)*Dq + h*DHq + sc;
      const float* vp = Vp + (size_t)(b*Sq + kt*64 + sr)*Dq + h*DHq + sc;
      #pragma unroll
      for (int c = 0; c < 16; c += 4){
        f32x4 v = *(const f32x4*)(kp + c);
        KsT[sc+c  ][sr] = v[0]; KsT[sc+c+1][sr] = v[1];
        KsT[sc+c+2][sr] = v[2]; KsT[sc+c+3][sr] = v[3];
      }
      #pragma unroll
      for (int c = 0; c < 16; c += 4){
        f32x4 v = *(const f32x4*)(vp + c);
        *(f32x4*)&Vs[sr][sc+c] = v;
      }
    }
    __syncthreads();
    float s[4][4];
    #pragma unroll
    for (int i=0;i<4;i++) for (int j=0;j<4;j++) s[i][j]=0.f;
    #pragma unroll 8
    for (int d = 0; d < 64; d++){
      f32x4 a = *(const f32x4*)&QsT[d][ty*4];
      f32x4 k = *(const f32x4*)&KsT[d][tx*4];
      #pragma unroll
      for (int i=0;i<4;i++)
        #pragma unroll
        for (int j=0;j<4;j++) s[i][j] += a[i]*k[j];
    }
    f32x4 mk = *(const f32x4*)(mrow + kt*64 + tx*4);
    float pr[4][4], rp[4];
    #pragma unroll
    for (int i=0;i<4;i++){
      rp[i]=0.f;
      #pragma unroll
      for (int j=0;j<4;j++){
        float p = __expf(s[i][j]*0.125f + mk[j]);
        pr[i][j]=p; rp[i]+=p;
      }
    }
    #pragma unroll
    for (int off=1; off<16; off<<=1)
      #pragma unroll
      for (int i=0;i<4;i++) rp[i] += __shfl_xor(rp[i], off);
    #pragma unroll
    for (int i=0;i<4;i++) rs[i] += rp[i];
    #pragma unroll
    for (int i=0;i<4;i++)
      #pragma unroll
      for (int j=0;j<4;j++){
        const int k = tx*4 + j;
        unsigned int off = (unsigned int)(k*256 + (ty*4+i)*4) ^ ((k&7)<<4);
        *(float*)((char*)PsT + off) = pr[i][j];
      }
    __syncthreads();
    #pragma unroll 8
    for (int k = 0; k < 64; k++){
      unsigned int off = (unsigned int)(k*256 + ty*16) ^ ((k&7)<<4);
      f32x4 a = *(const f32x4*)((const char*)PsT + off);
      f32x4 v = *(const f32x4*)&Vs[k][tx*4];
      #pragma unroll
      for (int i=0;i<4;i++)
        #pragma unroll
        for (int j=0;j<4;j++) accp[i][j] += a[i]*v[j];
    }
  }
  #pragma unroll
  for (int i=0;i<4;i++){
    const float inv = 1.0f/rs[i];
    f32x4 o;
    #pragma unroll
    for (int j=0;j<4;j++) o[j] = accp[i][j]*inv;
    *(f32x4*)(ctx + (size_t)(b*Sq + qt*64 + ty*4 + i)*Dq + h*DHq + tx*4) = o;
  }
}

// ---------------- transpose + f32->bf16 (weights -> [N][K] bf16) ----------------
__global__ void transpose_bf16_k(const float* __restrict__ src, unsigned short* __restrict__ dst,
                                 int K, int N)
{
  __shared__ float t[64][65];
  const int tid = threadIdx.x;
  const size_t mo = (size_t)blockIdx.z * K * N;
  const int k0 = blockIdx.y * 64, n0 = blockIdx.x * 64;
  const int r = tid >> 2, c0 = (tid & 3) * 16;
  const float* sp = src + mo + (size_t)(k0 + r) * N + n0 + c0;
  #pragma unroll
  for (int cc = 0; cc < 16; cc += 4){
    f32x4 v = *(const f32x4*)(sp + cc);
    t[r][c0+cc] = v[0]; t[r][c0+cc+1] = v[1]; t[r][c0+cc+2] = v[2]; t[r][c0+cc+3] = v[3];
  }
  __syncthreads();
  unsigned short* dp = dst + mo + (size_t)(n0 + r) * K + k0 + c0;
  u32x4 h0, h1v;
  #pragma unroll
  for (int i = 0; i < 4; i++) h0[i]  = pk2(t[c0+2*i  ][r], t[c0+2*i+1][r]);
  #pragma unroll
  for (int i = 0; i < 4; i++) h1v[i] = pk2(t[c0+8+2*i][r], t[c0+9+2*i][r]);
  *(u32x4*)(dp)     = h0;
  *(u32x4*)(dp + 8) = h1v;
}

// ---------------- bf16 MFMA GEMM (FFN path) ----------------
// AMODE: 0 f32 rows; 1 f32 rows via tok_idx; 2 bf16 rows
// OMODE: 0 bf16 store (h1); 1 f32 write+bias; 2 f32 scatter add gate*(res+bias)
template<int AMODE, int OMODE, bool GELU_, bool GROUPED>
__global__ __launch_bounds__(256,2) void gemm_bf16_k(
    const void* __restrict__ Av, const unsigned short* __restrict__ BT,
    const float* __restrict__ bias, float* __restrict__ Cf, unsigned short* __restrict__ Cb,
    int M, int N, int K,
    const int* __restrict__ tile_g, const int* __restrict__ tile_r0,
    const int* __restrict__ grp_off, const int* __restrict__ n_tiles,
    const int* __restrict__ tok_idx, const float* __restrict__ gate_s,
    size_t bstride, int bias_stride)
{
  __shared__ unsigned short As[128][32];
  __shared__ unsigned short Bs[128][32];
  const int tid = threadIdx.x;
  const int lane = tid & 63, wave = tid >> 6;
  const int wm = wave >> 1, wn = wave & 1;
  const int col0 = blockIdx.x * 128;
  int row0, gend = 1 << 30, g = 0;
  if constexpr (GROUPED){
    const int t = blockIdx.y;
    if (t >= *n_tiles) return;
    g = tile_g[t];
    row0 = grp_off[g] + tile_r0[t];
    gend = grp_off[g+1];
  } else {
    row0 = blockIdx.y * 128;
  }
  const unsigned short* Bp = BT + (size_t)g * bstride;
  const float* bp = bias + (size_t)g * bias_stride;

  const int sr = tid >> 1;
  const int sk = (tid & 1) * 16;
  int arow = row0 + sr;
  if constexpr (GROUPED) arow = (arow < gend - 1) ? arow : (gend - 1);
  if constexpr (AMODE == 1) arow = tok_idx[arow];
  const float*          afp = (const float*)Av          + (size_t)arow * K + sk;
  const unsigned short* abp = (const unsigned short*)Av + (size_t)arow * K + sk;
  const unsigned short* bfp = Bp + (size_t)(col0 + sr) * K + sk;

  f32x4 acc[4][4];
  #pragma unroll
  for (int mi=0;mi<4;mi++)
    #pragma unroll
    for (int ni=0;ni<4;ni++) acc[mi][ni] = (f32x4){0.f,0.f,0.f,0.f};

  for (int k0 = 0; k0 < K; k0 += 32){
    u32x4 bl0 = *(const u32x4*)(bfp + k0);
    u32x4 bl1 = *(const u32x4*)(bfp + k0 + 8);
    u32x4 al0, al1;
    if constexpr (AMODE == 2){
      al0 = *(const u32x4*)(abp + k0);
      al1 = *(const u32x4*)(abp + k0 + 8);
    } else {
      f32x4 f0 = *(const f32x4*)(afp + k0);
      f32x4 f1 = *(const f32x4*)(afp + k0 + 4);
      f32x4 f2 = *(const f32x4*)(afp + k0 + 8);
      f32x4 f3 = *(const f32x4*)(afp + k0 + 12);
      al0[0]=pk2(f0[0],f0[1]); al0[1]=pk2(f0[2],f0[3]); al0[2]=pk2(f1[0],f1[1]); al0[3]=pk2(f1[2],f1[3]);
      al1[0]=pk2(f2[0],f2[1]); al1[1]=pk2(f2[2],f2[3]); al1[2]=pk2(f3[0],f3[1]); al1[3]=pk2(f3[2],f3[3]);
    }
    __syncthreads();
    *(u32x4*)&As[sr][sk]     = al0;
    *(u32x4*)&As[sr][sk + 8] = al1;
    *(u32x4*)&Bs[sr][sk]     = bl0;
    *(u32x4*)&Bs[sr][sk + 8] = bl1;
    __syncthreads();
    bf16x8 af[4], bfr[4];
    #pragma unroll
    for (int mi=0;mi<4;mi++){
      u32x4 t = *(const u32x4*)&As[wm*64 + mi*16 + (lane&15)][8*(lane>>4)];
      af[mi] = __builtin_bit_cast(bf16x8, t);
    }
    #pragma unroll
    for (int ni=0;ni<4;ni++){
      u32x4 t = *(const u32x4*)&Bs[wn*64 + ni*16 + (lane&15)][8*(lane>>4)];
      bfr[ni] = __builtin_bit_cast(bf16x8, t);
    }
    #pragma unroll
    for (int mi=0;mi<4;mi++)
      #pragma unroll
      for (int ni=0;ni<4;ni++)
        acc[mi][ni] = __builtin_amdgcn_mfma_f32_16x16x32_bf16(af[mi], bfr[ni], acc[mi][ni], 0, 0, 0);
  }

  const int erow = 4*(lane >> 4);
  const int ecol = lane & 15;
  #pragma unroll
  for (int mi=0;mi<4;mi++)
    #pragma unroll
    for (int ni=0;ni<4;ni++){
      const int c = col0 + wn*64 + ni*16 + ecol;
      const float bb = bp[c];
      #pragma unroll
      for (int r=0;r<4;r++){
        const int R = row0 + wm*64 + mi*16 + erow + r;
        if (GROUPED && R >= gend) continue;
        float v = acc[mi][ni][r] + bb;
        if (GELU_) v = 0.5f*v*(1.0f + erff(v*0.70710678118654752f));
        if constexpr (OMODE == 0){
          Cb[(size_t)R*N + c] = f2bf(v);
        } else if constexpr (OMODE == 1){
          Cf[(size_t)R*N + c] = v;
        } else {
          const int tok = tok_idx[R];
          const float gt = gate_s[R];
          float* p = Cf + (size_t)tok*N + c;
          *p += gt*v;
        }
      }
    }
}

// ---------------- token-level switch router (f32, one wave/token) ----------------
__global__ void token_router_k(const float* __restrict__ att, const int* __restrict__ sel,
    const float* __restrict__ sww, const float* __restrict__ swb,
    int* __restrict__ grp, float* __restrict__ gate, int* __restrict__ grp_cnt)
{
  const int t = blockIdx.x*4 + (threadIdx.x >> 6);
  const int lane = threadIdx.x & 63;
  const int e = sel[t >> 9];
  const float* x = att + (size_t)t * Dq;
  const float* w = sww + (size_t)e * Dq * 4;
  float a0=0.f, a1=0.f, a2=0.f, a3=0.f;
  #pragma unroll 4
  for (int i = 0; i < 12; i++){
    const int d = lane + i*64;
    const float xv = x[d];
    f32x4 wv = *(const f32x4*)&w[d*4];
    a0 += xv*wv[0]; a1 += xv*wv[1]; a2 += xv*wv[2]; a3 += xv*wv[3];
  }
  #pragma unroll
  for (int off = 32; off; off >>= 1){
    a0 += __shfl_xor(a0, off); a1 += __shfl_xor(a1, off);
    a2 += __shfl_xor(a2, off); a3 += __shfl_xor(a3, off);
  }
  if (lane == 0){
    const float l0 = a0 + swb[e*4+0], l1 = a1 + swb[e*4+1];
    const float l2 = a2 + swb[e*4+2], l3 = a3 + swb[e*4+3];
    const float mx = fmaxf(fmaxf(l0,l1), fmaxf(l2,l3));
    const float p0 = expf(l0-mx), p1 = expf(l1-mx), p2 = expf(l2-mx), p3 = expf(l3-mx);
    const float ssum = p0+p1+p2+p3;
    int am = 0; float bv = p0;
    if (p1 > bv){ bv=p1; am=1; }
    if (p2 > bv){ bv=p2; am=2; }
    if (p3 > bv){ bv=p3; am=3; }
    grp[t] = e*4 + am;
    gate[t] = bv/ssum;
    atomicAdd(&grp_cnt[e*4 + am], 1);
  }
}

__global__ void build_offsets_k(const int* __restrict__ grp_cnt, int* __restrict__ grp_off,
    int* __restrict__ tile_g, int* __restrict__ tile_r0, int* __restrict__ n_tiles)
{
  int off = 0, nt = 0;
  for (int g = 0; g < 16; g++){
    grp_off[g] = off;
    const int c = grp_cnt[g];
    for (int r0 = 0; r0 < c; r0 += 128){ tile_g[nt] = g; tile_r0[nt] = r0; nt++; }
    off += c;
  }
  grp_off[16] = off;
  *n_tiles = nt;
}

__global__ void scatter_k(const int* __restrict__ grp, const float* __restrict__ gate,
    const int* __restrict__ grp_off, int* __restrict__ fill,
    int* __restrict__ tok_idx, float* __restrict__ gate_s)
{
  const int t = blockIdx.x*256 + threadIdx.x;
  const int g = grp[t];
  const int pos = grp_off[g] + atomicAdd(&fill[g], 1);
  tok_idx[pos] = t;
  gate_s[pos] = gate[t];
}

// ---------------- final residual-add + LayerNorm ----------------
__global__ __launch_bounds__(256) void final_ln_k(const float* __restrict__ att,
    const float* __restrict__ acc, const float* __restrict__ lg,
    const float* __restrict__ lb, float* __restrict__ out)
{
  const int row = blockIdx.x, tid = threadIdx.x;
  const float* a = att + (size_t)row * Dq;
  const float* c = acc + (size_t)row * Dq;
  float x[3];
  #pragma unroll
  for (int i = 0; i < 3; i++) x[i] = a[tid + 256*i] + c[tid + 256*i];
  __shared__ float red[256];
  red[tid] = x[0] + x[1] + x[2];
  __syncthreads();
  for (int st = 128; st; st >>= 1){
    if (tid < st) red[tid] += red[tid + st];
    __syncthreads();
  }
  const float mu = red[0] * (1.0f/768.0f);
  __syncthreads();
  const float d0 = x[0]-mu, d1 = x[1]-mu, d2 = x[2]-mu;
  red[tid] = d0*d0 + d1*d1 + d2*d2;
  __syncthreads();
  for (int st = 128; st; st >>= 1){
    if (tid < st) red[tid] += red[tid + st];
    __syncthreads();
  }
  const float inv = 1.0f/sqrtf(red[0]*(1.0f/768.0f) + 1e-12f);
  #pragma unroll
  for (int i = 0; i < 3; i++){
    const int col = tid + 256*i;
    out[(size_t)row*Dq + col] = (x[i]-mu)*inv*lg[col] + lb[col];
  }
}

// ======================= launch =======================
extern "C" void kernel_launch(void* const* d_in, const int* in_sizes, int n_in,
                              void* d_out, int out_size, void* d_ws, size_t ws_size,
                              hipStream_t stream)
{
  (void)in_sizes; (void)n_in; (void)out_size; (void)ws_size;
  const float* hs    = (const float*)d_in[0];
  const float* amask = (const float*)d_in[1];
  const float* sw_enc_w = (const float*)d_in[3];
  const float* sw_enc_b = (const float*)d_in[4];
  const float* sw_w  = (const float*)d_in[5];
  const float* sw_b  = (const float*)d_in[6];
  const float* ca_wq = (const float*)d_in[7];
  const float* ca_bq = (const float*)d_in[8];
  const float* ca_wk = (const float*)d_in[9];
  const float* ca_bk = (const float*)d_in[10];
  const float* ca_wv = (const float*)d_in[11];
  const float* ca_bv = (const float*)d_in[12];
  const float* ca_wo = (const float*)d_in[13];
  const float* ca_bo = (const float*)d_in[14];
  const float* ua_wq = (const float*)d_in[15];
  const float* ua_bq = (const float*)d_in[16];
  const float* ua_wk = (const float*)d_in[17];
  const float* ua_bk = (const float*)d_in[18];
  const float* ua_wv = (const float*)d_in[19];
  const float* ua_bv = (const float*)d_in[20];
  const float* ua_wo = (const float*)d_in[21];
  const float* ua_bo = (const float*)d_in[22];
  const float* cf_w1 = (const float*)d_in[23];
  const float* cf_b1 = (const float*)d_in[24];
  const float* cf_w2 = (const float*)d_in[25];
  const float* cf_b2 = (const float*)d_in[26];
  const float* uf_sw_w = (const float*)d_in[27];
  const float* uf_sw_b = (const float*)d_in[28];
  const float* uf_w1 = (const float*)d_in[29];
  const float* uf_b1 = (const float*)d_in[30];
  const float* uf_w2 = (const float*)d_in[31];
  const float* uf_b2 = (const float*)d_in[32];
  const float* ln_g  = (const float*)d_in[33];
  const float* ln_b  = (const float*)d_in[34];
  float* out = (float*)d_out;

  char* W = (char*)d_ws;
  int*   sel     = (int*)(W + 0);
  float* pm      = (float*)(W + 64);
  int*   grp_cnt = (int*)(W + 128);
  int*   fill    = (int*)(W + 192);
  int*   ntile   = (int*)(W + 256);
  int*   grp_off = (int*)(W + 512);
  int*   tile_g  = (int*)(W + 1024);
  int*   tile_r  = (int*)(W + 1408);
  int*   grp     = (int*)(W + 4096);
  float* gate    = (float*)(W + 36864);
  int*   tok_idx = (int*)(W + 69632);
  float* gate_s  = (float*)(W + 102400);
  float* part    = (float*)(W + 262144);
  float* att     = (float*)(W + 2097152);    // [8192][768] f32
  float* facc    = (float*)(W + 27262976);   // [8192][768] f32
  float* Qb      = (float*)(W + 52428800);   // phase1
  float* Kb      = (float*)(W + 77594624);
  float* Vb      = (float*)(W + 102760448);
  float* Cx      = (float*)(W + 127926272);
  unsigned short* h1  = (unsigned short*)(W + 52428800);   // phase2 (reuse Q/K)
  unsigned short* w1T = (unsigned short*)(W + 102760448);  // phase2 (reuse V/ctx)
  unsigned short* w2T = (unsigned short*)(W + 182976512);

  hipMemsetAsync(W, 0, 1024, stream);

  // sequence router (exact f32)
  pooled_partial_k<<<dim3(Bq,3,4),256,0,stream>>>(hs, part);
  router_seq_k<<<Bq,128,0,stream>>>(part, sw_enc_w, sw_enc_b, sw_w, sw_b, sel, pm);

  // common attention (f32 path)
  gemm_f32_k<0,0><<<dim3(6,64),256,0,stream>>>(hs, ca_wq, ca_bq, Qb, NTq, Dq, Dq, nullptr, nullptr);
  gemm_f32_k<0,0><<<dim3(6,64),256,0,stream>>>(hs, ca_wk, ca_bk, Kb, NTq, Dq, Dq, nullptr, nullptr);
  gemm_f32_k<0,0><<<dim3(6,64),256,0,stream>>>(hs, ca_wv, ca_bv, Vb, NTq, Dq, Dq, nullptr, nullptr);
  attn_f32_k<<<dim3(8,Hq,Bq),256,0,stream>>>(Qb, Kb, Vb, amask, Cx);
  gemm_f32_k<0,0><<<dim3(6,64),256,0,stream>>>(Cx, ca_wo, ca_bo, att, NTq, Dq, Dq, nullptr, nullptr);

  // unique attention (selected expert per sequence), att += pm * result
  gemm_f32_k<1,0><<<dim3(6,64),256,0,stream>>>(hs, ua_wq, ua_bq, Qb, NTq, Dq, Dq, sel, nullptr);
  gemm_f32_k<1,0><<<dim3(6,64),256,0,stream>>>(hs, ua_wk, ua_bk, Kb, NTq, Dq, Dq, sel, nullptr);
  gemm_f32_k<1,0><<<dim3(6,64),256,0,stream>>>(hs, ua_wv, ua_bv, Vb, NTq, Dq, Dq, sel, nullptr);
  attn_f32_k<<<dim3(8,Hq,Bq),256,0,stream>>>(Qb, Kb, Vb, amask, Cx);
  gemm_f32_k<1,1><<<dim3(6,64),256,0,stream>>>(Cx, ua_wo, ua_bo, att, NTq, Dq, Dq, sel, pm);

  // FFN weights -> transposed bf16 (phase-2 regions now free)
  transpose_bf16_k<<<dim3(48,12,1), 256,0,stream>>>(cf_w1, w1T, Dq, Fq);
  transpose_bf16_k<<<dim3(48,12,16),256,0,stream>>>(uf_w1, w1T + 2359296, Dq, Fq);
  transpose_bf16_k<<<dim3(12,48,1), 256,0,stream>>>(cf_w2, w2T, Fq, Dq);
  transpose_bf16_k<<<dim3(12,48,16),256,0,stream>>>(uf_w2, w2T + 2359296, Fq, Dq);

  // common FFN (bf16 MFMA)
  gemm_bf16_k<0,0,true,false><<<dim3(24,64),256,0,stream>>>((const void*)att, w1T, cf_b1, nullptr, h1,
      NTq, Fq, Dq, nullptr,nullptr,nullptr,nullptr,nullptr,nullptr, (size_t)0, 0);
  gemm_bf16_k<2,1,false,false><<<dim3(6,64),256,0,stream>>>((const void*)h1, w2T, cf_b2, facc, nullptr,
      NTq, Dq, Fq, nullptr,nullptr,nullptr,nullptr,nullptr,nullptr, (size_t)0, 0);

  // token routing (f32, on accurate att)
  token_router_k<<<2048,256,0,stream>>>(att, sel, uf_sw_w, uf_sw_b, grp, gate, grp_cnt);
  build_offsets_k<<<1,1,0,stream>>>(grp_cnt, grp_off, tile_g, tile_r, ntile);
  scatter_k<<<32,256,0,stream>>>(grp, gate, grp_off, fill, tok_idx, gate_s);

  // unique FFN (grouped, top-1 inner expert, gated scatter-add)
  gemm_bf16_k<1,0,true,true><<<dim3(24,80),256,0,stream>>>((const void*)att, w1T + 2359296, uf_b1, nullptr, h1,
      NTq, Fq, Dq, tile_g, tile_r, grp_off, ntile, tok_idx, gate_s, (size_t)2359296, Fq);
  gemm_bf16_k<2,2,false,true><<<dim3(6,80),256,0,stream>>>((const void*)h1, w2T + 2359296, uf_b2, facc, nullptr,
      NTq, Dq, Fq, tile_g, tile_r, grp_off, ntile, tok_idx, gate_s, (size_t)2359296, Dq);

  // residual + LayerNorm
  final_ln_k<<<NTq,256,0,stream>>>(att, facc, ln_g, ln_b, out);
}

// Round 2
// 1616.904 us; speedup vs baseline: 1.4623x; 1.4623x over previous
//
#include <hip/hip_runtime.h>
#include <cstdint>
#include <cstddef>

#define Bq  16
#define Sq  512
#define Dq  768
#define Hq  12
#define DHq 64
#define Fq  3072
#define SWq 128
#define NTq 8192

typedef float        f32x4  __attribute__((ext_vector_type(4)));
typedef unsigned int u32x4  __attribute__((ext_vector_type(4)));
typedef __bf16       bf16x8 __attribute__((ext_vector_type(8)));
typedef _Float16     f16x8  __attribute__((ext_vector_type(8)));
typedef _Float16     f16x4  __attribute__((ext_vector_type(4)));

__device__ __forceinline__ unsigned short f2bf(float f){
  unsigned int u = __builtin_bit_cast(unsigned int, f);
  u = (u + 0x7fffu + ((u >> 16) & 1u)) >> 16;
  return (unsigned short)u;
}
__device__ __forceinline__ unsigned int pk2(float a, float b){
  return (unsigned int)f2bf(a) | ((unsigned int)f2bf(b) << 16);
}

// ---------------- pooled partial sums (seq router input) ----------------
__global__ void pooled_partial_k(const float* __restrict__ x, float* __restrict__ part){
  const int b = blockIdx.x, dc = blockIdx.y, z = blockIdx.z;
  const int d = dc*256 + threadIdx.x;
  const float* p = x + (size_t)b*Sq*Dq + (size_t)z*128*Dq + d;
  float s = 0.f;
  #pragma unroll 4
  for (int i = 0; i < 128; i++) s += p[(size_t)i*Dq];
  part[((size_t)z*Bq + b)*Dq + d] = s;
}

// ---------------- sequence-level router (exact f32) ----------------
__global__ void router_seq_k(const float* __restrict__ part,
    const float* __restrict__ ew, const float* __restrict__ eb,
    const float* __restrict__ sw, const float* __restrict__ sb,
    int* __restrict__ sel, float* __restrict__ pm)
{
  const int b = blockIdx.x, j = threadIdx.x;   // 128 threads
  __shared__ float h[SWq];
  __shared__ float pl[Dq];
  #pragma unroll
  for (int i = 0; i < 6; i++){
    int d = j + i*128;
    float s = part[(size_t)(0*Bq+b)*Dq + d] + part[(size_t)(1*Bq+b)*Dq + d]
            + part[(size_t)(2*Bq+b)*Dq + d] + part[(size_t)(3*Bq+b)*Dq + d];
    pl[d] = s * (1.0f/512.0f);
  }
  __syncthreads();
  float a = eb[j];
  for (int d = 0; d < Dq; d++) a += pl[d] * ew[d*SWq + j];
  h[j] = a;
  __syncthreads();
  if (j == 0){
    float lg[4];
    for (int e = 0; e < 4; e++){
      float t = sb[e];
      for (int k = 0; k < SWq; k++) t += h[k] * sw[k*4 + e];
      lg[e] = t;
    }
    float mx = fmaxf(fmaxf(lg[0],lg[1]), fmaxf(lg[2],lg[3]));
    float p[4], ssum = 0.f;
    for (int e = 0; e < 4; e++){ p[e] = expf(lg[e]-mx); ssum += p[e]; }
    int am = 0; float bv = p[0];
    for (int e = 1; e < 4; e++) if (p[e] > bv){ bv = p[e]; am = e; }
    sel[b] = am; pm[b] = bv/ssum;
  }
}

// ---------------- f32 -> f16 hi/lo split (x1024 scale) ----------------
__global__ void split_f16_k(const float* __restrict__ x, _Float16* __restrict__ hh,
                            _Float16* __restrict__ ll, int n4){
  const int i = blockIdx.x*256 + threadIdx.x;
  if (i >= n4) return;
  f32x4 v = ((const f32x4*)x)[i];
  f16x4 vh, vl;
  #pragma unroll
  for (int j = 0; j < 4; j++){
    float s = v[j] * 1024.0f;
    _Float16 a = (_Float16)s;
    vh[j] = a;
    vl[j] = (_Float16)(s - (float)a);
  }
  ((f16x4*)hh)[i] = vh;
  ((f16x4*)ll)[i] = vl;
}

// ------- weight transpose + f16 hi/lo split: src [K][N] -> dst [N][K] x1024 -------
__global__ void transpose_f16s_k(const float* __restrict__ src,
    _Float16* __restrict__ dH, _Float16* __restrict__ dL,
    int K, int N, long srcStride, long dstStride, int rowOff)
{
  __shared__ float t[64][65];
  const int tid = threadIdx.x;
  const size_t so = (size_t)blockIdx.z * srcStride;
  const size_t dof = (size_t)blockIdx.z * dstStride;
  const int k0 = blockIdx.y * 64, n0 = blockIdx.x * 64;
  const int r = tid >> 2, c0 = (tid & 3) * 16;
  const float* sp = src + so + (size_t)(k0 + r) * N + n0 + c0;
  #pragma unroll
  for (int cc = 0; cc < 16; cc += 4){
    f32x4 v = *(const f32x4*)(sp + cc);
    t[r][c0+cc] = v[0]; t[r][c0+cc+1] = v[1]; t[r][c0+cc+2] = v[2]; t[r][c0+cc+3] = v[3];
  }
  __syncthreads();
  _Float16* ph = dH + dof + (size_t)(rowOff + n0 + r) * K + k0 + c0;
  _Float16* pl = dL + dof + (size_t)(rowOff + n0 + r) * K + k0 + c0;
  #pragma unroll
  for (int cc = 0; cc < 16; cc += 4){
    f16x4 vh, vl;
    #pragma unroll
    for (int j = 0; j < 4; j++){
      float s = t[c0+cc+j][r] * 1024.0f;
      _Float16 a = (_Float16)s;
      vh[j] = a; vl[j] = (_Float16)(s - (float)a);
    }
    *(f16x4*)(ph + cc) = vh;
    *(f16x4*)(pl + cc) = vl;
  }
}

// ---------------- concat q/k/v biases -> [E][2304] ----------------
__global__ void concat_bias3_k(const float* __restrict__ bq, const float* __restrict__ bk,
    const float* __restrict__ bv, float* __restrict__ dst, int srcStride)
{
  const int e = blockIdx.y;
  const int i = blockIdx.x*256 + threadIdx.x;   // grid.x=3 -> i<768
  dst[(size_t)e*2304 + i]        = bq[(size_t)e*srcStride + i];
  dst[(size_t)e*2304 + 768 + i]  = bk[(size_t)e*srcStride + i];
  dst[(size_t)e*2304 + 1536 + i] = bv[(size_t)e*srcStride + i];
}

// ---------------- split-f16 3-term MFMA GEMM (~f32 accuracy) ----------------
// A = (AH+AL)/1024 [M][K], B^T = (BH+BL)/1024 [N][K]; C = A@B + bias
// BMODE: 0 shared B; 1 per-sequence expert. OMODE: 0 C=v; 1 C += pm*v
template<int BMODE, int OMODE>
__global__ __launch_bounds__(256,2) void gemm_f16s_k(
    const _Float16* __restrict__ AH, const _Float16* __restrict__ AL,
    const _Float16* __restrict__ BH, const _Float16* __restrict__ BL,
    const float* __restrict__ bias, float* __restrict__ C,
    int N, int K, long estride, int bias_stride,
    const int* __restrict__ sel, const float* __restrict__ pm)
{
  __shared__ _Float16 AsH[128][40];
  __shared__ _Float16 AsL[128][40];
  __shared__ _Float16 BsH[128][40];
  __shared__ _Float16 BsL[128][40];
  const int tid = threadIdx.x;
  const int lane = tid & 63, wave = tid >> 6;
  const int wm = wave >> 1, wn = wave & 1;
  const int row0 = blockIdx.y * 128, col0 = blockIdx.x * 128;
  const _Float16* bh = BH; const _Float16* bl = BL; const float* bp = bias;
  float cs = 1.0f;
  if constexpr (BMODE == 1){
    const int e = sel[row0 >> 9];
    bh += (size_t)e * estride; bl += (size_t)e * estride;
    bp += (size_t)e * bias_stride;
  }
  if constexpr (OMODE == 1) cs = pm[row0 >> 9];

  const int sr = tid >> 1, sk = (tid & 1) * 16;
  const _Float16* ahp = AH + (size_t)(row0 + sr) * K + sk;
  const _Float16* alp = AL + (size_t)(row0 + sr) * K + sk;
  const _Float16* bhp = bh + (size_t)(col0 + sr) * K + sk;
  const _Float16* blp = bl + (size_t)(col0 + sr) * K + sk;

  f32x4 acc[4][4];
  #pragma unroll
  for (int mi=0;mi<4;mi++)
    #pragma unroll
    for (int ni=0;ni<4;ni++) acc[mi][ni] = (f32x4){0.f,0.f,0.f,0.f};

  for (int k0 = 0; k0 < K; k0 += 32){
    u32x4 vah0 = *(const u32x4*)(ahp + k0);
    u32x4 vah1 = *(const u32x4*)(ahp + k0 + 8);
    u32x4 val0 = *(const u32x4*)(alp + k0);
    u32x4 val1 = *(const u32x4*)(alp + k0 + 8);
    u32x4 vbh0 = *(const u32x4*)(bhp + k0);
    u32x4 vbh1 = *(const u32x4*)(bhp + k0 + 8);
    u32x4 vbl0 = *(const u32x4*)(blp + k0);
    u32x4 vbl1 = *(const u32x4*)(blp + k0 + 8);
    __syncthreads();
    *(u32x4*)&AsH[sr][sk]   = vah0; *(u32x4*)&AsH[sr][sk+8] = vah1;
    *(u32x4*)&AsL[sr][sk]   = val0; *(u32x4*)&AsL[sr][sk+8] = val1;
    *(u32x4*)&BsH[sr][sk]   = vbh0; *(u32x4*)&BsH[sr][sk+8] = vbh1;
    *(u32x4*)&BsL[sr][sk]   = vbl0; *(u32x4*)&BsL[sr][sk+8] = vbl1;
    __syncthreads();
    f16x8 fah[4], fal[4], fbh[4], fbl[4];
    #pragma unroll
    for (int mi=0;mi<4;mi++){
      const int r = wm*64 + mi*16 + (lane&15), c = 8*(lane>>4);
      fah[mi] = __builtin_bit_cast(f16x8, *(const u32x4*)&AsH[r][c]);
      fal[mi] = __builtin_bit_cast(f16x8, *(const u32x4*)&AsL[r][c]);
    }
    #pragma unroll
    for (int ni=0;ni<4;ni++){
      const int r = wn*64 + ni*16 + (lane&15), c = 8*(lane>>4);
      fbh[ni] = __builtin_bit_cast(f16x8, *(const u32x4*)&BsH[r][c]);
      fbl[ni] = __builtin_bit_cast(f16x8, *(const u32x4*)&BsL[r][c]);
    }
    #pragma unroll
    for (int mi=0;mi<4;mi++)
      #pragma unroll
      for (int ni=0;ni<4;ni++){
        acc[mi][ni] = __builtin_amdgcn_mfma_f32_16x16x32_f16(fah[mi], fbh[ni], acc[mi][ni], 0, 0, 0);
        acc[mi][ni] = __builtin_amdgcn_mfma_f32_16x16x32_f16(fah[mi], fbl[ni], acc[mi][ni], 0, 0, 0);
        acc[mi][ni] = __builtin_amdgcn_mfma_f32_16x16x32_f16(fal[mi], fbh[ni], acc[mi][ni], 0, 0, 0);
      }
  }

  const float INV = 1.0f/1048576.0f;   // undo 1024*1024 scaling (exact pow2)
  const int erow = 4*(lane >> 4);
  const int ecol = lane & 15;
  #pragma unroll
  for (int mi=0;mi<4;mi++)
    #pragma unroll
    for (int ni=0;ni<4;ni++){
      const int c = col0 + wn*64 + ni*16 + ecol;
      const float bb = bp[c];
      #pragma unroll
      for (int r=0;r<4;r++){
        const int R = row0 + wm*64 + mi*16 + erow + r;
        const float v = acc[mi][ni][r]*INV + bb;
        if constexpr (OMODE == 0){
          C[(size_t)R*N + c] = v;
        } else {
          C[(size_t)R*N + c] += cs*v;
        }
      }
    }
}

// ------- f32 attention (exact VALU path; conflict-free LDS; f16-split ctx out) -------
__global__ __launch_bounds__(256,2) void attn_f32_k(
    const float* __restrict__ QKV, const float* __restrict__ mask,
    _Float16* __restrict__ ctxH, _Float16* __restrict__ ctxL)
{
  __shared__ float QsT[64][64];   // [d][q], col ^ ((d>>4)&3)<<3
  __shared__ float KsT[64][64];   // [d][k], same swizzle
  __shared__ float VsT[64][64];   // [feat][k], col ^ ((feat>>2)&15)<<2
  __shared__ float Ps [64][64];   // [q][k], plain
  const int qt = blockIdx.x, h = blockIdx.y, b = blockIdx.z;
  const int tid = threadIdx.x;
  const int tx = tid & 15, ty = tid >> 4;
  const int sr = tid >> 2, sc = (tid & 3) * 16;
  {
    const float* qp = QKV + (size_t)(b*Sq + qt*64 + sr)*2304 + h*DHq + sc;
    #pragma unroll
    for (int c = 0; c < 16; c += 4){
      f32x4 v = *(const f32x4*)(qp + c);
      #pragma unroll
      for (int t = 0; t < 4; t++){
        const int row = sc + c + t;
        QsT[row][sr ^ (((row>>4)&3)<<3)] = v[t];
      }
    }
  }
  float accp[4][4]; float rs[4];
  #pragma unroll
  for (int i=0;i<4;i++){ rs[i]=0.f; for (int j=0;j<4;j++) accp[i][j]=0.f; }
  const float* mrow = mask + b*Sq;

  for (int kt = 0; kt < 8; kt++){
    __syncthreads();
    {
      const float* kp = QKV + (size_t)(b*Sq + kt*64 + sr)*2304 + 768 + h*DHq + sc;
      const float* vp = kp + 768;
      #pragma unroll
      for (int c = 0; c < 16; c += 4){
        f32x4 v = *(const f32x4*)(kp + c);
        #pragma unroll
        for (int t = 0; t < 4; t++){
          const int row = sc + c + t;
          KsT[row][sr ^ (((row>>4)&3)<<3)] = v[t];
        }
      }
      #pragma unroll
      for (int c = 0; c < 16; c += 4){
        f32x4 v = *(const f32x4*)(vp + c);
        #pragma unroll
        for (int t = 0; t < 4; t++){
          const int row = sc + c + t;
          VsT[row][sr ^ (((row>>2)&15)<<2)] = v[t];
        }
      }
    }
    __syncthreads();
    float s[4][4];
    #pragma unroll
    for (int i=0;i<4;i++)
      #pragma unroll
      for (int j=0;j<4;j++) s[i][j]=0.f;
    #pragma unroll 8
    for (int d = 0; d < 64; d++){
      const int sw = ((d>>4)&3)<<3;
      f32x4 a = *(const f32x4*)&QsT[d][(ty*4) ^ sw];
      f32x4 k = *(const f32x4*)&KsT[d][(tx*4) ^ sw];
      #pragma unroll
      for (int i=0;i<4;i++)
        #pragma unroll
        for (int j=0;j<4;j++) s[i][j] += a[i]*k[j];
    }
    f32x4 mk = *(const f32x4*)(mrow + kt*64 + tx*4);
    float pr[4][4], rp[4];
    #pragma unroll
    for (int i=0;i<4;i++){
      rp[i]=0.f;
      #pragma unroll
      for (int j=0;j<4;j++){
        float p = __expf(s[i][j]*0.125f + mk[j]);
        pr[i][j]=p; rp[i]+=p;
      }
    }
    #pragma unroll
    for (int off=1; off<16; off<<=1)
      #pragma unroll
      for (int i=0;i<4;i++) rp[i] += __shfl_xor(rp[i], off);
    #pragma unroll
    for (int i=0;i<4;i++) rs[i] += rp[i];
    #pragma unroll
    for (int i=0;i<4;i++)
      *(f32x4*)&Ps[ty*4+i][tx*4] = (f32x4){pr[i][0],pr[i][1],pr[i][2],pr[i][3]};
    __syncthreads();
    #pragma unroll 4
    for (int k0 = 0; k0 < 64; k0 += 4){
      f32x4 pa[4], vv[4];
      #pragma unroll
      for (int i=0;i<4;i++) pa[i] = *(const f32x4*)&Ps[ty*4+i][k0];
      #pragma unroll
      for (int j=0;j<4;j++){
        const int r = tx*4+j;
        vv[j] = *(const f32x4*)&VsT[r][k0 ^ (((r>>2)&15)<<2)];
      }
      #pragma unroll
      for (int i=0;i<4;i++)
        #pragma unroll
        for (int j=0;j<4;j++)
          accp[i][j] += pa[i][0]*vv[j][0] + pa[i][1]*vv[j][1]
                      + pa[i][2]*vv[j][2] + pa[i][3]*vv[j][3];
    }
  }
  #pragma unroll
  for (int i=0;i<4;i++){
    const float inv = 1024.0f/rs[i];
    f16x4 hh, ll;
    #pragma unroll
    for (int j=0;j<4;j++){
      float o = accp[i][j]*inv;
      _Float16 a = (_Float16)o;
      hh[j] = a; ll[j] = (_Float16)(o - (float)a);
    }
    const size_t off = (size_t)(b*Sq + qt*64 + ty*4 + i)*Dq + h*DHq + tx*4;
    *(f16x4*)(ctxH + off) = hh;
    *(f16x4*)(ctxL + off) = ll;
  }
}

// ---------------- transpose + f32->bf16 (FFN weights -> [N][K] bf16) ----------------
__global__ void transpose_bf16_k(const float* __restrict__ src, unsigned short* __restrict__ dst,
                                 int K, int N)
{
  __shared__ float t[64][65];
  const int tid = threadIdx.x;
  const size_t mo = (size_t)blockIdx.z * K * N;
  const int k0 = blockIdx.y * 64, n0 = blockIdx.x * 64;
  const int r = tid >> 2, c0 = (tid & 3) * 16;
  const float* sp = src + mo + (size_t)(k0 + r) * N + n0 + c0;
  #pragma unroll
  for (int cc = 0; cc < 16; cc += 4){
    f32x4 v = *(const f32x4*)(sp + cc);
    t[r][c0+cc] = v[0]; t[r][c0+cc+1] = v[1]; t[r][c0+cc+2] = v[2]; t[r][c0+cc+3] = v[3];
  }
  __syncthreads();
  unsigned short* dp = dst + mo + (size_t)(n0 + r) * K + k0 + c0;
  u32x4 h0, h1v;
  #pragma unroll
  for (int i = 0; i < 4; i++) h0[i]  = pk2(t[c0+2*i  ][r], t[c0+2*i+1][r]);
  #pragma unroll
  for (int i = 0; i < 4; i++) h1v[i] = pk2(t[c0+8+2*i][r], t[c0+9+2*i][r]);
  *(u32x4*)(dp)     = h0;
  *(u32x4*)(dp + 8) = h1v;
}

// ---------------- bf16 MFMA GEMM (FFN path) ----------------
// AMODE: 0 f32 rows; 1 f32 rows via tok_idx; 2 bf16 rows
// OMODE: 0 bf16 store (h1); 1 f32 write+bias; 2 f32 scatter add gate*(res+bias)
template<int AMODE, int OMODE, bool GELU_, bool GROUPED>
__global__ __launch_bounds__(256,2) void gemm_bf16_k(
    const void* __restrict__ Av, const unsigned short* __restrict__ BT,
    const float* __restrict__ bias, float* __restrict__ Cf, unsigned short* __restrict__ Cb,
    int M, int N, int K,
    const int* __restrict__ tile_g, const int* __restrict__ tile_r0,
    const int* __restrict__ grp_off, const int* __restrict__ n_tiles,
    const int* __restrict__ tok_idx, const float* __restrict__ gate_s,
    size_t bstride, int bias_stride)
{
  __shared__ unsigned short As[128][40];
  __shared__ unsigned short Bs[128][40];
  const int tid = threadIdx.x;
  const int lane = tid & 63, wave = tid >> 6;
  const int wm = wave >> 1, wn = wave & 1;
  const int col0 = blockIdx.x * 128;
  int row0, gend = 1 << 30, g = 0;
  if constexpr (GROUPED){
    const int t = blockIdx.y;
    if (t >= *n_tiles) return;
    g = tile_g[t];
    row0 = grp_off[g] + tile_r0[t];
    gend = grp_off[g+1];
  } else {
    row0 = blockIdx.y * 128;
  }
  const unsigned short* Bp = BT + (size_t)g * bstride;
  const float* bp = bias + (size_t)g * bias_stride;

  const int sr = tid >> 1;
  const int sk = (tid & 1) * 16;
  int arow = row0 + sr;
  if constexpr (GROUPED) arow = (arow < gend - 1) ? arow : (gend - 1);
  if constexpr (AMODE == 1) arow = tok_idx[arow];
  const float*          afp = (const float*)Av          + (size_t)arow * K + sk;
  const unsigned short* abp = (const unsigned short*)Av + (size_t)arow * K + sk;
  const unsigned short* bfp = Bp + (size_t)(col0 + sr) * K + sk;

  f32x4 acc[4][4];
  #pragma unroll
  for (int mi=0;mi<4;mi++)
    #pragma unroll
    for (int ni=0;ni<4;ni++) acc[mi][ni] = (f32x4){0.f,0.f,0.f,0.f};

  for (int k0 = 0; k0 < K; k0 += 32){
    u32x4 bl0 = *(const u32x4*)(bfp + k0);
    u32x4 bl1 = *(const u32x4*)(bfp + k0 + 8);
    u32x4 al0, al1;
    if constexpr (AMODE == 2){
      al0 = *(const u32x4*)(abp + k0);
      al1 = *(const u32x4*)(abp + k0 + 8);
    } else {
      f32x4 f0 = *(const f32x4*)(afp + k0);
      f32x4 f1 = *(const f32x4*)(afp + k0 + 4);
      f32x4 f2 = *(const f32x4*)(afp + k0 + 8);
      f32x4 f3 = *(const f32x4*)(afp + k0 + 12);
      al0[0]=pk2(f0[0],f0[1]); al0[1]=pk2(f0[2],f0[3]); al0[2]=pk2(f1[0],f1[1]); al0[3]=pk2(f1[2],f1[3]);
      al1[0]=pk2(f2[0],f2[1]); al1[1]=pk2(f2[2],f2[3]); al1[2]=pk2(f3[0],f3[1]); al1[3]=pk2(f3[2],f3[3]);
    }
    __syncthreads();
    *(u32x4*)&As[sr][sk]     = al0;
    *(u32x4*)&As[sr][sk + 8] = al1;
    *(u32x4*)&Bs[sr][sk]     = bl0;
    *(u32x4*)&Bs[sr][sk + 8] = bl1;
    __syncthreads();
    bf16x8 af[4], bfr[4];
    #pragma unroll
    for (int mi=0;mi<4;mi++){
      u32x4 t = *(const u32x4*)&As[wm*64 + mi*16 + (lane&15)][8*(lane>>4)];
      af[mi] = __builtin_bit_cast(bf16x8, t);
    }
    #pragma unroll
    for (int ni=0;ni<4;ni++){
      u32x4 t = *(const u32x4*)&Bs[wn*64 + ni*16 + (lane&15)][8*(lane>>4)];
      bfr[ni] = __builtin_bit_cast(bf16x8, t);
    }
    #pragma unroll
    for (int mi=0;mi<4;mi++)
      #pragma unroll
      for (int ni=0;ni<4;ni++)
        acc[mi][ni] = __builtin_amdgcn_mfma_f32_16x16x32_bf16(af[mi], bfr[ni], acc[mi][ni], 0, 0, 0);
  }

  const int erow = 4*(lane >> 4);
  const int ecol = lane & 15;
  #pragma unroll
  for (int mi=0;mi<4;mi++)
    #pragma unroll
    for (int ni=0;ni<4;ni++){
      const int c = col0 + wn*64 + ni*16 + ecol;
      const float bb = bp[c];
      #pragma unroll
      for (int r=0;r<4;r++){
        const int R = row0 + wm*64 + mi*16 + erow + r;
        if (GROUPED && R >= gend) continue;
        float v = acc[mi][ni][r] + bb;
        if (GELU_) v = 0.5f*v*(1.0f + erff(v*0.70710678118654752f));
        if constexpr (OMODE == 0){
          Cb[(size_t)R*N + c] = f2bf(v);
        } else if constexpr (OMODE == 1){
          Cf[(size_t)R*N + c] = v;
        } else {
          const int tok = tok_idx[R];
          const float gt = gate_s[R];
          float* p = Cf + (size_t)tok*N + c;
          *p += gt*v;
        }
      }
    }
}

// ---------------- token-level switch router (f32, one wave/token) ----------------
__global__ void token_router_k(const float* __restrict__ att, const int* __restrict__ sel,
    const float* __restrict__ sww, const float* __restrict__ swb,
    int* __restrict__ grp, float* __restrict__ gate, int* __restrict__ grp_cnt)
{
  const int t = blockIdx.x*4 + (threadIdx.x >> 6);
  const int lane = threadIdx.x & 63;
  const int e = sel[t >> 9];
  const float* x = att + (size_t)t * Dq;
  const float* w = sww + (size_t)e * Dq * 4;
  float a0=0.f, a1=0.f, a2=0.f, a3=0.f;
  #pragma unroll 4
  for (int i = 0; i < 12; i++){
    const int d = lane + i*64;
    const float xv = x[d];
    f32x4 wv = *(const f32x4*)&w[d*4];
    a0 += xv*wv[0]; a1 += xv*wv[1]; a2 += xv*wv[2]; a3 += xv*wv[3];
  }
  #pragma unroll
  for (int off = 32; off; off >>= 1){
    a0 += __shfl_xor(a0, off); a1 += __shfl_xor(a1, off);
    a2 += __shfl_xor(a2, off); a3 += __shfl_xor(a3, off);
  }
  if (lane == 0){
    const float l0 = a0 + swb[e*4+0], l1 = a1 + swb[e*4+1];
    const float l2 = a2 + swb[e*4+2], l3 = a3 + swb[e*4+3];
    const float mx = fmaxf(fmaxf(l0,l1), fmaxf(l2,l3));
    const float p0 = expf(l0-mx), p1 = expf(l1-mx), p2 = expf(l2-mx), p3 = expf(l3-mx);
    const float ssum = p0+p1+p2+p3;
    int am = 0; float bv = p0;
    if (p1 > bv){ bv=p1; am=1; }
    if (p2 > bv){ bv=p2; am=2; }
    if (p3 > bv){ bv=p3; am=3; }
    grp[t] = e*4 + am;
    gate[t] = bv/ssum;
    atomicAdd(&grp_cnt[e*4 + am], 1);
  }
}

__global__ void build_offsets_k(const int* __restrict__ grp_cnt, int* __restrict__ grp_off,
    int* __restrict__ tile_g, int* __restrict__ tile_r0, int* __restrict__ n_tiles)
{
  int off = 0, nt = 0;
  for (int g = 0; g < 16; g++){
    grp_off[g] = off;
    const int c = grp_cnt[g];
    for (int r0 = 0; r0 < c; r0 += 128){ tile_g[nt] = g; tile_r0[nt] = r0; nt++; }
    off += c;
  }
  grp_off[16] = off;
  *n_tiles = nt;
}

__global__ void scatter_k(const int* __restrict__ grp, const float* __restrict__ gate,
    const int* __restrict__ grp_off, int* __restrict__ fill,
    int* __restrict__ tok_idx, float* __restrict__ gate_s)
{
  const int t = blockIdx.x*256 + threadIdx.x;
  const int g = grp[t];
  const int pos = grp_off[g] + atomicAdd(&fill[g], 1);
  tok_idx[pos] = t;
  gate_s[pos] = gate[t];
}

// ---------------- final residual-add + LayerNorm ----------------
__global__ __launch_bounds__(256) void final_ln_k(const float* __restrict__ att,
    const float* __restrict__ acc, const float* __restrict__ lg,
    const float* __restrict__ lb, float* __restrict__ out)
{
  const int row = blockIdx.x, tid = threadIdx.x;
  const float* a = att + (size_t)row * Dq;
  const float* c = acc + (size_t)row * Dq;
  float x[3];
  #pragma unroll
  for (int i = 0; i < 3; i++) x[i] = a[tid + 256*i] + c[tid + 256*i];
  __shared__ float red[256];
  red[tid] = x[0] + x[1] + x[2];
  __syncthreads();
  for (int st = 128; st; st >>= 1){
    if (tid < st) red[tid] += red[tid + st];
    __syncthreads();
  }
  const float mu = red[0] * (1.0f/768.0f);
  __syncthreads();
  const float d0 = x[0]-mu, d1 = x[1]-mu, d2 = x[2]-mu;
  red[tid] = d0*d0 + d1*d1 + d2*d2;
  __syncthreads();
  for (int st = 128; st; st >>= 1){
    if (tid < st) red[tid] += red[tid + st];
    __syncthreads();
  }
  const float inv = 1.0f/sqrtf(red[0]*(1.0f/768.0f) + 1e-12f);
  #pragma unroll
  for (int i = 0; i < 3; i++){
    const int col = tid + 256*i;
    out[(size_t)row*Dq + col] = (x[i]-mu)*inv*lg[col] + lb[col];
  }
}

// ======================= launch =======================
extern "C" void kernel_launch(void* const* d_in, const int* in_sizes, int n_in,
                              void* d_out, int out_size, void* d_ws, size_t ws_size,
                              hipStream_t stream)
{
  (void)in_sizes; (void)n_in; (void)out_size; (void)ws_size;
  const float* hs    = (const float*)d_in[0];
  const float* amask = (const float*)d_in[1];
  const float* sw_enc_w = (const float*)d_in[3];
  const float* sw_enc_b = (const float*)d_in[4];
  const float* sw_w  = (const float*)d_in[5];
  const float* sw_b  = (const float*)d_in[6];
  const float* ca_wq = (const float*)d_in[7];
  const float* ca_bq = (const float*)d_in[8];
  const float* ca_wk = (const float*)d_in[9];
  const float* ca_bk = (const float*)d_in[10];
  const float* ca_wv = (const float*)d_in[11];
  const float* ca_bv = (const float*)d_in[12];
  const float* ca_wo = (const float*)d_in[13];
  const float* ca_bo = (const float*)d_in[14];
  const float* ua_wq = (const float*)d_in[15];
  const float* ua_bq = (const float*)d_in[16];
  const float* ua_wk = (const float*)d_in[17];
  const float* ua_bk = (const float*)d_in[18];
  const float* ua_wv = (const float*)d_in[19];
  const float* ua_bv = (const float*)d_in[20];
  const float* ua_wo = (const float*)d_in[21];
  const float* ua_bo = (const float*)d_in[22];
  const float* cf_w1 = (const float*)d_in[23];
  const float* cf_b1 = (const float*)d_in[24];
  const float* cf_w2 = (const float*)d_in[25];
  const float* cf_b2 = (const float*)d_in[26];
  const float* uf_sw_w = (const float*)d_in[27];
  const float* uf_sw_b = (const float*)d_in[28];
  const float* uf_w1 = (const float*)d_in[29];
  const float* uf_b1 = (const float*)d_in[30];
  const float* uf_w2 = (const float*)d_in[31];
  const float* uf_b2 = (const float*)d_in[32];
  const float* ln_g  = (const float*)d_in[33];
  const float* ln_b  = (const float*)d_in[34];
  float* out = (float*)d_out;

  char* W = (char*)d_ws;
  // control block (zeroed each launch)
  int*   sel     = (int*)(W + 0);
  float* pm      = (float*)(W + 64);
  int*   grp_cnt = (int*)(W + 128);
  int*   fill    = (int*)(W + 192);
  int*   ntile   = (int*)(W + 256);
  int*   grp_off = (int*)(W + 512);
  int*   tile_g  = (int*)(W + 1024);
  int*   tile_r  = (int*)(W + 2048);
  float* part    = (float*)(W + 3072);          // 64*768*4 = 196608 -> needs own space
  // NOTE: part needs 4*16*768*4 = 196608 B; place it in phase-A scratch below.

  float* att  = (float*)(W + 4096);             // [8192][768] f32, end 25169920
  float* facc = (float*)(W + 25169920);         // [8192][768] f32, end 50335744
  const size_t X = 50335744;
  _Float16* hsH  = (_Float16*)(W + X);                 // 12582912
  _Float16* hsL  = (_Float16*)(W + X + 12582912);      // end X+25165824
  float*    QKV  = (float*)(W + X + 25165824);         // 75497472, end X+100663296
  _Float16* ctxH = (_Float16*)(W + X + 100663296);     // 12582912
  _Float16* ctxL = (_Float16*)(W + X + 113246208);     // end X+125829120
  _Float16* wqkv_cH = (_Float16*)(W + X + 125829120);  // 3538944
  _Float16* wqkv_cL = (_Float16*)(W + X + 129368064);
  _Float16* wqkv_uH = (_Float16*)(W + X + 132907008);  // 14155776
  _Float16* wqkv_uL = (_Float16*)(W + X + 147062784);
  _Float16* wo_cH   = (_Float16*)(W + X + 161218560);  // 1179648
  _Float16* wo_cL   = (_Float16*)(W + X + 162398208);
  _Float16* wo_uH   = (_Float16*)(W + X + 163577856);  // 4718592
  _Float16* wo_uL   = (_Float16*)(W + X + 168296448);  // end X+173015040
  float* qkvb_c = (float*)(W + X + 173015040);         // 9216
  float* qkvb_u = (float*)(W + X + 173024256);         // 36864, end X+173061120
  float* partb  = (float*)(W + X + 173061120);         // 196608, end X+173257728

  // phase B (after attention) reuses phase-A scratch:
  unsigned short* w1T = (unsigned short*)(W + X);              // 17*2359296*2 = 80216064
  unsigned short* w2T = (unsigned short*)(W + X + 80216064);   // end X+160432128
  unsigned short* h1  = (unsigned short*)(W + X + 160432128);  // 50331648, end X+210763776
  int*   grp     = (int*)(W + 261099520);
  float* gate    = (float*)(W + 261132288);
  int*   tok_idx = (int*)(W + 261165056);
  float* gate_s  = (float*)(W + 261197824);    // end 261230592

  hipMemsetAsync(W, 0, 3072, stream);

  // ---- sequence router (exact f32) ----
  pooled_partial_k<<<dim3(Bq,3,4),256,0,stream>>>(hs, partb);
  router_seq_k<<<Bq,128,0,stream>>>(partb, sw_enc_w, sw_enc_b, sw_w, sw_b, sel, pm);

  // ---- prepare split-f16 operands ----
  split_f16_k<<<6144,256,0,stream>>>(hs, hsH, hsL, NTq*Dq/4);
  transpose_f16s_k<<<dim3(12,12,1),256,0,stream>>>(ca_wq, wqkv_cH, wqkv_cL, Dq, Dq, 0, 0, 0);
  transpose_f16s_k<<<dim3(12,12,1),256,0,stream>>>(ca_wk, wqkv_cH, wqkv_cL, Dq, Dq, 0, 0, 768);
  transpose_f16s_k<<<dim3(12,12,1),256,0,stream>>>(ca_wv, wqkv_cH, wqkv_cL, Dq, Dq, 0, 0, 1536);
  transpose_f16s_k<<<dim3(12,12,4),256,0,stream>>>(ua_wq, wqkv_uH, wqkv_uL, Dq, Dq, (long)Dq*Dq, (long)2304*768, 0);
  transpose_f16s_k<<<dim3(12,12,4),256,0,stream>>>(ua_wk, wqkv_uH, wqkv_uL, Dq, Dq, (long)Dq*Dq, (long)2304*768, 768);
  transpose_f16s_k<<<dim3(12,12,4),256,0,stream>>>(ua_wv, wqkv_uH, wqkv_uL, Dq, Dq, (long)Dq*Dq, (long)2304*768, 1536);
  transpose_f16s_k<<<dim3(12,12,1),256,0,stream>>>(ca_wo, wo_cH, wo_cL, Dq, Dq, 0, 0, 0);
  transpose_f16s_k<<<dim3(12,12,4),256,0,stream>>>(ua_wo, wo_uH, wo_uL, Dq, Dq, (long)Dq*Dq, (long)Dq*Dq, 0);
  concat_bias3_k<<<dim3(3,1),256,0,stream>>>(ca_bq, ca_bk, ca_bv, qkvb_c, 0);
  concat_bias3_k<<<dim3(3,4),256,0,stream>>>(ua_bq, ua_bk, ua_bv, qkvb_u, 768);

  // ---- common attention ----
  gemm_f16s_k<0,0><<<dim3(18,64),256,0,stream>>>(hsH, hsL, wqkv_cH, wqkv_cL, qkvb_c, QKV,
      2304, Dq, 0, 0, nullptr, nullptr);
  attn_f32_k<<<dim3(8,Hq,Bq),256,0,stream>>>(QKV, amask, ctxH, ctxL);
  gemm_f16s_k<0,0><<<dim3(6,64),256,0,stream>>>(ctxH, ctxL, wo_cH, wo_cL, ca_bo, att,
      Dq, Dq, 0, 0, nullptr, nullptr);

  // ---- unique attention (selected expert), att += pm * result ----
  gemm_f16s_k<1,0><<<dim3(18,64),256,0,stream>>>(hsH, hsL, wqkv_uH, wqkv_uL, qkvb_u, QKV,
      2304, Dq, (long)2304*768, 2304, sel, nullptr);
  attn_f32_k<<<dim3(8,Hq,Bq),256,0,stream>>>(QKV, amask, ctxH, ctxL);
  gemm_f16s_k<1,1><<<dim3(6,64),256,0,stream>>>(ctxH, ctxL, wo_uH, wo_uL, ua_bo, att,
      Dq, Dq, (long)Dq*Dq, Dq, sel, pm);

  // ---- FFN weights -> transposed bf16 (phase-A scratch now free) ----
  transpose_bf16_k<<<dim3(48,12,1), 256,0,stream>>>(cf_w1, w1T, Dq, Fq);
  transpose_bf16_k<<<dim3(48,12,16),256,0,stream>>>(uf_w1, w1T + 2359296, Dq, Fq);
  transpose_bf16_k<<<dim3(12,48,1), 256,0,stream>>>(cf_w2, w2T, Fq, Dq);
  transpose_bf16_k<<<dim3(12,48,16),256,0,stream>>>(uf_w2, w2T + 2359296, Fq, Dq);

  // ---- common FFN (bf16 MFMA) ----
  gemm_bf16_k<0,0,true,false><<<dim3(24,64),256,0,stream>>>((const void*)att, w1T, cf_b1, nullptr, h1,
      NTq, Fq, Dq, nullptr,nullptr,nullptr,nullptr,nullptr,nullptr, (size_t)0, 0);
  gemm_bf16_k<2,1,false,false><<<dim3(6,64),256,0,stream>>>((const void*)h1, w2T, cf_b2, facc, nullptr,
      NTq, Dq, Fq, nullptr,nullptr,nullptr,nullptr,nullptr,nullptr, (size_t)0, 0);

  // ---- token routing (f32, on accurate att) ----
  token_router_k<<<2048,256,0,stream>>>(att, sel, uf_sw_w, uf_sw_b, grp, gate, grp_cnt);
  build_offsets_k<<<1,1,0,stream>>>(grp_cnt, grp_off, tile_g, tile_r, ntile);
  scatter_k<<<32,256,0,stream>>>(grp, gate, grp_off, fill, tok_idx, gate_s);

  // ---- unique FFN (grouped, top-1 inner expert, gated scatter-add) ----
  gemm_bf16_k<1,0,true,true><<<dim3(24,80),256,0,stream>>>((const void*)att, w1T + 2359296, uf_b1, nullptr, h1,
      NTq, Fq, Dq, tile_g, tile_r, grp_off, ntile, tok_idx, gate_s, (size_t)2359296, Fq);
  gemm_bf16_k<2,2,false,true><<<dim3(6,80),256,0,stream>>>((const void*)h1, w2T + 2359296, uf_b2, facc, nullptr,
      NTq, Dq, Fq, tile_g, tile_r, grp_off, ntile, tok_idx, gate_s, (size_t)2359296, Dq);

  // ---- residual + LayerNorm ----
  final_ln_k<<<NTq,256,0,stream>>>(att, facc, ln_g, ln_b, out);
}

// Round 4
// 1287.637 us; speedup vs baseline: 1.8362x; 1.2557x over previous
//
#include <hip/hip_runtime.h>
#include <cstdint>
#include <cstddef>

#define Bq  16
#define Sq  512
#define Dq  768
#define Hq  12
#define DHq 64
#define Fq  3072
#define SWq 128
#define NTq 8192

typedef float        f32x4  __attribute__((ext_vector_type(4)));
typedef float        f32x16 __attribute__((ext_vector_type(16)));
typedef unsigned int u32x4  __attribute__((ext_vector_type(4)));
typedef __bf16       bf16x8 __attribute__((ext_vector_type(8)));
typedef _Float16     f16x8  __attribute__((ext_vector_type(8)));
typedef _Float16     f16x4  __attribute__((ext_vector_type(4)));
typedef _Float16     f16x2  __attribute__((ext_vector_type(2)));
typedef int          i32x2  __attribute__((ext_vector_type(2)));

__device__ __forceinline__ unsigned short f2bf(float f){
  unsigned int u = __builtin_bit_cast(unsigned int, f);
  u = (u + 0x7fffu + ((u >> 16) & 1u)) >> 16;
  return (unsigned short)u;
}
__device__ __forceinline__ unsigned int pk2(float a, float b){
  return (unsigned int)f2bf(a) | ((unsigned int)f2bf(b) << 16);
}
__device__ __forceinline__ i32x2 pl32swap(unsigned int a, unsigned int b){
  return __builtin_amdgcn_permlane32_swap((int)a, (int)b, false, false);
}
__device__ __forceinline__ f16x2 cvt_pk(float a, float b){
  return __builtin_bit_cast(f16x2, __builtin_amdgcn_cvt_pkrtz(a, b));
}

// ---------------- pooled partial sums (seq router input) ----------------
__global__ void pooled_partial_k(const float* __restrict__ x, float* __restrict__ part){
  const int b = blockIdx.x, dc = blockIdx.y, z = blockIdx.z;
  const int d = dc*256 + threadIdx.x;
  const float* p = x + (size_t)b*Sq*Dq + (size_t)z*128*Dq + d;
  float s = 0.f;
  #pragma unroll 4
  for (int i = 0; i < 128; i++) s += p[(size_t)i*Dq];
  part[((size_t)z*Bq + b)*Dq + d] = s;
}

// ---------------- sequence-level router (exact f32) ----------------
__global__ void router_seq_k(const float* __restrict__ part,
    const float* __restrict__ ew, const float* __restrict__ eb,
    const float* __restrict__ sw, const float* __restrict__ sb,
    int* __restrict__ sel, float* __restrict__ pm)
{
  const int b = blockIdx.x, j = threadIdx.x;   // 128 threads
  __shared__ float h[SWq];
  __shared__ float pl[Dq];
  #pragma unroll
  for (int i = 0; i < 6; i++){
    int d = j + i*128;
    float s = part[(size_t)(0*Bq+b)*Dq + d] + part[(size_t)(1*Bq+b)*Dq + d]
            + part[(size_t)(2*Bq+b)*Dq + d] + part[(size_t)(3*Bq+b)*Dq + d];
    pl[d] = s * (1.0f/512.0f);
  }
  __syncthreads();
  float a = eb[j];
  for (int d = 0; d < Dq; d++) a += pl[d] * ew[d*SWq + j];
  h[j] = a;
  __syncthreads();
  if (j == 0){
    float lg[4];
    for (int e = 0; e < 4; e++){
      float t = sb[e];
      for (int k = 0; k < SWq; k++) t += h[k] * sw[k*4 + e];
      lg[e] = t;
    }
    float mx = fmaxf(fmaxf(lg[0],lg[1]), fmaxf(lg[2],lg[3]));
    float p[4], ssum = 0.f;
    for (int e = 0; e < 4; e++){ p[e] = expf(lg[e]-mx); ssum += p[e]; }
    int am = 0; float bv = p[0];
    for (int e = 1; e < 4; e++) if (p[e] > bv){ bv = p[e]; am = e; }
    sel[b] = am; pm[b] = bv/ssum;
  }
}

// ---------------- f32 -> f16 hi/lo split (x1024 scale) ----------------
__global__ void split_f16_k(const float* __restrict__ x, _Float16* __restrict__ hh,
                            _Float16* __restrict__ ll, int n4){
  const int i = blockIdx.x*256 + threadIdx.x;
  if (i >= n4) return;
  f32x4 v = ((const f32x4*)x)[i];
  f16x4 vh, vl;
  #pragma unroll
  for (int j = 0; j < 4; j++){
    float s = v[j] * 1024.0f;
    _Float16 a = (_Float16)s;
    vh[j] = a;
    vl[j] = (_Float16)(s - (float)a);
  }
  ((f16x4*)hh)[i] = vh;
  ((f16x4*)ll)[i] = vl;
}

// ------- weight transpose + f16 hi/lo split: src [K][N] -> dst [N][K] x1024 -------
__global__ void transpose_f16s_k(const float* __restrict__ src,
    _Float16* __restrict__ dH, _Float16* __restrict__ dL,
    int K, int N, long srcStride, long dstStride, int rowOff)
{
  __shared__ float t[64][65];
  const int tid = threadIdx.x;
  const size_t so = (size_t)blockIdx.z * srcStride;
  const size_t dof = (size_t)blockIdx.z * dstStride;
  const int k0 = blockIdx.y * 64, n0 = blockIdx.x * 64;
  const int r = tid >> 2, c0 = (tid & 3) * 16;
  const float* sp = src + so + (size_t)(k0 + r) * N + n0 + c0;
  #pragma unroll
  for (int cc = 0; cc < 16; cc += 4){
    f32x4 v = *(const f32x4*)(sp + cc);
    t[r][c0+cc] = v[0]; t[r][c0+cc+1] = v[1]; t[r][c0+cc+2] = v[2]; t[r][c0+cc+3] = v[3];
  }
  __syncthreads();
  _Float16* ph = dH + dof + (size_t)(rowOff + n0 + r) * K + k0 + c0;
  _Float16* pl = dL + dof + (size_t)(rowOff + n0 + r) * K + k0 + c0;
  #pragma unroll
  for (int cc = 0; cc < 16; cc += 4){
    f16x4 vh, vl;
    #pragma unroll
    for (int j = 0; j < 4; j++){
      float s = t[c0+cc+j][r] * 1024.0f;
      _Float16 a = (_Float16)s;
      vh[j] = a; vl[j] = (_Float16)(s - (float)a);
    }
    *(f16x4*)(ph + cc) = vh;
    *(f16x4*)(pl + cc) = vl;
  }
}

// ---------------- concat q/k/v biases -> [E][2304] ----------------
__global__ void concat_bias3_k(const float* __restrict__ bq, const float* __restrict__ bk,
    const float* __restrict__ bv, float* __restrict__ dst, int srcStride)
{
  const int e = blockIdx.y;
  const int i = blockIdx.x*256 + threadIdx.x;   // grid.x=3 -> i<768
  dst[(size_t)e*2304 + i]        = bq[(size_t)e*srcStride + i];
  dst[(size_t)e*2304 + 768 + i]  = bk[(size_t)e*srcStride + i];
  dst[(size_t)e*2304 + 1536 + i] = bv[(size_t)e*srcStride + i];
}

// ---------------- split-f16 3-term MFMA GEMM (~f32 accuracy) ----------------
// A = (AH+AL)/1024 [M][K], B^T = (BH+BL)/1024 [N][K]; C = A@B + bias
// BMODE: 0 shared B; 1 per-sequence expert.
// OMODE: 0 C=v (f32); 1 C += pm*v (f32); 2 split-f16 x1024 store to Ch/Cl
template<int BMODE, int OMODE>
__global__ __launch_bounds__(256,2) void gemm_f16s_k(
    const _Float16* __restrict__ AH, const _Float16* __restrict__ AL,
    const _Float16* __restrict__ BH, const _Float16* __restrict__ BL,
    const float* __restrict__ bias, float* __restrict__ C,
    _Float16* __restrict__ Ch, _Float16* __restrict__ Cl,
    int N, int K, long estride, int bias_stride,
    const int* __restrict__ sel, const float* __restrict__ pm)
{
  __shared__ _Float16 AsH[128][40];
  __shared__ _Float16 AsL[128][40];
  __shared__ _Float16 BsH[128][40];
  __shared__ _Float16 BsL[128][40];
  const int tid = threadIdx.x;
  const int lane = tid & 63, wave = tid >> 6;
  const int wm = wave >> 1, wn = wave & 1;
  const int row0 = blockIdx.y * 128, col0 = blockIdx.x * 128;
  const _Float16* bh = BH; const _Float16* bl = BL; const float* bp = bias;
  float cs = 1.0f;
  if constexpr (BMODE == 1){
    const int e = sel[row0 >> 9];
    bh += (size_t)e * estride; bl += (size_t)e * estride;
    bp += (size_t)e * bias_stride;
  }
  if constexpr (OMODE == 1) cs = pm[row0 >> 9];

  const int sr = tid >> 1, sk = (tid & 1) * 16;
  const _Float16* ahp = AH + (size_t)(row0 + sr) * K + sk;
  const _Float16* alp = AL + (size_t)(row0 + sr) * K + sk;
  const _Float16* bhp = bh + (size_t)(col0 + sr) * K + sk;
  const _Float16* blp = bl + (size_t)(col0 + sr) * K + sk;

  f32x4 acc[4][4];
  #pragma unroll
  for (int mi=0;mi<4;mi++)
    #pragma unroll
    for (int ni=0;ni<4;ni++) acc[mi][ni] = (f32x4){0.f,0.f,0.f,0.f};

  for (int k0 = 0; k0 < K; k0 += 32){
    u32x4 vah0 = *(const u32x4*)(ahp + k0);
    u32x4 vah1 = *(const u32x4*)(ahp + k0 + 8);
    u32x4 val0 = *(const u32x4*)(alp + k0);
    u32x4 val1 = *(const u32x4*)(alp + k0 + 8);
    u32x4 vbh0 = *(const u32x4*)(bhp + k0);
    u32x4 vbh1 = *(const u32x4*)(bhp + k0 + 8);
    u32x4 vbl0 = *(const u32x4*)(blp + k0);
    u32x4 vbl1 = *(const u32x4*)(blp + k0 + 8);
    __syncthreads();
    *(u32x4*)&AsH[sr][sk]   = vah0; *(u32x4*)&AsH[sr][sk+8] = vah1;
    *(u32x4*)&AsL[sr][sk]   = val0; *(u32x4*)&AsL[sr][sk+8] = val1;
    *(u32x4*)&BsH[sr][sk]   = vbh0; *(u32x4*)&BsH[sr][sk+8] = vbh1;
    *(u32x4*)&BsL[sr][sk]   = vbl0; *(u32x4*)&BsL[sr][sk+8] = vbl1;
    __syncthreads();
    f16x8 fah[4], fal[4], fbh[4], fbl[4];
    #pragma unroll
    for (int mi=0;mi<4;mi++){
      const int r = wm*64 + mi*16 + (lane&15), c = 8*(lane>>4);
      fah[mi] = __builtin_bit_cast(f16x8, *(const u32x4*)&AsH[r][c]);
      fal[mi] = __builtin_bit_cast(f16x8, *(const u32x4*)&AsL[r][c]);
    }
    #pragma unroll
    for (int ni=0;ni<4;ni++){
      const int r = wn*64 + ni*16 + (lane&15), c = 8*(lane>>4);
      fbh[ni] = __builtin_bit_cast(f16x8, *(const u32x4*)&BsH[r][c]);
      fbl[ni] = __builtin_bit_cast(f16x8, *(const u32x4*)&BsL[r][c]);
    }
    #pragma unroll
    for (int mi=0;mi<4;mi++)
      #pragma unroll
      for (int ni=0;ni<4;ni++){
        acc[mi][ni] = __builtin_amdgcn_mfma_f32_16x16x32_f16(fah[mi], fbh[ni], acc[mi][ni], 0, 0, 0);
        acc[mi][ni] = __builtin_amdgcn_mfma_f32_16x16x32_f16(fah[mi], fbl[ni], acc[mi][ni], 0, 0, 0);
        acc[mi][ni] = __builtin_amdgcn_mfma_f32_16x16x32_f16(fal[mi], fbh[ni], acc[mi][ni], 0, 0, 0);
      }
  }

  const float INV = 1.0f/1048576.0f;   // undo 1024*1024 scaling (exact pow2)
  const int erow = 4*(lane >> 4);
  const int ecol = lane & 15;
  #pragma unroll
  for (int mi=0;mi<4;mi++)
    #pragma unroll
    for (int ni=0;ni<4;ni++){
      const int c = col0 + wn*64 + ni*16 + ecol;
      const float bb = bp[c];
      #pragma unroll
      for (int r=0;r<4;r++){
        const int R = row0 + wm*64 + mi*16 + erow + r;
        const float v = acc[mi][ni][r]*INV + bb;
        if constexpr (OMODE == 0){
          C[(size_t)R*N + c] = v;
        } else if constexpr (OMODE == 1){
          C[(size_t)R*N + c] += cs*v;
        } else {
          const float vs = v * 1024.0f;
          const _Float16 hi = (_Float16)vs;
          Ch[(size_t)R*N + c] = hi;
          Cl[(size_t)R*N + c] = (_Float16)(vs - (float)hi);
        }
      }
    }
}

// ------- split-f16 MFMA attention (swapped-QK, in-register softmax) -------
// QKV in split-f16 x1024: [8192][2304] (Q|K|V). ctx out split-f16 x1024.
__global__ __launch_bounds__(256,2) void attn_mfma_k(
    const _Float16* __restrict__ qkvH, const _Float16* __restrict__ qkvL,
    const float* __restrict__ mask,
    _Float16* __restrict__ ctxH, _Float16* __restrict__ ctxL)
{
  __shared__ _Float16 Kh[64][72], Kl[64][72];
  __shared__ _Float16 Vh[64][72], Vl[64][72];   // transposed: [d][k]
  __shared__ float msk[64];
  __shared__ float rsi[4][32];
  const int qb = blockIdx.x, h = blockIdx.y, b = blockIdx.z;
  const int tid = threadIdx.x;
  const int l = tid & 63, w = tid >> 6;
  const int l31 = l & 31, g5 = l >> 5;
  const float SC = 1.0f/8388608.0f;   // 2^-20 (split scale) * 1/8 (1/sqrt(64))

  // Q B-fragments (persistent): col=q=lane&31, k=d=c*16+g5*8+j
  u32x4 qfh[4], qfl[4];
  {
    const size_t qoff = (size_t)(b*Sq + qb*128 + w*32 + l31) * 2304 + h*DHq + g5*8;
    #pragma unroll
    for (int c = 0; c < 4; c++){
      qfh[c] = *(const u32x4*)(qkvH + qoff + c*16);
      qfl[c] = *(const u32x4*)(qkvL + qoff + c*16);
    }
  }
  f32x16 oacc[2];
  #pragma unroll
  for (int nt = 0; nt < 2; nt++)
    #pragma unroll
    for (int i = 0; i < 16; i++) oacc[nt][i] = 0.f;
  float rsl = 0.f;
  const float* mrow = mask + b*Sq;

  for (int kt = 0; kt < 8; kt++){
    __syncthreads();
    // ---- stage K (natural) and V (transposed) tiles, hi+lo ----
    {
      const size_t krow = (size_t)(b*Sq + kt*64 + l) * 2304 + 768 + h*DHq;
      #pragma unroll
      for (int i = 0; i < 2; i++){
        const int ch = w + i*4;           // 8 x 16B chunks per row
        *(u32x4*)&Kh[l][ch*8] = *(const u32x4*)(qkvH + krow + ch*8);
        *(u32x4*)&Kl[l][ch*8] = *(const u32x4*)(qkvL + krow + ch*8);
      }
      const size_t vrow = krow + 768 + w*16;
      f16x8 v0 = __builtin_bit_cast(f16x8, *(const u32x4*)(qkvH + vrow));
      f16x8 v1 = __builtin_bit_cast(f16x8, *(const u32x4*)(qkvH + vrow + 8));
      f16x8 u0 = __builtin_bit_cast(f16x8, *(const u32x4*)(qkvL + vrow));
      f16x8 u1 = __builtin_bit_cast(f16x8, *(const u32x4*)(qkvL + vrow + 8));
      #pragma unroll
      for (int i = 0; i < 8; i++){
        Vh[w*16 + i][l] = v0[i]; Vh[w*16 + 8 + i][l] = v1[i];
        Vl[w*16 + i][l] = u0[i]; Vl[w*16 + 8 + i][l] = u1[i];
      }
      if (tid < 64) msk[tid] = mrow[kt*64 + tid] + 6.9314718055994531f; // + ln(1024)
    }
    __syncthreads();

    // ---- S^T = K · Q^T (rows = kcol, cols = q) ----
    f32x16 sacc[2];
    #pragma unroll
    for (int mt = 0; mt < 2; mt++)
      #pragma unroll
      for (int i = 0; i < 16; i++) sacc[mt][i] = 0.f;
    #pragma unroll
    for (int mt = 0; mt < 2; mt++){
      #pragma unroll
      for (int c = 0; c < 4; c++){
        f16x8 kh = __builtin_bit_cast(f16x8, *(const u32x4*)&Kh[mt*32 + l31][c*16 + g5*8]);
        f16x8 kl = __builtin_bit_cast(f16x8, *(const u32x4*)&Kl[mt*32 + l31][c*16 + g5*8]);
        f16x8 qh = __builtin_bit_cast(f16x8, qfh[c]);
        f16x8 ql = __builtin_bit_cast(f16x8, qfl[c]);
        sacc[mt] = __builtin_amdgcn_mfma_f32_32x32x16_f16(kh, qh, sacc[mt], 0, 0, 0);
        sacc[mt] = __builtin_amdgcn_mfma_f32_32x32x16_f16(kh, ql, sacc[mt], 0, 0, 0);
        sacc[mt] = __builtin_amdgcn_mfma_f32_32x32x16_f16(kl, qh, sacc[mt], 0, 0, 0);
      }
    }

    // ---- softmax numerator p = exp(s)*1024, split-pack to f16 hi/lo ----
    unsigned int hP[2][4][2], lP[2][4][2];
    #pragma unroll
    for (int mt = 0; mt < 2; mt++){
      #pragma unroll
      for (int m = 0; m < 4; m++){
        f32x4 mk = *(const f32x4*)&msk[mt*32 + m*8 + g5*4];
        float p0 = __expf(fmaf(sacc[mt][4*m+0], SC, mk[0]));
        float p1 = __expf(fmaf(sacc[mt][4*m+1], SC, mk[1]));
        float p2 = __expf(fmaf(sacc[mt][4*m+2], SC, mk[2]));
        float p3 = __expf(fmaf(sacc[mt][4*m+3], SC, mk[3]));
        rsl += (p0 + p1) + (p2 + p3);
        f16x2 h0 = cvt_pk(p0, p1);
        f16x2 h1 = cvt_pk(p2, p3);
        f16x2 e0, e1;
        e0[0] = (_Float16)(p0 - (float)h0[0]); e0[1] = (_Float16)(p1 - (float)h0[1]);
        e1[0] = (_Float16)(p2 - (float)h1[0]); e1[1] = (_Float16)(p3 - (float)h1[1]);
        hP[mt][m][0] = __builtin_bit_cast(unsigned int, h0);
        hP[mt][m][1] = __builtin_bit_cast(unsigned int, h1);
        lP[mt][m][0] = __builtin_bit_cast(unsigned int, e0);
        lP[mt][m][1] = __builtin_bit_cast(unsigned int, e1);
      }
    }

    // ---- O += P · V  (A-fragments assembled via permlane32_swap) ----
    #pragma unroll
    for (int mt = 0; mt < 2; mt++){
      #pragma unroll
      for (int cc = 0; cc < 2; cc++){
        i32x2 sh0 = pl32swap(hP[mt][2*cc][0], hP[mt][2*cc+1][0]);
        i32x2 sh1 = pl32swap(hP[mt][2*cc][1], hP[mt][2*cc+1][1]);
        i32x2 sl0 = pl32swap(lP[mt][2*cc][0], lP[mt][2*cc+1][0]);
        i32x2 sl1 = pl32swap(lP[mt][2*cc][1], lP[mt][2*cc+1][1]);
        u32x4 pah = (u32x4){(unsigned)sh0[0], (unsigned)sh1[0], (unsigned)sh0[1], (unsigned)sh1[1]};
        u32x4 pal = (u32x4){(unsigned)sl0[0], (unsigned)sl1[0], (unsigned)sl0[1], (unsigned)sl1[1]};
        f16x8 ph = __builtin_bit_cast(f16x8, pah);
        f16x8 pe = __builtin_bit_cast(f16x8, pal);
        const int kof = (mt*2 + cc)*16 + g5*8;
        #pragma unroll
        for (int nt = 0; nt < 2; nt++){
          f16x8 vh = __builtin_bit_cast(f16x8, *(const u32x4*)&Vh[nt*32 + l31][kof]);
          f16x8 vl = __builtin_bit_cast(f16x8, *(const u32x4*)&Vl[nt*32 + l31][kof]);
          oacc[nt] = __builtin_amdgcn_mfma_f32_32x32x16_f16(ph, vh, oacc[nt], 0, 0, 0);
          oacc[nt] = __builtin_amdgcn_mfma_f32_32x32x16_f16(ph, vl, oacc[nt], 0, 0, 0);
          oacc[nt] = __builtin_amdgcn_mfma_f32_32x32x16_f16(pe, vh, oacc[nt], 0, 0, 0);
        }
      }
    }
  }

  // ---- row-sum total (lane + partner lane across 32-halves), reciprocal ----
  {
    unsigned int rb = __builtin_bit_cast(unsigned int, rsl);
    i32x2 sw = pl32swap(rb, rb);
    float partner = __builtin_bit_cast(float, (l >= 32) ? sw[0] : sw[1]);
    float tot = rsl + partner;
    if (l < 32) rsi[w][l31] = 1.0f / tot;
  }
  __syncthreads();

  // ---- epilogue: divide, split-f16 store (x1024 kept: o_store = acc/rs) ----
  const size_t obase = (size_t)(b*Sq + qb*128 + w*32);
  #pragma unroll
  for (int nt = 0; nt < 2; nt++){
    const int col = h*DHq + nt*32 + l31;
    #pragma unroll
    for (int r = 0; r < 16; r++){
      const int q = (r&3) + 8*(r>>2) + 4*g5;
      const float v = oacc[nt][r] * rsi[w][q];
      const _Float16 hi = (_Float16)v;
      const size_t off = (obase + q)*Dq + col;
      ctxH[off] = hi;
      ctxL[off] = (_Float16)(v - (float)hi);
    }
  }
}

// ---------------- transpose + f32->bf16 (FFN weights -> [N][K] bf16) ----------------
__global__ void transpose_bf16_k(const float* __restrict__ src, unsigned short* __restrict__ dst,
                                 int K, int N)
{
  __shared__ float t[64][65];
  const int tid = threadIdx.x;
  const size_t mo = (size_t)blockIdx.z * K * N;
  const int k0 = blockIdx.y * 64, n0 = blockIdx.x * 64;
  const int r = tid >> 2, c0 = (tid & 3) * 16;
  const float* sp = src + mo + (size_t)(k0 + r) * N + n0 + c0;
  #pragma unroll
  for (int cc = 0; cc < 16; cc += 4){
    f32x4 v = *(const f32x4*)(sp + cc);
    t[r][c0+cc] = v[0]; t[r][c0+cc+1] = v[1]; t[r][c0+cc+2] = v[2]; t[r][c0+cc+3] = v[3];
  }
  __syncthreads();
  unsigned short* dp = dst + mo + (size_t)(n0 + r) * K + k0 + c0;
  u32x4 h0, h1v;
  #pragma unroll
  for (int i = 0; i < 4; i++) h0[i]  = pk2(t[c0+2*i  ][r], t[c0+2*i+1][r]);
  #pragma unroll
  for (int i = 0; i < 4; i++) h1v[i] = pk2(t[c0+8+2*i][r], t[c0+9+2*i][r]);
  *(u32x4*)(dp)     = h0;
  *(u32x4*)(dp + 8) = h1v;
}

// ---------------- bf16 MFMA GEMM (FFN path) ----------------
// AMODE: 0 f32 rows; 1 f32 rows via tok_idx; 2 bf16 rows
// OMODE: 0 bf16 store (h1); 1 f32 write+bias; 2 f32 scatter add gate*(res+bias)
template<int AMODE, int OMODE, bool GELU_, bool GROUPED>
__global__ __launch_bounds__(256,2) void gemm_bf16_k(
    const void* __restrict__ Av, const unsigned short* __restrict__ BT,
    const float* __restrict__ bias, float* __restrict__ Cf, unsigned short* __restrict__ Cb,
    int M, int N, int K,
    const int* __restrict__ tile_g, const int* __restrict__ tile_r0,
    const int* __restrict__ grp_off, const int* __restrict__ n_tiles,
    const int* __restrict__ tok_idx, const float* __restrict__ gate_s,
    size_t bstride, int bias_stride)
{
  __shared__ unsigned short As[128][40];
  __shared__ unsigned short Bs[128][40];
  const int tid = threadIdx.x;
  const int lane = tid & 63, wave = tid >> 6;
  const int wm = wave >> 1, wn = wave & 1;
  const int col0 = blockIdx.x * 128;
  int row0, gend = 1 << 30, g = 0;
  if constexpr (GROUPED){
    const int t = blockIdx.y;
    if (t >= *n_tiles) return;
    g = tile_g[t];
    row0 = grp_off[g] + tile_r0[t];
    gend = grp_off[g+1];
  } else {
    row0 = blockIdx.y * 128;
  }
  const unsigned short* Bp = BT + (size_t)g * bstride;
  const float* bp = bias + (size_t)g * bias_stride;

  const int sr = tid >> 1;
  const int sk = (tid & 1) * 16;
  int arow = row0 + sr;
  if constexpr (GROUPED) arow = (arow < gend - 1) ? arow : (gend - 1);
  if constexpr (AMODE == 1) arow = tok_idx[arow];
  const float*          afp = (const float*)Av          + (size_t)arow * K + sk;
  const unsigned short* abp = (const unsigned short*)Av + (size_t)arow * K + sk;
  const unsigned short* bfp = Bp + (size_t)(col0 + sr) * K + sk;

  f32x4 acc[4][4];
  #pragma unroll
  for (int mi=0;mi<4;mi++)
    #pragma unroll
    for (int ni=0;ni<4;ni++) acc[mi][ni] = (f32x4){0.f,0.f,0.f,0.f};

  for (int k0 = 0; k0 < K; k0 += 32){
    u32x4 bl0 = *(const u32x4*)(bfp + k0);
    u32x4 bl1 = *(const u32x4*)(bfp + k0 + 8);
    u32x4 al0, al1;
    if constexpr (AMODE == 2){
      al0 = *(const u32x4*)(abp + k0);
      al1 = *(const u32x4*)(abp + k0 + 8);
    } else {
      f32x4 f0 = *(const f32x4*)(afp + k0);
      f32x4 f1 = *(const f32x4*)(afp + k0 + 4);
      f32x4 f2 = *(const f32x4*)(afp + k0 + 8);
      f32x4 f3 = *(const f32x4*)(afp + k0 + 12);
      al0[0]=pk2(f0[0],f0[1]); al0[1]=pk2(f0[2],f0[3]); al0[2]=pk2(f1[0],f1[1]); al0[3]=pk2(f1[2],f1[3]);
      al1[0]=pk2(f2[0],f2[1]); al1[1]=pk2(f2[2],f2[3]); al1[2]=pk2(f3[0],f3[1]); al1[3]=pk2(f3[2],f3[3]);
    }
    __syncthreads();
    *(u32x4*)&As[sr][sk]     = al0;
    *(u32x4*)&As[sr][sk + 8] = al1;
    *(u32x4*)&Bs[sr][sk]     = bl0;
    *(u32x4*)&Bs[sr][sk + 8] = bl1;
    __syncthreads();
    bf16x8 af[4], bfr[4];
    #pragma unroll
    for (int mi=0;mi<4;mi++){
      u32x4 t = *(const u32x4*)&As[wm*64 + mi*16 + (lane&15)][8*(lane>>4)];
      af[mi] = __builtin_bit_cast(bf16x8, t);
    }
    #pragma unroll
    for (int ni=0;ni<4;ni++){
      u32x4 t = *(const u32x4*)&Bs[wn*64 + ni*16 + (lane&15)][8*(lane>>4)];
      bfr[ni] = __builtin_bit_cast(bf16x8, t);
    }
    #pragma unroll
    for (int mi=0;mi<4;mi++)
      #pragma unroll
      for (int ni=0;ni<4;ni++)
        acc[mi][ni] = __builtin_amdgcn_mfma_f32_16x16x32_bf16(af[mi], bfr[ni], acc[mi][ni], 0, 0, 0);
  }

  const int erow = 4*(lane >> 4);
  const int ecol = lane & 15;
  #pragma unroll
  for (int mi=0;mi<4;mi++)
    #pragma unroll
    for (int ni=0;ni<4;ni++){
      const int c = col0 + wn*64 + ni*16 + ecol;
      const float bb = bp[c];
      #pragma unroll
      for (int r=0;r<4;r++){
        const int R = row0 + wm*64 + mi*16 + erow + r;
        if (GROUPED && R >= gend) continue;
        float v = acc[mi][ni][r] + bb;
        if (GELU_) v = 0.5f*v*(1.0f + erff(v*0.70710678118654752f));
        if constexpr (OMODE == 0){
          Cb[(size_t)R*N + c] = f2bf(v);
        } else if constexpr (OMODE == 1){
          Cf[(size_t)R*N + c] = v;
        } else {
          const int tok = tok_idx[R];
          const float gt = gate_s[R];
          float* p = Cf + (size_t)tok*N + c;
          *p += gt*v;
        }
      }
    }
}

// ---------------- token-level switch router (f32, one wave/token) ----------------
__global__ void token_router_k(const float* __restrict__ att, const int* __restrict__ sel,
    const float* __restrict__ sww, const float* __restrict__ swb,
    int* __restrict__ grp, float* __restrict__ gate, int* __restrict__ grp_cnt)
{
  const int t = blockIdx.x*4 + (threadIdx.x >> 6);
  const int lane = threadIdx.x & 63;
  const int e = sel[t >> 9];
  const float* x = att + (size_t)t * Dq;
  const float* w = sww + (size_t)e * Dq * 4;
  float a0=0.f, a1=0.f, a2=0.f, a3=0.f;
  #pragma unroll 4
  for (int i = 0; i < 12; i++){
    const int d = lane + i*64;
    const float xv = x[d];
    f32x4 wv = *(const f32x4*)&w[d*4];
    a0 += xv*wv[0]; a1 += xv*wv[1]; a2 += xv*wv[2]; a3 += xv*wv[3];
  }
  #pragma unroll
  for (int off = 32; off; off >>= 1){
    a0 += __shfl_xor(a0, off); a1 += __shfl_xor(a1, off);
    a2 += __shfl_xor(a2, off); a3 += __shfl_xor(a3, off);
  }
  if (lane == 0){
    const float l0 = a0 + swb[e*4+0], l1 = a1 + swb[e*4+1];
    const float l2 = a2 + swb[e*4+2], l3 = a3 + swb[e*4+3];
    const float mx = fmaxf(fmaxf(l0,l1), fmaxf(l2,l3));
    const float p0 = expf(l0-mx), p1 = expf(l1-mx), p2 = expf(l2-mx), p3 = expf(l3-mx);
    const float ssum = p0+p1+p2+p3;
    int am = 0; float bv = p0;
    if (p1 > bv){ bv=p1; am=1; }
    if (p2 > bv){ bv=p2; am=2; }
    if (p3 > bv){ bv=p3; am=3; }
    grp[t] = e*4 + am;
    gate[t] = bv/ssum;
    atomicAdd(&grp_cnt[e*4 + am], 1);
  }
}

__global__ void build_offsets_k(const int* __restrict__ grp_cnt, int* __restrict__ grp_off,
    int* __restrict__ tile_g, int* __restrict__ tile_r0, int* __restrict__ n_tiles)
{
  int off = 0, nt = 0;
  for (int g = 0; g < 16; g++){
    grp_off[g] = off;
    const int c = grp_cnt[g];
    for (int r0 = 0; r0 < c; r0 += 128){ tile_g[nt] = g; tile_r0[nt] = r0; nt++; }
    off += c;
  }
  grp_off[16] = off;
  *n_tiles = nt;
}

__global__ void scatter_k(const int* __restrict__ grp, const float* __restrict__ gate,
    const int* __restrict__ grp_off, int* __restrict__ fill,
    int* __restrict__ tok_idx, float* __restrict__ gate_s)
{
  const int t = blockIdx.x*256 + threadIdx.x;
  const int g = grp[t];
  const int pos = grp_off[g] + atomicAdd(&fill[g], 1);
  tok_idx[pos] = t;
  gate_s[pos] = gate[t];
}

// ---------------- final residual-add + LayerNorm ----------------
__global__ __launch_bounds__(256) void final_ln_k(const float* __restrict__ att,
    const float* __restrict__ acc, const float* __restrict__ lg,
    const float* __restrict__ lb, float* __restrict__ out)
{
  const int row = blockIdx.x, tid = threadIdx.x;
  const float* a = att + (size_t)row * Dq;
  const float* c = acc + (size_t)row * Dq;
  float x[3];
  #pragma unroll
  for (int i = 0; i < 3; i++) x[i] = a[tid + 256*i] + c[tid + 256*i];
  __shared__ float red[256];
  red[tid] = x[0] + x[1] + x[2];
  __syncthreads();
  for (int st = 128; st; st >>= 1){
    if (tid < st) red[tid] += red[tid + st];
    __syncthreads();
  }
  const float mu = red[0] * (1.0f/768.0f);
  __syncthreads();
  const float d0 = x[0]-mu, d1 = x[1]-mu, d2 = x[2]-mu;
  red[tid] = d0*d0 + d1*d1 + d2*d2;
  __syncthreads();
  for (int st = 128; st; st >>= 1){
    if (tid < st) red[tid] += red[tid + st];
    __syncthreads();
  }
  const float inv = 1.0f/sqrtf(red[0]*(1.0f/768.0f) + 1e-12f);
  #pragma unroll
  for (int i = 0; i < 3; i++){
    const int col = tid + 256*i;
    out[(size_t)row*Dq + col] = (x[i]-mu)*inv*lg[col] + lb[col];
  }
}

// ======================= launch =======================
extern "C" void kernel_launch(void* const* d_in, const int* in_sizes, int n_in,
                              void* d_out, int out_size, void* d_ws, size_t ws_size,
                              hipStream_t stream)
{
  (void)in_sizes; (void)n_in; (void)out_size; (void)ws_size;
  const float* hs    = (const float*)d_in[0];
  const float* amask = (const float*)d_in[1];
  const float* sw_enc_w = (const float*)d_in[3];
  const float* sw_enc_b = (const float*)d_in[4];
  const float* sw_w  = (const float*)d_in[5];
  const float* sw_b  = (const float*)d_in[6];
  const float* ca_wq = (const float*)d_in[7];
  const float* ca_bq = (const float*)d_in[8];
  const float* ca_wk = (const float*)d_in[9];
  const float* ca_bk = (const float*)d_in[10];
  const float* ca_wv = (const float*)d_in[11];
  const float* ca_bv = (const float*)d_in[12];
  const float* ca_wo = (const float*)d_in[13];
  const float* ca_bo = (const float*)d_in[14];
  const float* ua_wq = (const float*)d_in[15];
  const float* ua_bq = (const float*)d_in[16];
  const float* ua_wk = (const float*)d_in[17];
  const float* ua_bk = (const float*)d_in[18];
  const float* ua_wv = (const float*)d_in[19];
  const float* ua_bv = (const float*)d_in[20];
  const float* ua_wo = (const float*)d_in[21];
  const float* ua_bo = (const float*)d_in[22];
  const float* cf_w1 = (const float*)d_in[23];
  const float* cf_b1 = (const float*)d_in[24];
  const float* cf_w2 = (const float*)d_in[25];
  const float* cf_b2 = (const float*)d_in[26];
  const float* uf_sw_w = (const float*)d_in[27];
  const float* uf_sw_b = (const float*)d_in[28];
  const float* uf_w1 = (const float*)d_in[29];
  const float* uf_b1 = (const float*)d_in[30];
  const float* uf_w2 = (const float*)d_in[31];
  const float* uf_b2 = (const float*)d_in[32];
  const float* ln_g  = (const float*)d_in[33];
  const float* ln_b  = (const float*)d_in[34];
  float* out = (float*)d_out;

  char* W = (char*)d_ws;
  // control block (zeroed each launch)
  int*   sel     = (int*)(W + 0);
  float* pm      = (float*)(W + 64);
  int*   grp_cnt = (int*)(W + 128);
  int*   fill    = (int*)(W + 192);
  int*   ntile   = (int*)(W + 256);
  int*   grp_off = (int*)(W + 512);
  int*   tile_g  = (int*)(W + 1024);
  int*   tile_r  = (int*)(W + 2048);

  float* att  = (float*)(W + 4096);             // [8192][768] f32
  float* facc = (float*)(W + 25169920);         // [8192][768] f32
  const size_t X = 50335744;
  _Float16* hsH  = (_Float16*)(W + X);                 // 12,582,912
  _Float16* hsL  = (_Float16*)(W + X + 12582912);
  _Float16* qkvH = (_Float16*)(W + X + 25165824);      // 37,748,736
  _Float16* qkvL = (_Float16*)(W + X + 62914560);      // end X+100663296
  _Float16* ctxH = (_Float16*)(W + X + 100663296);     // 12,582,912
  _Float16* ctxL = (_Float16*)(W + X + 113246208);     // end X+125829120
  _Float16* wqkv_cH = (_Float16*)(W + X + 125829120);  // 3,538,944
  _Float16* wqkv_cL = (_Float16*)(W + X + 129368064);
  _Float16* wqkv_uH = (_Float16*)(W + X + 132907008);  // 14,155,776
  _Float16* wqkv_uL = (_Float16*)(W + X + 147062784);
  _Float16* wo_cH   = (_Float16*)(W + X + 161218560);  // 1,179,648
  _Float16* wo_cL   = (_Float16*)(W + X + 162398208);
  _Float16* wo_uH   = (_Float16*)(W + X + 163577856);  // 4,718,592
  _Float16* wo_uL   = (_Float16*)(W + X + 168296448);  // end X+173015040
  float* qkvb_c = (float*)(W + X + 173015040);         // 9,216
  float* qkvb_u = (float*)(W + X + 173024256);         // 36,864
  float* partb  = (float*)(W + X + 173061120);         // 196,608

  // phase B (after attention) reuses phase-A scratch:
  unsigned short* w1T = (unsigned short*)(W + X);              // 80,216,064
  unsigned short* w2T = (unsigned short*)(W + X + 80216064);   // end X+160432128
  unsigned short* h1  = (unsigned short*)(W + X + 160432128);  // 50,331,648
  int*   grp     = (int*)(W + 261099520);
  float* gate    = (float*)(W + 261132288);
  int*   tok_idx = (int*)(W + 261165056);
  float* gate_s  = (float*)(W + 261197824);

  hipMemsetAsync(W, 0, 3072, stream);

  // ---- sequence router (exact f32) ----
  pooled_partial_k<<<dim3(Bq,3,4),256,0,stream>>>(hs, partb);
  router_seq_k<<<Bq,128,0,stream>>>(partb, sw_enc_w, sw_enc_b, sw_w, sw_b, sel, pm);

  // ---- prepare split-f16 operands ----
  split_f16_k<<<6144,256,0,stream>>>(hs, hsH, hsL, NTq*Dq/4);
  transpose_f16s_k<<<dim3(12,12,1),256,0,stream>>>(ca_wq, wqkv_cH, wqkv_cL, Dq, Dq, 0, 0, 0);
  transpose_f16s_k<<<dim3(12,12,1),256,0,stream>>>(ca_wk, wqkv_cH, wqkv_cL, Dq, Dq, 0, 0, 768);
  transpose_f16s_k<<<dim3(12,12,1),256,0,stream>>>(ca_wv, wqkv_cH, wqkv_cL, Dq, Dq, 0, 0, 1536);
  transpose_f16s_k<<<dim3(12,12,4),256,0,stream>>>(ua_wq, wqkv_uH, wqkv_uL, Dq, Dq, (long)Dq*Dq, (long)2304*768, 0);
  transpose_f16s_k<<<dim3(12,12,4),256,0,stream>>>(ua_wk, wqkv_uH, wqkv_uL, Dq, Dq, (long)Dq*Dq, (long)2304*768, 768);
  transpose_f16s_k<<<dim3(12,12,4),256,0,stream>>>(ua_wv, wqkv_uH, wqkv_uL, Dq, Dq, (long)Dq*Dq, (long)2304*768, 1536);
  transpose_f16s_k<<<dim3(12,12,1),256,0,stream>>>(ca_wo, wo_cH, wo_cL, Dq, Dq, 0, 0, 0);
  transpose_f16s_k<<<dim3(12,12,4),256,0,stream>>>(ua_wo, wo_uH, wo_uL, Dq, Dq, (long)Dq*Dq, (long)Dq*Dq, 0);
  concat_bias3_k<<<dim3(3,1),256,0,stream>>>(ca_bq, ca_bk, ca_bv, qkvb_c, 0);
  concat_bias3_k<<<dim3(3,4),256,0,stream>>>(ua_bq, ua_bk, ua_bv, qkvb_u, 768);

  // ---- common attention ----
  gemm_f16s_k<0,2><<<dim3(18,64),256,0,stream>>>(hsH, hsL, wqkv_cH, wqkv_cL, qkvb_c,
      nullptr, qkvH, qkvL, 2304, Dq, 0, 0, nullptr, nullptr);
  attn_mfma_k<<<dim3(4,Hq,Bq),256,0,stream>>>(qkvH, qkvL, amask, ctxH, ctxL);
  gemm_f16s_k<0,0><<<dim3(6,64),256,0,stream>>>(ctxH, ctxL, wo_cH, wo_cL, ca_bo,
      att, nullptr, nullptr, Dq, Dq, 0, 0, nullptr, nullptr);

  // ---- unique attention (selected expert), att += pm * result ----
  gemm_f16s_k<1,2><<<dim3(18,64),256,0,stream>>>(hsH, hsL, wqkv_uH, wqkv_uL, qkvb_u,
      nullptr, qkvH, qkvL, 2304, Dq, (long)2304*768, 2304, sel, nullptr);
  attn_mfma_k<<<dim3(4,Hq,Bq),256,0,stream>>>(qkvH, qkvL, amask, ctxH, ctxL);
  gemm_f16s_k<1,1><<<dim3(6,64),256,0,stream>>>(ctxH, ctxL, wo_uH, wo_uL, ua_bo,
      att, nullptr, nullptr, Dq, Dq, (long)Dq*Dq, Dq, sel, pm);

  // ---- FFN weights -> transposed bf16 (phase-A scratch now free) ----
  transpose_bf16_k<<<dim3(48,12,1), 256,0,stream>>>(cf_w1, w1T, Dq, Fq);
  transpose_bf16_k<<<dim3(48,12,16),256,0,stream>>>(uf_w1, w1T + 2359296, Dq, Fq);
  transpose_bf16_k<<<dim3(12,48,1), 256,0,stream>>>(cf_w2, w2T, Fq, Dq);
  transpose_bf16_k<<<dim3(12,48,16),256,0,stream>>>(uf_w2, w2T + 2359296, Fq, Dq);

  // ---- common FFN (bf16 MFMA) ----
  gemm_bf16_k<0,0,true,false><<<dim3(24,64),256,0,stream>>>((const void*)att, w1T, cf_b1, nullptr, h1,
      NTq, Fq, Dq, nullptr,nullptr,nullptr,nullptr,nullptr,nullptr, (size_t)0, 0);
  gemm_bf16_k<2,1,false,false><<<dim3(6,64),256,0,stream>>>((const void*)h1, w2T, cf_b2, facc, nullptr,
      NTq, Dq, Fq, nullptr,nullptr,nullptr,nullptr,nullptr,nullptr, (size_t)0, 0);

  // ---- token routing (f32, on accurate att) ----
  token_router_k<<<2048,256,0,stream>>>(att, sel, uf_sw_w, uf_sw_b, grp, gate, grp_cnt);
  build_offsets_k<<<1,1,0,stream>>>(grp_cnt, grp_off, tile_g, tile_r, ntile);
  scatter_k<<<32,256,0,stream>>>(grp, gate, grp_off, fill, tok_idx, gate_s);

  // ---- unique FFN (grouped, top-1 inner expert, gated scatter-add) ----
  gemm_bf16_k<1,0,true,true><<<dim3(24,80),256,0,stream>>>((const void*)att, w1T + 2359296, uf_b1, nullptr, h1,
      NTq, Fq, Dq, tile_g, tile_r, grp_off, ntile, tok_idx, gate_s, (size_t)2359296, Fq);
  gemm_bf16_k<2,2,false,true><<<dim3(6,80),256,0,stream>>>((const void*)h1, w2T + 2359296, uf_b2, facc, nullptr,
      NTq, Dq, Fq, tile_g, tile_r, grp_off, ntile, tok_idx, gate_s, (size_t)2359296, Dq);

  // ---- residual + LayerNorm ----
  final_ln_k<<<NTq,256,0,stream>>>(att, facc, ln_g, ln_b, out);
}

// Round 5
// 1223.974 us; speedup vs baseline: 1.9317x; 1.0520x over previous
//
#include <hip/hip_runtime.h>
#include <cstdint>
#include <cstddef>

#define Bq  16
#define Sq  512
#define Dq  768
#define Hq  12
#define DHq 64
#define Fq  3072
#define SWq 128
#define NTq 8192

typedef float        f32x4  __attribute__((ext_vector_type(4)));
typedef float        f32x16 __attribute__((ext_vector_type(16)));
typedef unsigned int u32x4  __attribute__((ext_vector_type(4)));
typedef __bf16       bf16x8 __attribute__((ext_vector_type(8)));
typedef _Float16     f16x8  __attribute__((ext_vector_type(8)));
typedef _Float16     f16x4  __attribute__((ext_vector_type(4)));
typedef _Float16     f16x2  __attribute__((ext_vector_type(2)));
typedef int          i32x2  __attribute__((ext_vector_type(2)));

__device__ __forceinline__ unsigned short f2bf(float f){
  unsigned int u = __builtin_bit_cast(unsigned int, f);
  u = (u + 0x7fffu + ((u >> 16) & 1u)) >> 16;
  return (unsigned short)u;
}
__device__ __forceinline__ unsigned int pk2(float a, float b){
  return (unsigned int)f2bf(a) | ((unsigned int)f2bf(b) << 16);
}
__device__ __forceinline__ i32x2 pl32swap(unsigned int a, unsigned int b){
  return __builtin_amdgcn_permlane32_swap((int)a, (int)b, false, false);
}
__device__ __forceinline__ f16x2 cvt_pk(float a, float b){
  return __builtin_bit_cast(f16x2, __builtin_amdgcn_cvt_pkrtz(a, b));
}

// Band-supertile + XCD-aware bijective block remap.
// Each XCD gets a contiguous logical range = band(s) of 8 row-panels x all cols,
// row-fast within band: 8 consecutive blocks share one B col-tile; the band's
// 8 A-panels (~3.8MB) stay L2-resident. Requires gy%8==0 (all our grids: gy=64).
__device__ __forceinline__ void swz2d(int &bx, int &by){
  const int gx = gridDim.x, gy = gridDim.y;
  const int nb = gx * gy;
  const int bid = blockIdx.y * gx + blockIdx.x;
  if (((nb & 7) == 0) && ((gy & 7) == 0)){
    const int chunk = nb >> 3;
    const int lb = (bid & 7) * chunk + (bid >> 3);
    const int bw = gx << 3;              // blocks per band
    const int band = lb / bw;
    const int wn = lb - band * bw;
    bx = wn >> 3;
    by = (band << 3) + (wn & 7);
  } else {
    bx = blockIdx.x; by = blockIdx.y;
  }
}

// ---------------- pooled partial sums (seq router input) ----------------
__global__ void pooled_partial_k(const float* __restrict__ x, float* __restrict__ part){
  const int b = blockIdx.x, dc = blockIdx.y, z = blockIdx.z;
  const int d = dc*256 + threadIdx.x;
  const float* p = x + (size_t)b*Sq*Dq + (size_t)z*128*Dq + d;
  float s = 0.f;
  #pragma unroll 4
  for (int i = 0; i < 128; i++) s += p[(size_t)i*Dq];
  part[((size_t)z*Bq + b)*Dq + d] = s;
}

// ---------------- sequence-level router (exact f32) ----------------
__global__ void router_seq_k(const float* __restrict__ part,
    const float* __restrict__ ew, const float* __restrict__ eb,
    const float* __restrict__ sw, const float* __restrict__ sb,
    int* __restrict__ sel, float* __restrict__ pm)
{
  const int b = blockIdx.x, j = threadIdx.x;   // 128 threads
  __shared__ float h[SWq];
  __shared__ float pl[Dq];
  #pragma unroll
  for (int i = 0; i < 6; i++){
    int d = j + i*128;
    float s = part[(size_t)(0*Bq+b)*Dq + d] + part[(size_t)(1*Bq+b)*Dq + d]
            + part[(size_t)(2*Bq+b)*Dq + d] + part[(size_t)(3*Bq+b)*Dq + d];
    pl[d] = s * (1.0f/512.0f);
  }
  __syncthreads();
  float a = eb[j];
  for (int d = 0; d < Dq; d++) a += pl[d] * ew[d*SWq + j];
  h[j] = a;
  __syncthreads();
  if (j == 0){
    float lg[4];
    for (int e = 0; e < 4; e++){
      float t = sb[e];
      for (int k = 0; k < SWq; k++) t += h[k] * sw[k*4 + e];
      lg[e] = t;
    }
    float mx = fmaxf(fmaxf(lg[0],lg[1]), fmaxf(lg[2],lg[3]));
    float p[4], ssum = 0.f;
    for (int e = 0; e < 4; e++){ p[e] = expf(lg[e]-mx); ssum += p[e]; }
    int am = 0; float bv = p[0];
    for (int e = 1; e < 4; e++) if (p[e] > bv){ bv = p[e]; am = e; }
    sel[b] = am; pm[b] = bv/ssum;
  }
}

// ---------------- f32 -> f16 hi/lo split (x1024 scale) ----------------
__global__ void split_f16_k(const float* __restrict__ x, _Float16* __restrict__ hh,
                            _Float16* __restrict__ ll, int n4){
  const int i = blockIdx.x*256 + threadIdx.x;
  if (i >= n4) return;
  f32x4 v = ((const f32x4*)x)[i];
  f16x4 vh, vl;
  #pragma unroll
  for (int j = 0; j < 4; j++){
    float s = v[j] * 1024.0f;
    _Float16 a = (_Float16)s;
    vh[j] = a;
    vl[j] = (_Float16)(s - (float)a);
  }
  ((f16x4*)hh)[i] = vh;
  ((f16x4*)ll)[i] = vl;
}

// ------- weight transpose + f16 hi/lo split: src [K][N] -> dst [N][K] x1024 -------
__global__ void transpose_f16s_k(const float* __restrict__ src,
    _Float16* __restrict__ dH, _Float16* __restrict__ dL,
    int K, int N, long srcStride, long dstStride, int rowOff)
{
  __shared__ float t[64][65];
  const int tid = threadIdx.x;
  const size_t so = (size_t)blockIdx.z * srcStride;
  const size_t dof = (size_t)blockIdx.z * dstStride;
  const int k0 = blockIdx.y * 64, n0 = blockIdx.x * 64;
  const int r = tid >> 2, c0 = (tid & 3) * 16;
  const float* sp = src + so + (size_t)(k0 + r) * N + n0 + c0;
  #pragma unroll
  for (int cc = 0; cc < 16; cc += 4){
    f32x4 v = *(const f32x4*)(sp + cc);
    t[r][c0+cc] = v[0]; t[r][c0+cc+1] = v[1]; t[r][c0+cc+2] = v[2]; t[r][c0+cc+3] = v[3];
  }
  __syncthreads();
  _Float16* ph = dH + dof + (size_t)(rowOff + n0 + r) * K + k0 + c0;
  _Float16* pl = dL + dof + (size_t)(rowOff + n0 + r) * K + k0 + c0;
  #pragma unroll
  for (int cc = 0; cc < 16; cc += 4){
    f16x4 vh, vl;
    #pragma unroll
    for (int j = 0; j < 4; j++){
      float s = t[c0+cc+j][r] * 1024.0f;
      _Float16 a = (_Float16)s;
      vh[j] = a; vl[j] = (_Float16)(s - (float)a);
    }
    *(f16x4*)(ph + cc) = vh;
    *(f16x4*)(pl + cc) = vl;
  }
}

// ---------------- concat q/k/v biases -> [E][2304] ----------------
__global__ void concat_bias3_k(const float* __restrict__ bq, const float* __restrict__ bk,
    const float* __restrict__ bv, float* __restrict__ dst, int srcStride)
{
  const int e = blockIdx.y;
  const int i = blockIdx.x*256 + threadIdx.x;   // grid.x=3 -> i<768
  dst[(size_t)e*2304 + i]        = bq[(size_t)e*srcStride + i];
  dst[(size_t)e*2304 + 768 + i]  = bk[(size_t)e*srcStride + i];
  dst[(size_t)e*2304 + 1536 + i] = bv[(size_t)e*srcStride + i];
}

// ---------------- split-f16 3-term MFMA GEMM (~f32 accuracy) ----------------
// A = (AH+AL)/1024 [M][K], B^T = (BH+BL)/1024 [N][K]; C = A@B + bias
// BMODE: 0 shared B; 1 per-sequence expert.
// OMODE: 0 C=v (f32); 1 C += pm*v (f32); 2 split-f16 x1024 store to Ch/Cl
template<int BMODE, int OMODE>
__global__ __launch_bounds__(256,2) void gemm_f16s_k(
    const _Float16* __restrict__ AH, const _Float16* __restrict__ AL,
    const _Float16* __restrict__ BH, const _Float16* __restrict__ BL,
    const float* __restrict__ bias, float* __restrict__ C,
    _Float16* __restrict__ Ch, _Float16* __restrict__ Cl,
    int N, int K, long estride, int bias_stride,
    const int* __restrict__ sel, const float* __restrict__ pm)
{
  __shared__ _Float16 AsH[128][40];
  __shared__ _Float16 AsL[128][40];
  __shared__ _Float16 BsH[128][40];
  __shared__ _Float16 BsL[128][40];
  const int tid = threadIdx.x;
  const int lane = tid & 63, wave = tid >> 6;
  const int wm = wave >> 1, wn = wave & 1;
  int bx, by; swz2d(bx, by);
  const int row0 = by * 128, col0 = bx * 128;
  const _Float16* bh = BH; const _Float16* bl = BL; const float* bp = bias;
  float cs = 1.0f;
  if constexpr (BMODE == 1){
    const int e = sel[row0 >> 9];
    bh += (size_t)e * estride; bl += (size_t)e * estride;
    bp += (size_t)e * bias_stride;
  }
  if constexpr (OMODE == 1) cs = pm[row0 >> 9];

  const int sr = tid >> 1, sk = (tid & 1) * 16;
  const _Float16* ahp = AH + (size_t)(row0 + sr) * K + sk;
  const _Float16* alp = AL + (size_t)(row0 + sr) * K + sk;
  const _Float16* bhp = bh + (size_t)(col0 + sr) * K + sk;
  const _Float16* blp = bl + (size_t)(col0 + sr) * K + sk;

  f32x4 acc[4][4];
  #pragma unroll
  for (int mi=0;mi<4;mi++)
    #pragma unroll
    for (int ni=0;ni<4;ni++) acc[mi][ni] = (f32x4){0.f,0.f,0.f,0.f};

  for (int k0 = 0; k0 < K; k0 += 32){
    u32x4 vah0 = *(const u32x4*)(ahp + k0);
    u32x4 vah1 = *(const u32x4*)(ahp + k0 + 8);
    u32x4 val0 = *(const u32x4*)(alp + k0);
    u32x4 val1 = *(const u32x4*)(alp + k0 + 8);
    u32x4 vbh0 = *(const u32x4*)(bhp + k0);
    u32x4 vbh1 = *(const u32x4*)(bhp + k0 + 8);
    u32x4 vbl0 = *(const u32x4*)(blp + k0);
    u32x4 vbl1 = *(const u32x4*)(blp + k0 + 8);
    __syncthreads();
    *(u32x4*)&AsH[sr][sk]   = vah0; *(u32x4*)&AsH[sr][sk+8] = vah1;
    *(u32x4*)&AsL[sr][sk]   = val0; *(u32x4*)&AsL[sr][sk+8] = val1;
    *(u32x4*)&BsH[sr][sk]   = vbh0; *(u32x4*)&BsH[sr][sk+8] = vbh1;
    *(u32x4*)&BsL[sr][sk]   = vbl0; *(u32x4*)&BsL[sr][sk+8] = vbl1;
    __syncthreads();
    f16x8 fah[4], fal[4], fbh[4], fbl[4];
    #pragma unroll
    for (int mi=0;mi<4;mi++){
      const int r = wm*64 + mi*16 + (lane&15), c = 8*(lane>>4);
      fah[mi] = __builtin_bit_cast(f16x8, *(const u32x4*)&AsH[r][c]);
      fal[mi] = __builtin_bit_cast(f16x8, *(const u32x4*)&AsL[r][c]);
    }
    #pragma unroll
    for (int ni=0;ni<4;ni++){
      const int r = wn*64 + ni*16 + (lane&15), c = 8*(lane>>4);
      fbh[ni] = __builtin_bit_cast(f16x8, *(const u32x4*)&BsH[r][c]);
      fbl[ni] = __builtin_bit_cast(f16x8, *(const u32x4*)&BsL[r][c]);
    }
    #pragma unroll
    for (int mi=0;mi<4;mi++)
      #pragma unroll
      for (int ni=0;ni<4;ni++){
        acc[mi][ni] = __builtin_amdgcn_mfma_f32_16x16x32_f16(fah[mi], fbh[ni], acc[mi][ni], 0, 0, 0);
        acc[mi][ni] = __builtin_amdgcn_mfma_f32_16x16x32_f16(fah[mi], fbl[ni], acc[mi][ni], 0, 0, 0);
        acc[mi][ni] = __builtin_amdgcn_mfma_f32_16x16x32_f16(fal[mi], fbh[ni], acc[mi][ni], 0, 0, 0);
      }
  }

  const float INV = 1.0f/1048576.0f;   // undo 1024*1024 scaling (exact pow2)
  const int erow = 4*(lane >> 4);
  const int ecol = lane & 15;
  #pragma unroll
  for (int mi=0;mi<4;mi++)
    #pragma unroll
    for (int ni=0;ni<4;ni++){
      const int c = col0 + wn*64 + ni*16 + ecol;
      const float bb = bp[c];
      #pragma unroll
      for (int r=0;r<4;r++){
        const int R = row0 + wm*64 + mi*16 + erow + r;
        const float v = acc[mi][ni][r]*INV + bb;
        if constexpr (OMODE == 0){
          C[(size_t)R*N + c] = v;
        } else if constexpr (OMODE == 1){
          C[(size_t)R*N + c] += cs*v;
        } else {
          const float vs = v * 1024.0f;
          const _Float16 hi = (_Float16)vs;
          Ch[(size_t)R*N + c] = hi;
          Cl[(size_t)R*N + c] = (_Float16)(vs - (float)hi);
        }
      }
    }
}

// ------- split-f16 MFMA attention (swapped-QK, in-register softmax) -------
// QKV in split-f16 x1024: [8192][2304] (Q|K|V). ctx out split-f16 x1024.
__global__ __launch_bounds__(256,2) void attn_mfma_k(
    const _Float16* __restrict__ qkvH, const _Float16* __restrict__ qkvL,
    const float* __restrict__ mask,
    _Float16* __restrict__ ctxH, _Float16* __restrict__ ctxL)
{
  __shared__ _Float16 Kh[64][72], Kl[64][72];
  __shared__ _Float16 Vh[64][72], Vl[64][72];   // transposed: [d][k]
  __shared__ float msk[64];
  __shared__ float rsi[4][32];
  const int qb = blockIdx.x, h = blockIdx.y, b = blockIdx.z;
  const int tid = threadIdx.x;
  const int l = tid & 63, w = tid >> 6;
  const int l31 = l & 31, g5 = l >> 5;
  const float SC = 1.0f/8388608.0f;   // 2^-20 (split scale) * 1/8 (1/sqrt(64))

  // Q B-fragments (persistent): col=q=lane&31, k=d=c*16+g5*8+j
  u32x4 qfh[4], qfl[4];
  {
    const size_t qoff = (size_t)(b*Sq + qb*128 + w*32 + l31) * 2304 + h*DHq + g5*8;
    #pragma unroll
    for (int c = 0; c < 4; c++){
      qfh[c] = *(const u32x4*)(qkvH + qoff + c*16);
      qfl[c] = *(const u32x4*)(qkvL + qoff + c*16);
    }
  }
  f32x16 oacc[2];
  #pragma unroll
  for (int nt = 0; nt < 2; nt++)
    #pragma unroll
    for (int i = 0; i < 16; i++) oacc[nt][i] = 0.f;
  float rsl = 0.f;
  const float* mrow = mask + b*Sq;

  for (int kt = 0; kt < 8; kt++){
    __syncthreads();
    // ---- stage K (natural) and V (transposed) tiles, hi+lo ----
    {
      const size_t krow = (size_t)(b*Sq + kt*64 + l) * 2304 + 768 + h*DHq;
      #pragma unroll
      for (int i = 0; i < 2; i++){
        const int ch = w + i*4;           // 8 x 16B chunks per row
        *(u32x4*)&Kh[l][ch*8] = *(const u32x4*)(qkvH + krow + ch*8);
        *(u32x4*)&Kl[l][ch*8] = *(const u32x4*)(qkvL + krow + ch*8);
      }
      const size_t vrow = krow + 768 + w*16;
      f16x8 v0 = __builtin_bit_cast(f16x8, *(const u32x4*)(qkvH + vrow));
      f16x8 v1 = __builtin_bit_cast(f16x8, *(const u32x4*)(qkvH + vrow + 8));
      f16x8 u0 = __builtin_bit_cast(f16x8, *(const u32x4*)(qkvL + vrow));
      f16x8 u1 = __builtin_bit_cast(f16x8, *(const u32x4*)(qkvL + vrow + 8));
      #pragma unroll
      for (int i = 0; i < 8; i++){
        Vh[w*16 + i][l] = v0[i]; Vh[w*16 + 8 + i][l] = v1[i];
        Vl[w*16 + i][l] = u0[i]; Vl[w*16 + 8 + i][l] = u1[i];
      }
      if (tid < 64) msk[tid] = mrow[kt*64 + tid] + 6.9314718055994531f; // + ln(1024)
    }
    __syncthreads();

    // ---- S^T = K · Q^T (rows = kcol, cols = q) ----
    f32x16 sacc[2];
    #pragma unroll
    for (int mt = 0; mt < 2; mt++)
      #pragma unroll
      for (int i = 0; i < 16; i++) sacc[mt][i] = 0.f;
    #pragma unroll
    for (int mt = 0; mt < 2; mt++){
      #pragma unroll
      for (int c = 0; c < 4; c++){
        f16x8 kh = __builtin_bit_cast(f16x8, *(const u32x4*)&Kh[mt*32 + l31][c*16 + g5*8]);
        f16x8 kl = __builtin_bit_cast(f16x8, *(const u32x4*)&Kl[mt*32 + l31][c*16 + g5*8]);
        f16x8 qh = __builtin_bit_cast(f16x8, qfh[c]);
        f16x8 ql = __builtin_bit_cast(f16x8, qfl[c]);
        sacc[mt] = __builtin_amdgcn_mfma_f32_32x32x16_f16(kh, qh, sacc[mt], 0, 0, 0);
        sacc[mt] = __builtin_amdgcn_mfma_f32_32x32x16_f16(kh, ql, sacc[mt], 0, 0, 0);
        sacc[mt] = __builtin_amdgcn_mfma_f32_32x32x16_f16(kl, qh, sacc[mt], 0, 0, 0);
      }
    }

    // ---- softmax numerator p = exp(s)*1024, split-pack to f16 hi/lo ----
    unsigned int hP[2][4][2], lP[2][4][2];
    #pragma unroll
    for (int mt = 0; mt < 2; mt++){
      #pragma unroll
      for (int m = 0; m < 4; m++){
        f32x4 mk = *(const f32x4*)&msk[mt*32 + m*8 + g5*4];
        float p0 = __expf(fmaf(sacc[mt][4*m+0], SC, mk[0]));
        float p1 = __expf(fmaf(sacc[mt][4*m+1], SC, mk[1]));
        float p2 = __expf(fmaf(sacc[mt][4*m+2], SC, mk[2]));
        float p3 = __expf(fmaf(sacc[mt][4*m+3], SC, mk[3]));
        rsl += (p0 + p1) + (p2 + p3);
        f16x2 h0 = cvt_pk(p0, p1);
        f16x2 h1 = cvt_pk(p2, p3);
        f16x2 e0, e1;
        e0[0] = (_Float16)(p0 - (float)h0[0]); e0[1] = (_Float16)(p1 - (float)h0[1]);
        e1[0] = (_Float16)(p2 - (float)h1[0]); e1[1] = (_Float16)(p3 - (float)h1[1]);
        hP[mt][m][0] = __builtin_bit_cast(unsigned int, h0);
        hP[mt][m][1] = __builtin_bit_cast(unsigned int, h1);
        lP[mt][m][0] = __builtin_bit_cast(unsigned int, e0);
        lP[mt][m][1] = __builtin_bit_cast(unsigned int, e1);
      }
    }

    // ---- O += P · V  (A-fragments assembled via permlane32_swap) ----
    #pragma unroll
    for (int mt = 0; mt < 2; mt++){
      #pragma unroll
      for (int cc = 0; cc < 2; cc++){
        i32x2 sh0 = pl32swap(hP[mt][2*cc][0], hP[mt][2*cc+1][0]);
        i32x2 sh1 = pl32swap(hP[mt][2*cc][1], hP[mt][2*cc+1][1]);
        i32x2 sl0 = pl32swap(lP[mt][2*cc][0], lP[mt][2*cc+1][0]);
        i32x2 sl1 = pl32swap(lP[mt][2*cc][1], lP[mt][2*cc+1][1]);
        u32x4 pah = (u32x4){(unsigned)sh0[0], (unsigned)sh1[0], (unsigned)sh0[1], (unsigned)sh1[1]};
        u32x4 pal = (u32x4){(unsigned)sl0[0], (unsigned)sl1[0], (unsigned)sl0[1], (unsigned)sl1[1]};
        f16x8 ph = __builtin_bit_cast(f16x8, pah);
        f16x8 pe = __builtin_bit_cast(f16x8, pal);
        const int kof = (mt*2 + cc)*16 + g5*8;
        #pragma unroll
        for (int nt = 0; nt < 2; nt++){
          f16x8 vh = __builtin_bit_cast(f16x8, *(const u32x4*)&Vh[nt*32 + l31][kof]);
          f16x8 vl = __builtin_bit_cast(f16x8, *(const u32x4*)&Vl[nt*32 + l31][kof]);
          oacc[nt] = __builtin_amdgcn_mfma_f32_32x32x16_f16(ph, vh, oacc[nt], 0, 0, 0);
          oacc[nt] = __builtin_amdgcn_mfma_f32_32x32x16_f16(ph, vl, oacc[nt], 0, 0, 0);
          oacc[nt] = __builtin_amdgcn_mfma_f32_32x32x16_f16(pe, vh, oacc[nt], 0, 0, 0);
        }
      }
    }
  }

  // ---- row-sum total (lane + partner lane across 32-halves), reciprocal ----
  {
    unsigned int rb = __builtin_bit_cast(unsigned int, rsl);
    i32x2 sw = pl32swap(rb, rb);
    float partner = __builtin_bit_cast(float, (l >= 32) ? sw[0] : sw[1]);
    float tot = rsl + partner;
    if (l < 32) rsi[w][l31] = 1.0f / tot;
  }
  __syncthreads();

  // ---- epilogue: divide, split-f16 store (x1024 kept: o_store = acc/rs) ----
  const size_t obase = (size_t)(b*Sq + qb*128 + w*32);
  #pragma unroll
  for (int nt = 0; nt < 2; nt++){
    const int col = h*DHq + nt*32 + l31;
    #pragma unroll
    for (int r = 0; r < 16; r++){
      const int q = (r&3) + 8*(r>>2) + 4*g5;
      const float v = oacc[nt][r] * rsi[w][q];
      const _Float16 hi = (_Float16)v;
      const size_t off = (obase + q)*Dq + col;
      ctxH[off] = hi;
      ctxL[off] = (_Float16)(v - (float)hi);
    }
  }
}

// ---------------- transpose + f32->bf16 (FFN weights -> [N][K] bf16) ----------------
__global__ void transpose_bf16_k(const float* __restrict__ src, unsigned short* __restrict__ dst,
                                 int K, int N)
{
  __shared__ float t[64][65];
  const int tid = threadIdx.x;
  const size_t mo = (size_t)blockIdx.z * K * N;
  const int k0 = blockIdx.y * 64, n0 = blockIdx.x * 64;
  const int r = tid >> 2, c0 = (tid & 3) * 16;
  const float* sp = src + mo + (size_t)(k0 + r) * N + n0 + c0;
  #pragma unroll
  for (int cc = 0; cc < 16; cc += 4){
    f32x4 v = *(const f32x4*)(sp + cc);
    t[r][c0+cc] = v[0]; t[r][c0+cc+1] = v[1]; t[r][c0+cc+2] = v[2]; t[r][c0+cc+3] = v[3];
  }
  __syncthreads();
  unsigned short* dp = dst + mo + (size_t)(n0 + r) * K + k0 + c0;
  u32x4 h0, h1v;
  #pragma unroll
  for (int i = 0; i < 4; i++) h0[i]  = pk2(t[c0+2*i  ][r], t[c0+2*i+1][r]);
  #pragma unroll
  for (int i = 0; i < 4; i++) h1v[i] = pk2(t[c0+8+2*i][r], t[c0+9+2*i][r]);
  *(u32x4*)(dp)     = h0;
  *(u32x4*)(dp + 8) = h1v;
}

// ---------------- bf16 MFMA GEMM (FFN path) ----------------
// AMODE: 0 f32 rows; 1 f32 rows via tok_idx; 2 bf16 rows
// OMODE: 0 bf16 store (h1); 1 f32 write+bias; 2 f32 scatter add gate*(res+bias)
template<int AMODE, int OMODE, bool GELU_, bool GROUPED>
__global__ __launch_bounds__(256,2) void gemm_bf16_k(
    const void* __restrict__ Av, const unsigned short* __restrict__ BT,
    const float* __restrict__ bias, float* __restrict__ Cf, unsigned short* __restrict__ Cb,
    int M, int N, int K,
    const int* __restrict__ tile_g, const int* __restrict__ tile_r0,
    const int* __restrict__ grp_off, const int* __restrict__ n_tiles,
    const int* __restrict__ tok_idx, const float* __restrict__ gate_s,
    size_t bstride, int bias_stride)
{
  __shared__ unsigned short As[128][40];
  __shared__ unsigned short Bs[128][40];
  const int tid = threadIdx.x;
  const int lane = tid & 63, wave = tid >> 6;
  const int wm = wave >> 1, wn = wave & 1;
  int col0, row0, gend = 1 << 30, g = 0;
  if constexpr (GROUPED){
    const int t = blockIdx.y;
    if (t >= *n_tiles) return;
    g = tile_g[t];
    row0 = grp_off[g] + tile_r0[t];
    gend = grp_off[g+1];
    col0 = blockIdx.x * 128;
  } else {
    int bx, by; swz2d(bx, by);
    row0 = by * 128;
    col0 = bx * 128;
  }
  const unsigned short* Bp = BT + (size_t)g * bstride;
  const float* bp = bias + (size_t)g * bias_stride;

  const int sr = tid >> 1;
  const int sk = (tid & 1) * 16;
  int arow = row0 + sr;
  if constexpr (GROUPED) arow = (arow < gend - 1) ? arow : (gend - 1);
  if constexpr (AMODE == 1) arow = tok_idx[arow];
  const float*          afp = (const float*)Av          + (size_t)arow * K + sk;
  const unsigned short* abp = (const unsigned short*)Av + (size_t)arow * K + sk;
  const unsigned short* bfp = Bp + (size_t)(col0 + sr) * K + sk;

  f32x4 acc[4][4];
  #pragma unroll
  for (int mi=0;mi<4;mi++)
    #pragma unroll
    for (int ni=0;ni<4;ni++) acc[mi][ni] = (f32x4){0.f,0.f,0.f,0.f};

  for (int k0 = 0; k0 < K; k0 += 32){
    u32x4 bl0 = *(const u32x4*)(bfp + k0);
    u32x4 bl1 = *(const u32x4*)(bfp + k0 + 8);
    u32x4 al0, al1;
    if constexpr (AMODE == 2){
      al0 = *(const u32x4*)(abp + k0);
      al1 = *(const u32x4*)(abp + k0 + 8);
    } else {
      f32x4 f0 = *(const f32x4*)(afp + k0);
      f32x4 f1 = *(const f32x4*)(afp + k0 + 4);
      f32x4 f2 = *(const f32x4*)(afp + k0 + 8);
      f32x4 f3 = *(const f32x4*)(afp + k0 + 12);
      al0[0]=pk2(f0[0],f0[1]); al0[1]=pk2(f0[2],f0[3]); al0[2]=pk2(f1[0],f1[1]); al0[3]=pk2(f1[2],f1[3]);
      al1[0]=pk2(f2[0],f2[1]); al1[1]=pk2(f2[2],f2[3]); al1[2]=pk2(f3[0],f3[1]); al1[3]=pk2(f3[2],f3[3]);
    }
    __syncthreads();
    *(u32x4*)&As[sr][sk]     = al0;
    *(u32x4*)&As[sr][sk + 8] = al1;
    *(u32x4*)&Bs[sr][sk]     = bl0;
    *(u32x4*)&Bs[sr][sk + 8] = bl1;
    __syncthreads();
    bf16x8 af[4], bfr[4];
    #pragma unroll
    for (int mi=0;mi<4;mi++){
      u32x4 t = *(const u32x4*)&As[wm*64 + mi*16 + (lane&15)][8*(lane>>4)];
      af[mi] = __builtin_bit_cast(bf16x8, t);
    }
    #pragma unroll
    for (int ni=0;ni<4;ni++){
      u32x4 t = *(const u32x4*)&Bs[wn*64 + ni*16 + (lane&15)][8*(lane>>4)];
      bfr[ni] = __builtin_bit_cast(bf16x8, t);
    }
    #pragma unroll
    for (int mi=0;mi<4;mi++)
      #pragma unroll
      for (int ni=0;ni<4;ni++)
        acc[mi][ni] = __builtin_amdgcn_mfma_f32_16x16x32_bf16(af[mi], bfr[ni], acc[mi][ni], 0, 0, 0);
  }

  const int erow = 4*(lane >> 4);
  const int ecol = lane & 15;
  #pragma unroll
  for (int mi=0;mi<4;mi++)
    #pragma unroll
    for (int ni=0;ni<4;ni++){
      const int c = col0 + wn*64 + ni*16 + ecol;
      const float bb = bp[c];
      #pragma unroll
      for (int r=0;r<4;r++){
        const int R = row0 + wm*64 + mi*16 + erow + r;
        if (GROUPED && R >= gend) continue;
        float v = acc[mi][ni][r] + bb;
        if (GELU_) v = 0.5f*v*(1.0f + erff(v*0.70710678118654752f));
        if constexpr (OMODE == 0){
          Cb[(size_t)R*N + c] = f2bf(v);
        } else if constexpr (OMODE == 1){
          Cf[(size_t)R*N + c] = v;
        } else {
          const int tok = tok_idx[R];
          const float gt = gate_s[R];
          float* p = Cf + (size_t)tok*N + c;
          *p += gt*v;
        }
      }
    }
}

// ---------------- token-level switch router (f32, one wave/token) ----------------
__global__ void token_router_k(const float* __restrict__ att, const int* __restrict__ sel,
    const float* __restrict__ sww, const float* __restrict__ swb,
    int* __restrict__ grp, float* __restrict__ gate, int* __restrict__ grp_cnt)
{
  const int t = blockIdx.x*4 + (threadIdx.x >> 6);
  const int lane = threadIdx.x & 63;
  const int e = sel[t >> 9];
  const float* x = att + (size_t)t * Dq;
  const float* w = sww + (size_t)e * Dq * 4;
  float a0=0.f, a1=0.f, a2=0.f, a3=0.f;
  #pragma unroll 4
  for (int i = 0; i < 12; i++){
    const int d = lane + i*64;
    const float xv = x[d];
    f32x4 wv = *(const f32x4*)&w[d*4];
    a0 += xv*wv[0]; a1 += xv*wv[1]; a2 += xv*wv[2]; a3 += xv*wv[3];
  }
  #pragma unroll
  for (int off = 32; off; off >>= 1){
    a0 += __shfl_xor(a0, off); a1 += __shfl_xor(a1, off);
    a2 += __shfl_xor(a2, off); a3 += __shfl_xor(a3, off);
  }
  if (lane == 0){
    const float l0 = a0 + swb[e*4+0], l1 = a1 + swb[e*4+1];
    const float l2 = a2 + swb[e*4+2], l3 = a3 + swb[e*4+3];
    const float mx = fmaxf(fmaxf(l0,l1), fmaxf(l2,l3));
    const float p0 = expf(l0-mx), p1 = expf(l1-mx), p2 = expf(l2-mx), p3 = expf(l3-mx);
    const float ssum = p0+p1+p2+p3;
    int am = 0; float bv = p0;
    if (p1 > bv){ bv=p1; am=1; }
    if (p2 > bv){ bv=p2; am=2; }
    if (p3 > bv){ bv=p3; am=3; }
    grp[t] = e*4 + am;
    gate[t] = bv/ssum;
    atomicAdd(&grp_cnt[e*4 + am], 1);
  }
}

__global__ void build_offsets_k(const int* __restrict__ grp_cnt, int* __restrict__ grp_off,
    int* __restrict__ tile_g, int* __restrict__ tile_r0, int* __restrict__ n_tiles)
{
  int off = 0, nt = 0;
  for (int g = 0; g < 16; g++){
    grp_off[g] = off;
    const int c = grp_cnt[g];
    for (int r0 = 0; r0 < c; r0 += 128){ tile_g[nt] = g; tile_r0[nt] = r0; nt++; }
    off += c;
  }
  grp_off[16] = off;
  *n_tiles = nt;
}

__global__ void scatter_k(const int* __restrict__ grp, const float* __restrict__ gate,
    const int* __restrict__ grp_off, int* __restrict__ fill,
    int* __restrict__ tok_idx, float* __restrict__ gate_s)
{
  const int t = blockIdx.x*256 + threadIdx.x;
  const int g = grp[t];
  const int pos = grp_off[g] + atomicAdd(&fill[g], 1);
  tok_idx[pos] = t;
  gate_s[pos] = gate[t];
}

// ---------------- final residual-add + LayerNorm ----------------
__global__ __launch_bounds__(256) void final_ln_k(const float* __restrict__ att,
    const float* __restrict__ acc, const float* __restrict__ lg,
    const float* __restrict__ lb, float* __restrict__ out)
{
  const int row = blockIdx.x, tid = threadIdx.x;
  const float* a = att + (size_t)row * Dq;
  const float* c = acc + (size_t)row * Dq;
  float x[3];
  #pragma unroll
  for (int i = 0; i < 3; i++) x[i] = a[tid + 256*i] + c[tid + 256*i];
  __shared__ float red[256];
  red[tid] = x[0] + x[1] + x[2];
  __syncthreads();
  for (int st = 128; st; st >>= 1){
    if (tid < st) red[tid] += red[tid + st];
    __syncthreads();
  }
  const float mu = red[0] * (1.0f/768.0f);
  __syncthreads();
  const float d0 = x[0]-mu, d1 = x[1]-mu, d2 = x[2]-mu;
  red[tid] = d0*d0 + d1*d1 + d2*d2;
  __syncthreads();
  for (int st = 128; st; st >>= 1){
    if (tid < st) red[tid] += red[tid + st];
    __syncthreads();
  }
  const float inv = 1.0f/sqrtf(red[0]*(1.0f/768.0f) + 1e-12f);
  #pragma unroll
  for (int i = 0; i < 3; i++){
    const int col = tid + 256*i;
    out[(size_t)row*Dq + col] = (x[i]-mu)*inv*lg[col] + lb[col];
  }
}

// ======================= launch =======================
extern "C" void kernel_launch(void* const* d_in, const int* in_sizes, int n_in,
                              void* d_out, int out_size, void* d_ws, size_t ws_size,
                              hipStream_t stream)
{
  (void)in_sizes; (void)n_in; (void)out_size; (void)ws_size;
  const float* hs    = (const float*)d_in[0];
  const float* amask = (const float*)d_in[1];
  const float* sw_enc_w = (const float*)d_in[3];
  const float* sw_enc_b = (const float*)d_in[4];
  const float* sw_w  = (const float*)d_in[5];
  const float* sw_b  = (const float*)d_in[6];
  const float* ca_wq = (const float*)d_in[7];
  const float* ca_bq = (const float*)d_in[8];
  const float* ca_wk = (const float*)d_in[9];
  const float* ca_bk = (const float*)d_in[10];
  const float* ca_wv = (const float*)d_in[11];
  const float* ca_bv = (const float*)d_in[12];
  const float* ca_wo = (const float*)d_in[13];
  const float* ca_bo = (const float*)d_in[14];
  const float* ua_wq = (const float*)d_in[15];
  const float* ua_bq = (const float*)d_in[16];
  const float* ua_wk = (const float*)d_in[17];
  const float* ua_bk = (const float*)d_in[18];
  const float* ua_wv = (const float*)d_in[19];
  const float* ua_bv = (const float*)d_in[20];
  const float* ua_wo = (const float*)d_in[21];
  const float* ua_bo = (const float*)d_in[22];
  const float* cf_w1 = (const float*)d_in[23];
  const float* cf_b1 = (const float*)d_in[24];
  const float* cf_w2 = (const float*)d_in[25];
  const float* cf_b2 = (const float*)d_in[26];
  const float* uf_sw_w = (const float*)d_in[27];
  const float* uf_sw_b = (const float*)d_in[28];
  const float* uf_w1 = (const float*)d_in[29];
  const float* uf_b1 = (const float*)d_in[30];
  const float* uf_w2 = (const float*)d_in[31];
  const float* uf_b2 = (const float*)d_in[32];
  const float* ln_g  = (const float*)d_in[33];
  const float* ln_b  = (const float*)d_in[34];
  float* out = (float*)d_out;

  char* W = (char*)d_ws;
  // control block (zeroed each launch)
  int*   sel     = (int*)(W + 0);
  float* pm      = (float*)(W + 64);
  int*   grp_cnt = (int*)(W + 128);
  int*   fill    = (int*)(W + 192);
  int*   ntile   = (int*)(W + 256);
  int*   grp_off = (int*)(W + 512);
  int*   tile_g  = (int*)(W + 1024);
  int*   tile_r  = (int*)(W + 2048);

  float* att  = (float*)(W + 4096);             // [8192][768] f32
  float* facc = (float*)(W + 25169920);         // [8192][768] f32
  const size_t X = 50335744;
  _Float16* hsH  = (_Float16*)(W + X);                 // 12,582,912
  _Float16* hsL  = (_Float16*)(W + X + 12582912);
  _Float16* qkvH = (_Float16*)(W + X + 25165824);      // 37,748,736
  _Float16* qkvL = (_Float16*)(W + X + 62914560);      // end X+100663296
  _Float16* ctxH = (_Float16*)(W + X + 100663296);     // 12,582,912
  _Float16* ctxL = (_Float16*)(W + X + 113246208);     // end X+125829120
  _Float16* wqkv_cH = (_Float16*)(W + X + 125829120);  // 3,538,944
  _Float16* wqkv_cL = (_Float16*)(W + X + 129368064);
  _Float16* wqkv_uH = (_Float16*)(W + X + 132907008);  // 14,155,776
  _Float16* wqkv_uL = (_Float16*)(W + X + 147062784);
  _Float16* wo_cH   = (_Float16*)(W + X + 161218560);  // 1,179,648
  _Float16* wo_cL   = (_Float16*)(W + X + 162398208);
  _Float16* wo_uH   = (_Float16*)(W + X + 163577856);  // 4,718,592
  _Float16* wo_uL   = (_Float16*)(W + X + 168296448);  // end X+173015040
  float* qkvb_c = (float*)(W + X + 173015040);         // 9,216
  float* qkvb_u = (float*)(W + X + 173024256);         // 36,864
  float* partb  = (float*)(W + X + 173061120);         // 196,608

  // phase B (after attention) reuses phase-A scratch:
  unsigned short* w1T = (unsigned short*)(W + X);              // 80,216,064
  unsigned short* w2T = (unsigned short*)(W + X + 80216064);   // end X+160432128
  unsigned short* h1  = (unsigned short*)(W + X + 160432128);  // 50,331,648
  int*   grp     = (int*)(W + 261099520);
  float* gate    = (float*)(W + 261132288);
  int*   tok_idx = (int*)(W + 261165056);
  float* gate_s  = (float*)(W + 261197824);

  hipMemsetAsync(W, 0, 3072, stream);

  // ---- sequence router (exact f32) ----
  pooled_partial_k<<<dim3(Bq,3,4),256,0,stream>>>(hs, partb);
  router_seq_k<<<Bq,128,0,stream>>>(partb, sw_enc_w, sw_enc_b, sw_w, sw_b, sel, pm);

  // ---- prepare split-f16 operands ----
  split_f16_k<<<6144,256,0,stream>>>(hs, hsH, hsL, NTq*Dq/4);
  transpose_f16s_k<<<dim3(12,12,1),256,0,stream>>>(ca_wq, wqkv_cH, wqkv_cL, Dq, Dq, 0, 0, 0);
  transpose_f16s_k<<<dim3(12,12,1),256,0,stream>>>(ca_wk, wqkv_cH, wqkv_cL, Dq, Dq, 0, 0, 768);
  transpose_f16s_k<<<dim3(12,12,1),256,0,stream>>>(ca_wv, wqkv_cH, wqkv_cL, Dq, Dq, 0, 0, 1536);
  transpose_f16s_k<<<dim3(12,12,4),256,0,stream>>>(ua_wq, wqkv_uH, wqkv_uL, Dq, Dq, (long)Dq*Dq, (long)2304*768, 0);
  transpose_f16s_k<<<dim3(12,12,4),256,0,stream>>>(ua_wk, wqkv_uH, wqkv_uL, Dq, Dq, (long)Dq*Dq, (long)2304*768, 768);
  transpose_f16s_k<<<dim3(12,12,4),256,0,stream>>>(ua_wv, wqkv_uH, wqkv_uL, Dq, Dq, (long)Dq*Dq, (long)2304*768, 1536);
  transpose_f16s_k<<<dim3(12,12,1),256,0,stream>>>(ca_wo, wo_cH, wo_cL, Dq, Dq, 0, 0, 0);
  transpose_f16s_k<<<dim3(12,12,4),256,0,stream>>>(ua_wo, wo_uH, wo_uL, Dq, Dq, (long)Dq*Dq, (long)Dq*Dq, 0);
  concat_bias3_k<<<dim3(3,1),256,0,stream>>>(ca_bq, ca_bk, ca_bv, qkvb_c, 0);
  concat_bias3_k<<<dim3(3,4),256,0,stream>>>(ua_bq, ua_bk, ua_bv, qkvb_u, 768);

  // ---- common attention ----
  gemm_f16s_k<0,2><<<dim3(18,64),256,0,stream>>>(hsH, hsL, wqkv_cH, wqkv_cL, qkvb_c,
      nullptr, qkvH, qkvL, 2304, Dq, 0, 0, nullptr, nullptr);
  attn_mfma_k<<<dim3(4,Hq,Bq),256,0,stream>>>(qkvH, qkvL, amask, ctxH, ctxL);
  gemm_f16s_k<0,0><<<dim3(6,64),256,0,stream>>>(ctxH, ctxL, wo_cH, wo_cL, ca_bo,
      att, nullptr, nullptr, Dq, Dq, 0, 0, nullptr, nullptr);

  // ---- unique attention (selected expert), att += pm * result ----
  gemm_f16s_k<1,2><<<dim3(18,64),256,0,stream>>>(hsH, hsL, wqkv_uH, wqkv_uL, qkvb_u,
      nullptr, qkvH, qkvL, 2304, Dq, (long)2304*768, 2304, sel, nullptr);
  attn_mfma_k<<<dim3(4,Hq,Bq),256,0,stream>>>(qkvH, qkvL, amask, ctxH, ctxL);
  gemm_f16s_k<1,1><<<dim3(6,64),256,0,stream>>>(ctxH, ctxL, wo_uH, wo_uL, ua_bo,
      att, nullptr, nullptr, Dq, Dq, (long)Dq*Dq, Dq, sel, pm);

  // ---- FFN weights -> transposed bf16 (phase-A scratch now free) ----
  transpose_bf16_k<<<dim3(48,12,1), 256,0,stream>>>(cf_w1, w1T, Dq, Fq);
  transpose_bf16_k<<<dim3(48,12,16),256,0,stream>>>(uf_w1, w1T + 2359296, Dq, Fq);
  transpose_bf16_k<<<dim3(12,48,1), 256,0,stream>>>(cf_w2, w2T, Fq, Dq);
  transpose_bf16_k<<<dim3(12,48,16),256,0,stream>>>(uf_w2, w2T + 2359296, Fq, Dq);

  // ---- common FFN (bf16 MFMA) ----
  gemm_bf16_k<0,0,true,false><<<dim3(24,64),256,0,stream>>>((const void*)att, w1T, cf_b1, nullptr, h1,
      NTq, Fq, Dq, nullptr,nullptr,nullptr,nullptr,nullptr,nullptr, (size_t)0, 0);
  gemm_bf16_k<2,1,false,false><<<dim3(6,64),256,0,stream>>>((const void*)h1, w2T, cf_b2, facc, nullptr,
      NTq, Dq, Fq, nullptr,nullptr,nullptr,nullptr,nullptr,nullptr, (size_t)0, 0);

  // ---- token routing (f32, on accurate att) ----
  token_router_k<<<2048,256,0,stream>>>(att, sel, uf_sw_w, uf_sw_b, grp, gate, grp_cnt);
  build_offsets_k<<<1,1,0,stream>>>(grp_cnt, grp_off, tile_g, tile_r, ntile);
  scatter_k<<<32,256,0,stream>>>(grp, gate, grp_off, fill, tok_idx, gate_s);

  // ---- unique FFN (grouped, top-1 inner expert, gated scatter-add) ----
  gemm_bf16_k<1,0,true,true><<<dim3(24,80),256,0,stream>>>((const void*)att, w1T + 2359296, uf_b1, nullptr, h1,
      NTq, Fq, Dq, tile_g, tile_r, grp_off, ntile, tok_idx, gate_s, (size_t)2359296, Fq);
  gemm_bf16_k<2,2,false,true><<<dim3(6,80),256,0,stream>>>((const void*)h1, w2T + 2359296, uf_b2, facc, nullptr,
      NTq, Dq, Fq, tile_g, tile_r, grp_off, ntile, tok_idx, gate_s, (size_t)2359296, Dq);

  // ---- residual + LayerNorm ----
  final_ln_k<<<NTq,256,0,stream>>>(att, facc, ln_g, ln_b, out);
}

// Round 6
// 1216.578 us; speedup vs baseline: 1.9435x; 1.0061x over previous
//
#include <hip/hip_runtime.h>
#include <cstdint>
#include <cstddef>

#define Bq  16
#define Sq  512
#define Dq  768
#define Hq  12
#define DHq 64
#define Fq  3072
#define SWq 128
#define NTq 8192

typedef float        f32x4  __attribute__((ext_vector_type(4)));
typedef float        f32x16 __attribute__((ext_vector_type(16)));
typedef unsigned int u32x4  __attribute__((ext_vector_type(4)));
typedef __bf16       bf16x8 __attribute__((ext_vector_type(8)));
typedef _Float16     f16x8  __attribute__((ext_vector_type(8)));
typedef _Float16     f16x4  __attribute__((ext_vector_type(4)));
typedef _Float16     f16x2  __attribute__((ext_vector_type(2)));
typedef int          i32x2  __attribute__((ext_vector_type(2)));

__device__ __forceinline__ unsigned short f2bf(float f){
  unsigned int u = __builtin_bit_cast(unsigned int, f);
  u = (u + 0x7fffu + ((u >> 16) & 1u)) >> 16;
  return (unsigned short)u;
}
__device__ __forceinline__ unsigned int pk2(float a, float b){
  return (unsigned int)f2bf(a) | ((unsigned int)f2bf(b) << 16);
}
__device__ __forceinline__ i32x2 pl32swap(unsigned int a, unsigned int b){
  return __builtin_amdgcn_permlane32_swap((int)a, (int)b, false, false);
}
__device__ __forceinline__ f16x2 cvt_pk(float a, float b){
  return __builtin_bit_cast(f16x2, __builtin_amdgcn_cvt_pkrtz(a, b));
}

// Band-supertile + XCD-aware bijective block remap (non-grouped GEMMs).
// Each XCD gets contiguous bands of 8 row-panels x all cols, row-fast within band.
__device__ __forceinline__ void swz2d(int &bx, int &by){
  const int gx = gridDim.x, gy = gridDim.y;
  const int nb = gx * gy;
  const int bid = blockIdx.y * gx + blockIdx.x;
  if (((nb & 7) == 0) && ((gy & 7) == 0)){
    const int chunk = nb >> 3;
    const int lb = (bid & 7) * chunk + (bid >> 3);
    const int bw = gx << 3;              // blocks per band
    const int band = lb / bw;
    const int wn = lb - band * bw;
    bx = wn >> 3;
    by = (band << 3) + (wn & 7);
  } else {
    bx = blockIdx.x; by = blockIdx.y;
  }
}

// ---------------- pooled partial sums (seq router input) ----------------
__global__ void pooled_partial_k(const float* __restrict__ x, float* __restrict__ part){
  const int b = blockIdx.x, dc = blockIdx.y, z = blockIdx.z;
  const int d = dc*256 + threadIdx.x;
  const float* p = x + (size_t)b*Sq*Dq + (size_t)z*128*Dq + d;
  float s = 0.f;
  #pragma unroll 4
  for (int i = 0; i < 128; i++) s += p[(size_t)i*Dq];
  part[((size_t)z*Bq + b)*Dq + d] = s;
}

// ---------------- sequence-level router (exact f32) ----------------
__global__ void router_seq_k(const float* __restrict__ part,
    const float* __restrict__ ew, const float* __restrict__ eb,
    const float* __restrict__ sw, const float* __restrict__ sb,
    int* __restrict__ sel, float* __restrict__ pm)
{
  const int b = blockIdx.x, j = threadIdx.x;   // 128 threads
  __shared__ float h[SWq];
  __shared__ float pl[Dq];
  #pragma unroll
  for (int i = 0; i < 6; i++){
    int d = j + i*128;
    float s = part[(size_t)(0*Bq+b)*Dq + d] + part[(size_t)(1*Bq+b)*Dq + d]
            + part[(size_t)(2*Bq+b)*Dq + d] + part[(size_t)(3*Bq+b)*Dq + d];
    pl[d] = s * (1.0f/512.0f);
  }
  __syncthreads();
  float a = eb[j];
  for (int d = 0; d < Dq; d++) a += pl[d] * ew[d*SWq + j];
  h[j] = a;
  __syncthreads();
  if (j == 0){
    float lg[4];
    for (int e = 0; e < 4; e++){
      float t = sb[e];
      for (int k = 0; k < SWq; k++) t += h[k] * sw[k*4 + e];
      lg[e] = t;
    }
    float mx = fmaxf(fmaxf(lg[0],lg[1]), fmaxf(lg[2],lg[3]));
    float p[4], ssum = 0.f;
    for (int e = 0; e < 4; e++){ p[e] = expf(lg[e]-mx); ssum += p[e]; }
    int am = 0; float bv = p[0];
    for (int e = 1; e < 4; e++) if (p[e] > bv){ bv = p[e]; am = e; }
    sel[b] = am; pm[b] = bv/ssum;
  }
}

// ---------------- f32 -> f16 hi/lo split (x1024 scale) ----------------
__global__ void split_f16_k(const float* __restrict__ x, _Float16* __restrict__ hh,
                            _Float16* __restrict__ ll, int n4){
  const int i = blockIdx.x*256 + threadIdx.x;
  if (i >= n4) return;
  f32x4 v = ((const f32x4*)x)[i];
  f16x4 vh, vl;
  #pragma unroll
  for (int j = 0; j < 4; j++){
    float s = v[j] * 1024.0f;
    _Float16 a = (_Float16)s;
    vh[j] = a;
    vl[j] = (_Float16)(s - (float)a);
  }
  ((f16x4*)hh)[i] = vh;
  ((f16x4*)ll)[i] = vl;
}

// ------- weight transpose + f16 hi/lo split: src [K][N] -> dst [N][K] x1024 -------
__global__ void transpose_f16s_k(const float* __restrict__ src,
    _Float16* __restrict__ dH, _Float16* __restrict__ dL,
    int K, int N, long srcStride, long dstStride, int rowOff)
{
  __shared__ float t[64][65];
  const int tid = threadIdx.x;
  const size_t so = (size_t)blockIdx.z * srcStride;
  const size_t dof = (size_t)blockIdx.z * dstStride;
  const int k0 = blockIdx.y * 64, n0 = blockIdx.x * 64;
  const int r = tid >> 2, c0 = (tid & 3) * 16;
  const float* sp = src + so + (size_t)(k0 + r) * N + n0 + c0;
  #pragma unroll
  for (int cc = 0; cc < 16; cc += 4){
    f32x4 v = *(const f32x4*)(sp + cc);
    t[r][c0+cc] = v[0]; t[r][c0+cc+1] = v[1]; t[r][c0+cc+2] = v[2]; t[r][c0+cc+3] = v[3];
  }
  __syncthreads();
  _Float16* ph = dH + dof + (size_t)(rowOff + n0 + r) * K + k0 + c0;
  _Float16* pl = dL + dof + (size_t)(rowOff + n0 + r) * K + k0 + c0;
  #pragma unroll
  for (int cc = 0; cc < 16; cc += 4){
    f16x4 vh, vl;
    #pragma unroll
    for (int j = 0; j < 4; j++){
      float s = t[c0+cc+j][r] * 1024.0f;
      _Float16 a = (_Float16)s;
      vh[j] = a; vl[j] = (_Float16)(s - (float)a);
    }
    *(f16x4*)(ph + cc) = vh;
    *(f16x4*)(pl + cc) = vl;
  }
}

// ---------------- concat q/k/v biases -> [E][2304] ----------------
__global__ void concat_bias3_k(const float* __restrict__ bq, const float* __restrict__ bk,
    const float* __restrict__ bv, float* __restrict__ dst, int srcStride)
{
  const int e = blockIdx.y;
  const int i = blockIdx.x*256 + threadIdx.x;   // grid.x=3 -> i<768
  dst[(size_t)e*2304 + i]        = bq[(size_t)e*srcStride + i];
  dst[(size_t)e*2304 + 768 + i]  = bk[(size_t)e*srcStride + i];
  dst[(size_t)e*2304 + 1536 + i] = bv[(size_t)e*srcStride + i];
}

// ---------------- split-f16 3-term MFMA GEMM (~f32 accuracy) ----------------
template<int BMODE, int OMODE>
__global__ __launch_bounds__(256,2) void gemm_f16s_k(
    const _Float16* __restrict__ AH, const _Float16* __restrict__ AL,
    const _Float16* __restrict__ BH, const _Float16* __restrict__ BL,
    const float* __restrict__ bias, float* __restrict__ C,
    _Float16* __restrict__ Ch, _Float16* __restrict__ Cl,
    int N, int K, long estride, int bias_stride,
    const int* __restrict__ sel, const float* __restrict__ pm)
{
  __shared__ _Float16 AsH[128][40];
  __shared__ _Float16 AsL[128][40];
  __shared__ _Float16 BsH[128][40];
  __shared__ _Float16 BsL[128][40];
  const int tid = threadIdx.x;
  const int lane = tid & 63, wave = tid >> 6;
  const int wm = wave >> 1, wn = wave & 1;
  int bx, by; swz2d(bx, by);
  const int row0 = by * 128, col0 = bx * 128;
  const _Float16* bh = BH; const _Float16* bl = BL; const float* bp = bias;
  float cs = 1.0f;
  if constexpr (BMODE == 1){
    const int e = sel[row0 >> 9];
    bh += (size_t)e * estride; bl += (size_t)e * estride;
    bp += (size_t)e * bias_stride;
  }
  if constexpr (OMODE == 1) cs = pm[row0 >> 9];

  const int sr = tid >> 1, sk = (tid & 1) * 16;
  const _Float16* ahp = AH + (size_t)(row0 + sr) * K + sk;
  const _Float16* alp = AL + (size_t)(row0 + sr) * K + sk;
  const _Float16* bhp = bh + (size_t)(col0 + sr) * K + sk;
  const _Float16* blp = bl + (size_t)(col0 + sr) * K + sk;

  f32x4 acc[4][4];
  #pragma unroll
  for (int mi=0;mi<4;mi++)
    #pragma unroll
    for (int ni=0;ni<4;ni++) acc[mi][ni] = (f32x4){0.f,0.f,0.f,0.f};

  for (int k0 = 0; k0 < K; k0 += 32){
    u32x4 vah0 = *(const u32x4*)(ahp + k0);
    u32x4 vah1 = *(const u32x4*)(ahp + k0 + 8);
    u32x4 val0 = *(const u32x4*)(alp + k0);
    u32x4 val1 = *(const u32x4*)(alp + k0 + 8);
    u32x4 vbh0 = *(const u32x4*)(bhp + k0);
    u32x4 vbh1 = *(const u32x4*)(bhp + k0 + 8);
    u32x4 vbl0 = *(const u32x4*)(blp + k0);
    u32x4 vbl1 = *(const u32x4*)(blp + k0 + 8);
    __syncthreads();
    *(u32x4*)&AsH[sr][sk]   = vah0; *(u32x4*)&AsH[sr][sk+8] = vah1;
    *(u32x4*)&AsL[sr][sk]   = val0; *(u32x4*)&AsL[sr][sk+8] = val1;
    *(u32x4*)&BsH[sr][sk]   = vbh0; *(u32x4*)&BsH[sr][sk+8] = vbh1;
    *(u32x4*)&BsL[sr][sk]   = vbl0; *(u32x4*)&BsL[sr][sk+8] = vbl1;
    __syncthreads();
    f16x8 fah[4], fal[4], fbh[4], fbl[4];
    #pragma unroll
    for (int mi=0;mi<4;mi++){
      const int r = wm*64 + mi*16 + (lane&15), c = 8*(lane>>4);
      fah[mi] = __builtin_bit_cast(f16x8, *(const u32x4*)&AsH[r][c]);
      fal[mi] = __builtin_bit_cast(f16x8, *(const u32x4*)&AsL[r][c]);
    }
    #pragma unroll
    for (int ni=0;ni<4;ni++){
      const int r = wn*64 + ni*16 + (lane&15), c = 8*(lane>>4);
      fbh[ni] = __builtin_bit_cast(f16x8, *(const u32x4*)&BsH[r][c]);
      fbl[ni] = __builtin_bit_cast(f16x8, *(const u32x4*)&BsL[r][c]);
    }
    #pragma unroll
    for (int mi=0;mi<4;mi++)
      #pragma unroll
      for (int ni=0;ni<4;ni++){
        acc[mi][ni] = __builtin_amdgcn_mfma_f32_16x16x32_f16(fah[mi], fbh[ni], acc[mi][ni], 0, 0, 0);
        acc[mi][ni] = __builtin_amdgcn_mfma_f32_16x16x32_f16(fah[mi], fbl[ni], acc[mi][ni], 0, 0, 0);
        acc[mi][ni] = __builtin_amdgcn_mfma_f32_16x16x32_f16(fal[mi], fbh[ni], acc[mi][ni], 0, 0, 0);
      }
  }

  const float INV = 1.0f/1048576.0f;   // undo 1024*1024 scaling (exact pow2)
  const int erow = 4*(lane >> 4);
  const int ecol = lane & 15;
  #pragma unroll
  for (int mi=0;mi<4;mi++)
    #pragma unroll
    for (int ni=0;ni<4;ni++){
      const int c = col0 + wn*64 + ni*16 + ecol;
      const float bb = bp[c];
      #pragma unroll
      for (int r=0;r<4;r++){
        const int R = row0 + wm*64 + mi*16 + erow + r;
        const float v = acc[mi][ni][r]*INV + bb;
        if constexpr (OMODE == 0){
          C[(size_t)R*N + c] = v;
        } else if constexpr (OMODE == 1){
          C[(size_t)R*N + c] += cs*v;
        } else {
          const float vs = v * 1024.0f;
          const _Float16 hi = (_Float16)vs;
          Ch[(size_t)R*N + c] = hi;
          Cl[(size_t)R*N + c] = (_Float16)(vs - (float)hi);
        }
      }
    }
}

// ------- split-f16 MFMA attention (swapped-QK, in-register softmax) -------
__global__ __launch_bounds__(256,2) void attn_mfma_k(
    const _Float16* __restrict__ qkvH, const _Float16* __restrict__ qkvL,
    const float* __restrict__ mask,
    _Float16* __restrict__ ctxH, _Float16* __restrict__ ctxL)
{
  __shared__ _Float16 Kh[64][72], Kl[64][72];
  __shared__ _Float16 Vh[64][72], Vl[64][72];   // transposed: [d][k]
  __shared__ float msk[64];
  __shared__ float rsi[4][32];
  const int qb = blockIdx.x, h = blockIdx.y, b = blockIdx.z;
  const int tid = threadIdx.x;
  const int l = tid & 63, w = tid >> 6;
  const int l31 = l & 31, g5 = l >> 5;
  const float SC = 1.0f/8388608.0f;   // 2^-20 (split scale) * 1/8 (1/sqrt(64))

  u32x4 qfh[4], qfl[4];
  {
    const size_t qoff = (size_t)(b*Sq + qb*128 + w*32 + l31) * 2304 + h*DHq + g5*8;
    #pragma unroll
    for (int c = 0; c < 4; c++){
      qfh[c] = *(const u32x4*)(qkvH + qoff + c*16);
      qfl[c] = *(const u32x4*)(qkvL + qoff + c*16);
    }
  }
  f32x16 oacc[2];
  #pragma unroll
  for (int nt = 0; nt < 2; nt++)
    #pragma unroll
    for (int i = 0; i < 16; i++) oacc[nt][i] = 0.f;
  float rsl = 0.f;
  const float* mrow = mask + b*Sq;

  for (int kt = 0; kt < 8; kt++){
    __syncthreads();
    {
      const size_t krow = (size_t)(b*Sq + kt*64 + l) * 2304 + 768 + h*DHq;
      #pragma unroll
      for (int i = 0; i < 2; i++){
        const int ch = w + i*4;
        *(u32x4*)&Kh[l][ch*8] = *(const u32x4*)(qkvH + krow + ch*8);
        *(u32x4*)&Kl[l][ch*8] = *(const u32x4*)(qkvL + krow + ch*8);
      }
      const size_t vrow = krow + 768 + w*16;
      f16x8 v0 = __builtin_bit_cast(f16x8, *(const u32x4*)(qkvH + vrow));
      f16x8 v1 = __builtin_bit_cast(f16x8, *(const u32x4*)(qkvH + vrow + 8));
      f16x8 u0 = __builtin_bit_cast(f16x8, *(const u32x4*)(qkvL + vrow));
      f16x8 u1 = __builtin_bit_cast(f16x8, *(const u32x4*)(qkvL + vrow + 8));
      #pragma unroll
      for (int i = 0; i < 8; i++){
        Vh[w*16 + i][l] = v0[i]; Vh[w*16 + 8 + i][l] = v1[i];
        Vl[w*16 + i][l] = u0[i]; Vl[w*16 + 8 + i][l] = u1[i];
      }
      if (tid < 64) msk[tid] = mrow[kt*64 + tid] + 6.9314718055994531f; // + ln(1024)
    }
    __syncthreads();

    f32x16 sacc[2];
    #pragma unroll
    for (int mt = 0; mt < 2; mt++)
      #pragma unroll
      for (int i = 0; i < 16; i++) sacc[mt][i] = 0.f;
    #pragma unroll
    for (int mt = 0; mt < 2; mt++){
      #pragma unroll
      for (int c = 0; c < 4; c++){
        f16x8 kh = __builtin_bit_cast(f16x8, *(const u32x4*)&Kh[mt*32 + l31][c*16 + g5*8]);
        f16x8 kl = __builtin_bit_cast(f16x8, *(const u32x4*)&Kl[mt*32 + l31][c*16 + g5*8]);
        f16x8 qh = __builtin_bit_cast(f16x8, qfh[c]);
        f16x8 ql = __builtin_bit_cast(f16x8, qfl[c]);
        sacc[mt] = __builtin_amdgcn_mfma_f32_32x32x16_f16(kh, qh, sacc[mt], 0, 0, 0);
        sacc[mt] = __builtin_amdgcn_mfma_f32_32x32x16_f16(kh, ql, sacc[mt], 0, 0, 0);
        sacc[mt] = __builtin_amdgcn_mfma_f32_32x32x16_f16(kl, qh, sacc[mt], 0, 0, 0);
      }
    }

    unsigned int hP[2][4][2], lP[2][4][2];
    #pragma unroll
    for (int mt = 0; mt < 2; mt++){
      #pragma unroll
      for (int m = 0; m < 4; m++){
        f32x4 mk = *(const f32x4*)&msk[mt*32 + m*8 + g5*4];
        float p0 = __expf(fmaf(sacc[mt][4*m+0], SC, mk[0]));
        float p1 = __expf(fmaf(sacc[mt][4*m+1], SC, mk[1]));
        float p2 = __expf(fmaf(sacc[mt][4*m+2], SC, mk[2]));
        float p3 = __expf(fmaf(sacc[mt][4*m+3], SC, mk[3]));
        rsl += (p0 + p1) + (p2 + p3);
        f16x2 h0 = cvt_pk(p0, p1);
        f16x2 h1 = cvt_pk(p2, p3);
        f16x2 e0, e1;
        e0[0] = (_Float16)(p0 - (float)h0[0]); e0[1] = (_Float16)(p1 - (float)h0[1]);
        e1[0] = (_Float16)(p2 - (float)h1[0]); e1[1] = (_Float16)(p3 - (float)h1[1]);
        hP[mt][m][0] = __builtin_bit_cast(unsigned int, h0);
        hP[mt][m][1] = __builtin_bit_cast(unsigned int, h1);
        lP[mt][m][0] = __builtin_bit_cast(unsigned int, e0);
        lP[mt][m][1] = __builtin_bit_cast(unsigned int, e1);
      }
    }

    #pragma unroll
    for (int mt = 0; mt < 2; mt++){
      #pragma unroll
      for (int cc = 0; cc < 2; cc++){
        i32x2 sh0 = pl32swap(hP[mt][2*cc][0], hP[mt][2*cc+1][0]);
        i32x2 sh1 = pl32swap(hP[mt][2*cc][1], hP[mt][2*cc+1][1]);
        i32x2 sl0 = pl32swap(lP[mt][2*cc][0], lP[mt][2*cc+1][0]);
        i32x2 sl1 = pl32swap(lP[mt][2*cc][1], lP[mt][2*cc+1][1]);
        u32x4 pah = (u32x4){(unsigned)sh0[0], (unsigned)sh1[0], (unsigned)sh0[1], (unsigned)sh1[1]};
        u32x4 pal = (u32x4){(unsigned)sl0[0], (unsigned)sl1[0], (unsigned)sl0[1], (unsigned)sl1[1]};
        f16x8 ph = __builtin_bit_cast(f16x8, pah);
        f16x8 pe = __builtin_bit_cast(f16x8, pal);
        const int kof = (mt*2 + cc)*16 + g5*8;
        #pragma unroll
        for (int nt = 0; nt < 2; nt++){
          f16x8 vh = __builtin_bit_cast(f16x8, *(const u32x4*)&Vh[nt*32 + l31][kof]);
          f16x8 vl = __builtin_bit_cast(f16x8, *(const u32x4*)&Vl[nt*32 + l31][kof]);
          oacc[nt] = __builtin_amdgcn_mfma_f32_32x32x16_f16(ph, vh, oacc[nt], 0, 0, 0);
          oacc[nt] = __builtin_amdgcn_mfma_f32_32x32x16_f16(ph, vl, oacc[nt], 0, 0, 0);
          oacc[nt] = __builtin_amdgcn_mfma_f32_32x32x16_f16(pe, vh, oacc[nt], 0, 0, 0);
        }
      }
    }
  }

  {
    unsigned int rb = __builtin_bit_cast(unsigned int, rsl);
    i32x2 sw = pl32swap(rb, rb);
    float partner = __builtin_bit_cast(float, (l >= 32) ? sw[0] : sw[1]);
    float tot = rsl + partner;
    if (l < 32) rsi[w][l31] = 1.0f / tot;
  }
  __syncthreads();

  const size_t obase = (size_t)(b*Sq + qb*128 + w*32);
  #pragma unroll
  for (int nt = 0; nt < 2; nt++){
    const int col = h*DHq + nt*32 + l31;
    #pragma unroll
    for (int r = 0; r < 16; r++){
      const int q = (r&3) + 8*(r>>2) + 4*g5;
      const float v = oacc[nt][r] * rsi[w][q];
      const _Float16 hi = (_Float16)v;
      const size_t off = (obase + q)*Dq + col;
      ctxH[off] = hi;
      ctxL[off] = (_Float16)(v - (float)hi);
    }
  }
}

// ---------------- transpose + f32->bf16 (FFN weights -> [N][K] bf16) ----------------
__global__ void transpose_bf16_k(const float* __restrict__ src, unsigned short* __restrict__ dst,
                                 int K, int N)
{
  __shared__ float t[64][65];
  const int tid = threadIdx.x;
  const size_t mo = (size_t)blockIdx.z * K * N;
  const int k0 = blockIdx.y * 64, n0 = blockIdx.x * 64;
  const int r = tid >> 2, c0 = (tid & 3) * 16;
  const float* sp = src + mo + (size_t)(k0 + r) * N + n0 + c0;
  #pragma unroll
  for (int cc = 0; cc < 16; cc += 4){
    f32x4 v = *(const f32x4*)(sp + cc);
    t[r][c0+cc] = v[0]; t[r][c0+cc+1] = v[1]; t[r][c0+cc+2] = v[2]; t[r][c0+cc+3] = v[3];
  }
  __syncthreads();
  unsigned short* dp = dst + mo + (size_t)(n0 + r) * K + k0 + c0;
  u32x4 h0, h1v;
  #pragma unroll
  for (int i = 0; i < 4; i++) h0[i]  = pk2(t[c0+2*i  ][r], t[c0+2*i+1][r]);
  #pragma unroll
  for (int i = 0; i < 4; i++) h1v[i] = pk2(t[c0+8+2*i][r], t[c0+9+2*i][r]);
  *(u32x4*)(dp)     = h0;
  *(u32x4*)(dp + 8) = h1v;
}

// ---------------- bf16 MFMA GEMM (FFN path) ----------------
// MT: 128 or 64 row tile. AMODE: 0 f32 rows; 1 f32 rows via tok_idx; 2 bf16 rows
// OMODE: 0 bf16 store; 1 f32 write+bias; 2 f32 scatter add gate*(res+bias)
template<int MT, int AMODE, int OMODE, bool GELU_, bool GROUPED>
__global__ __launch_bounds__(256,2) void gemm_bf16_k(
    const void* __restrict__ Av, const unsigned short* __restrict__ BT,
    const float* __restrict__ bias, float* __restrict__ Cf, unsigned short* __restrict__ Cb,
    int N, int K,
    const int* __restrict__ tile_g, const int* __restrict__ tile_r0,
    const int* __restrict__ grp_off, const int* __restrict__ n_tiles,
    const int* __restrict__ tok_idx, const float* __restrict__ gate_s,
    size_t bstride, int bias_stride)
{
  constexpr int MI = MT / 32;            // acc rows per wave: 128->4, 64->2
  __shared__ unsigned short As[MT][40];
  __shared__ unsigned short Bs[128][40];
  const int tid = threadIdx.x;
  const int lane = tid & 63, wave = tid >> 6;
  const int wm = wave >> 1, wn = wave & 1;
  int col0, row0, gend = 1 << 30, g = 0;
  if constexpr (GROUPED){
    // col-fast XCD-chunk swizzle: each XCD owns contiguous tiles; blocks of one
    // tile (sharing the A-panel) stay on one XCD; expert-sorted tiles keep B warm.
    const int gx = gridDim.x;
    const int nb = gx * gridDim.y;
    const int bid = blockIdx.y * gx + blockIdx.x;
    int lb = bid;
    if ((nb & 7) == 0) lb = (bid & 7) * (nb >> 3) + (bid >> 3);
    const int t = lb / gx;
    col0 = (lb - t * gx) * 128;
    if (t >= *n_tiles) return;
    g = tile_g[t];
    row0 = grp_off[g] + tile_r0[t];
    gend = grp_off[g+1];
  } else {
    int bx, by; swz2d(bx, by);
    row0 = by * MT;
    col0 = bx * 128;
  }
  const unsigned short* Bp = BT + (size_t)g * bstride;
  const float* bp = bias + (size_t)g * bias_stride;

  const int sa_r = (MT == 128) ? (tid >> 1) : (tid >> 2);
  const int sa_k = (MT == 128) ? ((tid & 1) * 16) : ((tid & 3) * 8);
  const int sb_r = tid >> 1;
  const int sb_k = (tid & 1) * 16;
  int arow = row0 + sa_r;
  if constexpr (GROUPED) arow = (arow < gend - 1) ? arow : (gend - 1);
  if constexpr (AMODE == 1) arow = tok_idx[arow];
  const float*          afp = (const float*)Av          + (size_t)arow * K + sa_k;
  const unsigned short* abp = (const unsigned short*)Av + (size_t)arow * K + sa_k;
  const unsigned short* bfp = Bp + (size_t)(col0 + sb_r) * K + sb_k;

  f32x4 acc[MI][4];
  #pragma unroll
  for (int mi=0;mi<MI;mi++)
    #pragma unroll
    for (int ni=0;ni<4;ni++) acc[mi][ni] = (f32x4){0.f,0.f,0.f,0.f};

  for (int k0 = 0; k0 < K; k0 += 32){
    u32x4 bl0 = *(const u32x4*)(bfp + k0);
    u32x4 bl1 = *(const u32x4*)(bfp + k0 + 8);
    u32x4 al0, al1;
    if constexpr (AMODE == 2){
      al0 = *(const u32x4*)(abp + k0);
      if constexpr (MT == 128) al1 = *(const u32x4*)(abp + k0 + 8);
    } else {
      f32x4 f0 = *(const f32x4*)(afp + k0);
      f32x4 f1 = *(const f32x4*)(afp + k0 + 4);
      al0[0]=pk2(f0[0],f0[1]); al0[1]=pk2(f0[2],f0[3]); al0[2]=pk2(f1[0],f1[1]); al0[3]=pk2(f1[2],f1[3]);
      if constexpr (MT == 128){
        f32x4 f2 = *(const f32x4*)(afp + k0 + 8);
        f32x4 f3 = *(const f32x4*)(afp + k0 + 12);
        al1[0]=pk2(f2[0],f2[1]); al1[1]=pk2(f2[2],f2[3]); al1[2]=pk2(f3[0],f3[1]); al1[3]=pk2(f3[2],f3[3]);
      }
    }
    __syncthreads();
    *(u32x4*)&As[sa_r][sa_k] = al0;
    if constexpr (MT == 128) *(u32x4*)&As[sa_r][sa_k + 8] = al1;
    *(u32x4*)&Bs[sb_r][sb_k]     = bl0;
    *(u32x4*)&Bs[sb_r][sb_k + 8] = bl1;
    __syncthreads();
    bf16x8 af[MI], bfr[4];
    #pragma unroll
    for (int mi=0;mi<MI;mi++){
      u32x4 t = *(const u32x4*)&As[wm*(MT/2) + mi*16 + (lane&15)][8*(lane>>4)];
      af[mi] = __builtin_bit_cast(bf16x8, t);
    }
    #pragma unroll
    for (int ni=0;ni<4;ni++){
      u32x4 t = *(const u32x4*)&Bs[wn*64 + ni*16 + (lane&15)][8*(lane>>4)];
      bfr[ni] = __builtin_bit_cast(bf16x8, t);
    }
    #pragma unroll
    for (int mi=0;mi<MI;mi++)
      #pragma unroll
      for (int ni=0;ni<4;ni++)
        acc[mi][ni] = __builtin_amdgcn_mfma_f32_16x16x32_bf16(af[mi], bfr[ni], acc[mi][ni], 0, 0, 0);
  }

  const int erow = 4*(lane >> 4);
  const int ecol = lane & 15;
  #pragma unroll
  for (int mi=0;mi<MI;mi++)
    #pragma unroll
    for (int ni=0;ni<4;ni++){
      const int c = col0 + wn*64 + ni*16 + ecol;
      const float bb = bp[c];
      #pragma unroll
      for (int r=0;r<4;r++){
        const int R = row0 + wm*(MT/2) + mi*16 + erow + r;
        if (GROUPED && R >= gend) continue;
        float v = acc[mi][ni][r] + bb;
        if (GELU_) v = 0.5f*v*(1.0f + erff(v*0.70710678118654752f));
        if constexpr (OMODE == 0){
          Cb[(size_t)R*N + c] = f2bf(v);
        } else if constexpr (OMODE == 1){
          Cf[(size_t)R*N + c] = v;
        } else {
          const int tok = tok_idx[R];
          const float gt = gate_s[R];
          float* p = Cf + (size_t)tok*N + c;
          *p += gt*v;
        }
      }
    }
}

// ---------------- token-level switch router (f32, one wave/token) ----------------
__global__ void token_router_k(const float* __restrict__ att, const int* __restrict__ sel,
    const float* __restrict__ sww, const float* __restrict__ swb,
    int* __restrict__ grp, float* __restrict__ gate, int* __restrict__ grp_cnt)
{
  const int t = blockIdx.x*4 + (threadIdx.x >> 6);
  const int lane = threadIdx.x & 63;
  const int e = sel[t >> 9];
  const float* x = att + (size_t)t * Dq;
  const float* w = sww + (size_t)e * Dq * 4;
  float a0=0.f, a1=0.f, a2=0.f, a3=0.f;
  #pragma unroll 4
  for (int i = 0; i < 12; i++){
    const int d = lane + i*64;
    const float xv = x[d];
    f32x4 wv = *(const f32x4*)&w[d*4];
    a0 += xv*wv[0]; a1 += xv*wv[1]; a2 += xv*wv[2]; a3 += xv*wv[3];
  }
  #pragma unroll
  for (int off = 32; off; off >>= 1){
    a0 += __shfl_xor(a0, off); a1 += __shfl_xor(a1, off);
    a2 += __shfl_xor(a2, off); a3 += __shfl_xor(a3, off);
  }
  if (lane == 0){
    const float l0 = a0 + swb[e*4+0], l1 = a1 + swb[e*4+1];
    const float l2 = a2 + swb[e*4+2], l3 = a3 + swb[e*4+3];
    const float mx = fmaxf(fmaxf(l0,l1), fmaxf(l2,l3));
    const float p0 = expf(l0-mx), p1 = expf(l1-mx), p2 = expf(l2-mx), p3 = expf(l3-mx);
    const float ssum = p0+p1+p2+p3;
    int am = 0; float bv = p0;
    if (p1 > bv){ bv=p1; am=1; }
    if (p2 > bv){ bv=p2; am=2; }
    if (p3 > bv){ bv=p3; am=3; }
    grp[t] = e*4 + am;
    gate[t] = bv/ssum;
    atomicAdd(&grp_cnt[e*4 + am], 1);
  }
}

__global__ void build_offsets_k(const int* __restrict__ grp_cnt, int* __restrict__ grp_off,
    int* __restrict__ tg128, int* __restrict__ tr128, int* __restrict__ nt128,
    int* __restrict__ tg64, int* __restrict__ tr64, int* __restrict__ nt64)
{
  int off = 0, n1 = 0, n2 = 0;
  for (int g = 0; g < 16; g++){
    grp_off[g] = off;
    const int c = grp_cnt[g];
    for (int r0 = 0; r0 < c; r0 += 128){ tg128[n1] = g; tr128[n1] = r0; n1++; }
    for (int r0 = 0; r0 < c; r0 += 64){  tg64[n2]  = g; tr64[n2]  = r0; n2++; }
    off += c;
  }
  grp_off[16] = off;
  *nt128 = n1; *nt64 = n2;
}

__global__ void scatter_k(const int* __restrict__ grp, const float* __restrict__ gate,
    const int* __restrict__ grp_off, int* __restrict__ fill,
    int* __restrict__ tok_idx, float* __restrict__ gate_s)
{
  const int t = blockIdx.x*256 + threadIdx.x;
  const int g = grp[t];
  const int pos = grp_off[g] + atomicAdd(&fill[g], 1);
  tok_idx[pos] = t;
  gate_s[pos] = gate[t];
}

// ---------------- final residual-add + LayerNorm ----------------
__global__ __launch_bounds__(256) void final_ln_k(const float* __restrict__ att,
    const float* __restrict__ acc, const float* __restrict__ lg,
    const float* __restrict__ lb, float* __restrict__ out)
{
  const int row = blockIdx.x, tid = threadIdx.x;
  const float* a = att + (size_t)row * Dq;
  const float* c = acc + (size_t)row * Dq;
  float x[3];
  #pragma unroll
  for (int i = 0; i < 3; i++) x[i] = a[tid + 256*i] + c[tid + 256*i];
  __shared__ float red[256];
  red[tid] = x[0] + x[1] + x[2];
  __syncthreads();
  for (int st = 128; st; st >>= 1){
    if (tid < st) red[tid] += red[tid + st];
    __syncthreads();
  }
  const float mu = red[0] * (1.0f/768.0f);
  __syncthreads();
  const float d0 = x[0]-mu, d1 = x[1]-mu, d2 = x[2]-mu;
  red[tid] = d0*d0 + d1*d1 + d2*d2;
  __syncthreads();
  for (int st = 128; st; st >>= 1){
    if (tid < st) red[tid] += red[tid + st];
    __syncthreads();
  }
  const float inv = 1.0f/sqrtf(red[0]*(1.0f/768.0f) + 1e-12f);
  #pragma unroll
  for (int i = 0; i < 3; i++){
    const int col = tid + 256*i;
    out[(size_t)row*Dq + col] = (x[i]-mu)*inv*lg[col] + lb[col];
  }
}

// ======================= launch =======================
extern "C" void kernel_launch(void* const* d_in, const int* in_sizes, int n_in,
                              void* d_out, int out_size, void* d_ws, size_t ws_size,
                              hipStream_t stream)
{
  (void)in_sizes; (void)n_in; (void)out_size; (void)ws_size;
  const float* hs    = (const float*)d_in[0];
  const float* amask = (const float*)d_in[1];
  const float* sw_enc_w = (const float*)d_in[3];
  const float* sw_enc_b = (const float*)d_in[4];
  const float* sw_w  = (const float*)d_in[5];
  const float* sw_b  = (const float*)d_in[6];
  const float* ca_wq = (const float*)d_in[7];
  const float* ca_bq = (const float*)d_in[8];
  const float* ca_wk = (const float*)d_in[9];
  const float* ca_bk = (const float*)d_in[10];
  const float* ca_wv = (const float*)d_in[11];
  const float* ca_bv = (const float*)d_in[12];
  const float* ca_wo = (const float*)d_in[13];
  const float* ca_bo = (const float*)d_in[14];
  const float* ua_wq = (const float*)d_in[15];
  const float* ua_bq = (const float*)d_in[16];
  const float* ua_wk = (const float*)d_in[17];
  const float* ua_bk = (const float*)d_in[18];
  const float* ua_wv = (const float*)d_in[19];
  const float* ua_bv = (const float*)d_in[20];
  const float* ua_wo = (const float*)d_in[21];
  const float* ua_bo = (const float*)d_in[22];
  const float* cf_w1 = (const float*)d_in[23];
  const float* cf_b1 = (const float*)d_in[24];
  const float* cf_w2 = (const float*)d_in[25];
  const float* cf_b2 = (const float*)d_in[26];
  const float* uf_sw_w = (const float*)d_in[27];
  const float* uf_sw_b = (const float*)d_in[28];
  const float* uf_w1 = (const float*)d_in[29];
  const float* uf_b1 = (const float*)d_in[30];
  const float* uf_w2 = (const float*)d_in[31];
  const float* uf_b2 = (const float*)d_in[32];
  const float* ln_g  = (const float*)d_in[33];
  const float* ln_b  = (const float*)d_in[34];
  float* out = (float*)d_out;

  char* W = (char*)d_ws;
  // control block
  int*   sel     = (int*)(W + 0);
  float* pm      = (float*)(W + 64);
  int*   grp_cnt = (int*)(W + 128);
  int*   fill    = (int*)(W + 192);
  int*   ntile   = (int*)(W + 256);
  int*   ntile64 = (int*)(W + 320);
  int*   grp_off = (int*)(W + 512);
  int*   tile_g  = (int*)(W + 1024);
  int*   tile_r  = (int*)(W + 2048);
  int*   tile_g64= (int*)(W + 3072);   // up to 144 ints
  int*   tile_r64= (int*)(W + 4096);   // up to 144 ints

  float* att  = (float*)(W + 8192);             // [8192][768] f32
  float* facc = (float*)(W + 25174016);         // [8192][768] f32
  const size_t X = 50339840;
  _Float16* hsH  = (_Float16*)(W + X);                 // 12,582,912
  _Float16* hsL  = (_Float16*)(W + X + 12582912);
  _Float16* qkvH = (_Float16*)(W + X + 25165824);      // 37,748,736
  _Float16* qkvL = (_Float16*)(W + X + 62914560);      // end X+100663296
  _Float16* ctxH = (_Float16*)(W + X + 100663296);     // 12,582,912
  _Float16* ctxL = (_Float16*)(W + X + 113246208);     // end X+125829120
  _Float16* wqkv_cH = (_Float16*)(W + X + 125829120);  // 3,538,944
  _Float16* wqkv_cL = (_Float16*)(W + X + 129368064);
  _Float16* wqkv_uH = (_Float16*)(W + X + 132907008);  // 14,155,776
  _Float16* wqkv_uL = (_Float16*)(W + X + 147062784);
  _Float16* wo_cH   = (_Float16*)(W + X + 161218560);  // 1,179,648
  _Float16* wo_cL   = (_Float16*)(W + X + 162398208);
  _Float16* wo_uH   = (_Float16*)(W + X + 163577856);  // 4,718,592
  _Float16* wo_uL   = (_Float16*)(W + X + 168296448);  // end X+173015040
  float* qkvb_c = (float*)(W + X + 173015040);         // 9,216
  float* qkvb_u = (float*)(W + X + 173024256);         // 36,864
  float* partb  = (float*)(W + X + 173061120);         // 196,608

  // phase B (after attention) reuses phase-A scratch:
  unsigned short* w1T = (unsigned short*)(W + X);              // 80,216,064
  unsigned short* w2T = (unsigned short*)(W + X + 80216064);   // end X+160432128
  unsigned short* h1  = (unsigned short*)(W + X + 160432128);  // 50,331,648 -> ends X+210763776
  int*   grp     = (int*)(W + 261103616);
  float* gate    = (float*)(W + 261136384);
  int*   tok_idx = (int*)(W + 261169152);
  float* gate_s  = (float*)(W + 261201920);    // ends 261234688

  hipMemsetAsync(W, 0, 512, stream);

  // ---- sequence router (exact f32) ----
  pooled_partial_k<<<dim3(Bq,3,4),256,0,stream>>>(hs, partb);
  router_seq_k<<<Bq,128,0,stream>>>(partb, sw_enc_w, sw_enc_b, sw_w, sw_b, sel, pm);

  // ---- prepare split-f16 operands ----
  split_f16_k<<<6144,256,0,stream>>>(hs, hsH, hsL, NTq*Dq/4);
  transpose_f16s_k<<<dim3(12,12,1),256,0,stream>>>(ca_wq, wqkv_cH, wqkv_cL, Dq, Dq, 0, 0, 0);
  transpose_f16s_k<<<dim3(12,12,1),256,0,stream>>>(ca_wk, wqkv_cH, wqkv_cL, Dq, Dq, 0, 0, 768);
  transpose_f16s_k<<<dim3(12,12,1),256,0,stream>>>(ca_wv, wqkv_cH, wqkv_cL, Dq, Dq, 0, 0, 1536);
  transpose_f16s_k<<<dim3(12,12,4),256,0,stream>>>(ua_wq, wqkv_uH, wqkv_uL, Dq, Dq, (long)Dq*Dq, (long)2304*768, 0);
  transpose_f16s_k<<<dim3(12,12,4),256,0,stream>>>(ua_wk, wqkv_uH, wqkv_uL, Dq, Dq, (long)Dq*Dq, (long)2304*768, 768);
  transpose_f16s_k<<<dim3(12,12,4),256,0,stream>>>(ua_wv, wqkv_uH, wqkv_uL, Dq, Dq, (long)Dq*Dq, (long)2304*768, 1536);
  transpose_f16s_k<<<dim3(12,12,1),256,0,stream>>>(ca_wo, wo_cH, wo_cL, Dq, Dq, 0, 0, 0);
  transpose_f16s_k<<<dim3(12,12,4),256,0,stream>>>(ua_wo, wo_uH, wo_uL, Dq, Dq, (long)Dq*Dq, (long)Dq*Dq, 0);
  concat_bias3_k<<<dim3(3,1),256,0,stream>>>(ca_bq, ca_bk, ca_bv, qkvb_c, 0);
  concat_bias3_k<<<dim3(3,4),256,0,stream>>>(ua_bq, ua_bk, ua_bv, qkvb_u, 768);

  // ---- common attention ----
  gemm_f16s_k<0,2><<<dim3(18,64),256,0,stream>>>(hsH, hsL, wqkv_cH, wqkv_cL, qkvb_c,
      nullptr, qkvH, qkvL, 2304, Dq, 0, 0, nullptr, nullptr);
  attn_mfma_k<<<dim3(4,Hq,Bq),256,0,stream>>>(qkvH, qkvL, amask, ctxH, ctxL);
  gemm_f16s_k<0,0><<<dim3(6,64),256,0,stream>>>(ctxH, ctxL, wo_cH, wo_cL, ca_bo,
      att, nullptr, nullptr, Dq, Dq, 0, 0, nullptr, nullptr);

  // ---- unique attention (selected expert), att += pm * result ----
  gemm_f16s_k<1,2><<<dim3(18,64),256,0,stream>>>(hsH, hsL, wqkv_uH, wqkv_uL, qkvb_u,
      nullptr, qkvH, qkvL, 2304, Dq, (long)2304*768, 2304, sel, nullptr);
  attn_mfma_k<<<dim3(4,Hq,Bq),256,0,stream>>>(qkvH, qkvL, amask, ctxH, ctxL);
  gemm_f16s_k<1,1><<<dim3(6,64),256,0,stream>>>(ctxH, ctxL, wo_uH, wo_uL, ua_bo,
      att, nullptr, nullptr, Dq, Dq, (long)Dq*Dq, Dq, sel, pm);

  // ---- FFN weights -> transposed bf16 (phase-A scratch now free) ----
  transpose_bf16_k<<<dim3(48,12,1), 256,0,stream>>>(cf_w1, w1T, Dq, Fq);
  transpose_bf16_k<<<dim3(48,12,16),256,0,stream>>>(uf_w1, w1T + 2359296, Dq, Fq);
  transpose_bf16_k<<<dim3(12,48,1), 256,0,stream>>>(cf_w2, w2T, Fq, Dq);
  transpose_bf16_k<<<dim3(12,48,16),256,0,stream>>>(uf_w2, w2T + 2359296, Fq, Dq);

  // ---- common FFN (bf16 MFMA) ----
  gemm_bf16_k<128,0,0,true,false><<<dim3(24,64),256,0,stream>>>((const void*)att, w1T, cf_b1, nullptr, h1,
      Fq, Dq, nullptr,nullptr,nullptr,nullptr,nullptr,nullptr, (size_t)0, 0);
  gemm_bf16_k<64,2,1,false,false><<<dim3(6,128),256,0,stream>>>((const void*)h1, w2T, cf_b2, facc, nullptr,
      Dq, Fq, nullptr,nullptr,nullptr,nullptr,nullptr,nullptr, (size_t)0, 0);

  // ---- token routing (f32, on accurate att) ----
  token_router_k<<<2048,256,0,stream>>>(att, sel, uf_sw_w, uf_sw_b, grp, gate, grp_cnt);
  build_offsets_k<<<1,1,0,stream>>>(grp_cnt, grp_off, tile_g, tile_r, ntile, tile_g64, tile_r64, ntile64);
  scatter_k<<<32,256,0,stream>>>(grp, gate, grp_off, fill, tok_idx, gate_s);

  // ---- unique FFN (grouped, top-1 inner expert, gated scatter-add) ----
  gemm_bf16_k<128,1,0,true,true><<<dim3(24,80),256,0,stream>>>((const void*)att, w1T + 2359296, uf_b1, nullptr, h1,
      Fq, Dq, tile_g, tile_r, grp_off, ntile, tok_idx, gate_s, (size_t)2359296, Fq);
  gemm_bf16_k<64,2,2,false,true><<<dim3(6,144),256,0,stream>>>((const void*)h1, w2T + 2359296, uf_b2, facc, nullptr,
      Dq, Fq, tile_g64, tile_r64, grp_off, ntile64, tok_idx, gate_s, (size_t)2359296, Dq);

  // ---- residual + LayerNorm ----
  final_ln_k<<<NTq,256,0,stream>>>(att, facc, ln_g, ln_b, out);
}

// Round 7
// 1151.080 us; speedup vs baseline: 2.0540x; 1.0569x over previous
//
#include <hip/hip_runtime.h>
#include <cstdint>
#include <cstddef>

#define Bq  16
#define Sq  512
#define Dq  768
#define Hq  12
#define DHq 64
#define Fq  3072
#define SWq 128
#define NTq 8192

typedef float        f32x4  __attribute__((ext_vector_type(4)));
typedef float        f32x16 __attribute__((ext_vector_type(16)));
typedef unsigned int u32x4  __attribute__((ext_vector_type(4)));
typedef __bf16       bf16x8 __attribute__((ext_vector_type(8)));
typedef _Float16     f16x8  __attribute__((ext_vector_type(8)));
typedef _Float16     f16x4  __attribute__((ext_vector_type(4)));
typedef _Float16     f16x2  __attribute__((ext_vector_type(2)));
typedef int          i32x2  __attribute__((ext_vector_type(2)));

__device__ __forceinline__ unsigned short f2bf(float f){
  unsigned int u = __builtin_bit_cast(unsigned int, f);
  u = (u + 0x7fffu + ((u >> 16) & 1u)) >> 16;
  return (unsigned short)u;
}
__device__ __forceinline__ unsigned int pk2(float a, float b){
  return (unsigned int)f2bf(a) | ((unsigned int)f2bf(b) << 16);
}
__device__ __forceinline__ i32x2 pl32swap(unsigned int a, unsigned int b){
  return __builtin_amdgcn_permlane32_swap((int)a, (int)b, false, false);
}
__device__ __forceinline__ f16x2 cvt_pk(float a, float b){
  return __builtin_bit_cast(f16x2, __builtin_amdgcn_cvt_pkrtz(a, b));
}

// async global->LDS DMA, 16B per lane. LDS dest = wave-uniform base + lane*16.
typedef __attribute__((address_space(1))) void vg_t;
typedef __attribute__((address_space(3))) void vl_t;
__device__ __forceinline__ void gl_lds16(const void* g, void* l){
  __builtin_amdgcn_global_load_lds((vg_t*)g, (vl_t*)l, 16, 0, 0);
}

// Band-supertile + XCD-aware bijective block remap (non-grouped GEMMs).
__device__ __forceinline__ void swz2d(int &bx, int &by){
  const int gx = gridDim.x, gy = gridDim.y;
  const int nb = gx * gy;
  const int bid = blockIdx.y * gx + blockIdx.x;
  if (((nb & 7) == 0) && ((gy & 7) == 0)){
    const int chunk = nb >> 3;
    const int lb = (bid & 7) * chunk + (bid >> 3);
    const int bw = gx << 3;              // blocks per band
    const int band = lb / bw;
    const int wn = lb - band * bw;
    bx = wn >> 3;
    by = (band << 3) + (wn & 7);
  } else {
    bx = blockIdx.x; by = blockIdx.y;
  }
}

// ---------------- pooled partial sums (seq router input) ----------------
__global__ void pooled_partial_k(const float* __restrict__ x, float* __restrict__ part){
  const int b = blockIdx.x, dc = blockIdx.y, z = blockIdx.z;
  const int d = dc*256 + threadIdx.x;
  const float* p = x + (size_t)b*Sq*Dq + (size_t)z*128*Dq + d;
  float s = 0.f;
  #pragma unroll 4
  for (int i = 0; i < 128; i++) s += p[(size_t)i*Dq];
  part[((size_t)z*Bq + b)*Dq + d] = s;
}

// ---------------- sequence-level router (exact f32) ----------------
__global__ void router_seq_k(const float* __restrict__ part,
    const float* __restrict__ ew, const float* __restrict__ eb,
    const float* __restrict__ sw, const float* __restrict__ sb,
    int* __restrict__ sel, float* __restrict__ pm)
{
  const int b = blockIdx.x, j = threadIdx.x;   // 128 threads
  __shared__ float h[SWq];
  __shared__ float pl[Dq];
  #pragma unroll
  for (int i = 0; i < 6; i++){
    int d = j + i*128;
    float s = part[(size_t)(0*Bq+b)*Dq + d] + part[(size_t)(1*Bq+b)*Dq + d]
            + part[(size_t)(2*Bq+b)*Dq + d] + part[(size_t)(3*Bq+b)*Dq + d];
    pl[d] = s * (1.0f/512.0f);
  }
  __syncthreads();
  float a = eb[j];
  for (int d = 0; d < Dq; d++) a += pl[d] * ew[d*SWq + j];
  h[j] = a;
  __syncthreads();
  if (j == 0){
    float lg[4];
    for (int e = 0; e < 4; e++){
      float t = sb[e];
      for (int k = 0; k < SWq; k++) t += h[k] * sw[k*4 + e];
      lg[e] = t;
    }
    float mx = fmaxf(fmaxf(lg[0],lg[1]), fmaxf(lg[2],lg[3]));
    float p[4], ssum = 0.f;
    for (int e = 0; e < 4; e++){ p[e] = expf(lg[e]-mx); ssum += p[e]; }
    int am = 0; float bv = p[0];
    for (int e = 1; e < 4; e++) if (p[e] > bv){ bv = p[e]; am = e; }
    sel[b] = am; pm[b] = bv/ssum;
  }
}

// ---------------- f32 -> f16 hi/lo split (x1024 scale) ----------------
__global__ void split_f16_k(const float* __restrict__ x, _Float16* __restrict__ hh,
                            _Float16* __restrict__ ll, int n4){
  const int i = blockIdx.x*256 + threadIdx.x;
  if (i >= n4) return;
  f32x4 v = ((const f32x4*)x)[i];
  f16x4 vh, vl;
  #pragma unroll
  for (int j = 0; j < 4; j++){
    float s = v[j] * 1024.0f;
    _Float16 a = (_Float16)s;
    vh[j] = a;
    vl[j] = (_Float16)(s - (float)a);
  }
  ((f16x4*)hh)[i] = vh;
  ((f16x4*)ll)[i] = vl;
}

// ------- weight transpose + f16 hi/lo split: src [K][N] -> dst [N][K] x1024 -------
__global__ void transpose_f16s_k(const float* __restrict__ src,
    _Float16* __restrict__ dH, _Float16* __restrict__ dL,
    int K, int N, long srcStride, long dstStride, int rowOff)
{
  __shared__ float t[64][65];
  const int tid = threadIdx.x;
  const size_t so = (size_t)blockIdx.z * srcStride;
  const size_t dof = (size_t)blockIdx.z * dstStride;
  const int k0 = blockIdx.y * 64, n0 = blockIdx.x * 64;
  const int r = tid >> 2, c0 = (tid & 3) * 16;
  const float* sp = src + so + (size_t)(k0 + r) * N + n0 + c0;
  #pragma unroll
  for (int cc = 0; cc < 16; cc += 4){
    f32x4 v = *(const f32x4*)(sp + cc);
    t[r][c0+cc] = v[0]; t[r][c0+cc+1] = v[1]; t[r][c0+cc+2] = v[2]; t[r][c0+cc+3] = v[3];
  }
  __syncthreads();
  _Float16* ph = dH + dof + (size_t)(rowOff + n0 + r) * K + k0 + c0;
  _Float16* pl = dL + dof + (size_t)(rowOff + n0 + r) * K + k0 + c0;
  #pragma unroll
  for (int cc = 0; cc < 16; cc += 4){
    f16x4 vh, vl;
    #pragma unroll
    for (int j = 0; j < 4; j++){
      float s = t[c0+cc+j][r] * 1024.0f;
      _Float16 a = (_Float16)s;
      vh[j] = a; vl[j] = (_Float16)(s - (float)a);
    }
    *(f16x4*)(ph + cc) = vh;
    *(f16x4*)(pl + cc) = vl;
  }
}

// ---------------- concat q/k/v biases -> [E][2304] ----------------
__global__ void concat_bias3_k(const float* __restrict__ bq, const float* __restrict__ bk,
    const float* __restrict__ bv, float* __restrict__ dst, int srcStride)
{
  const int e = blockIdx.y;
  const int i = blockIdx.x*256 + threadIdx.x;   // grid.x=3 -> i<768
  dst[(size_t)e*2304 + i]        = bq[(size_t)e*srcStride + i];
  dst[(size_t)e*2304 + 768 + i]  = bk[(size_t)e*srcStride + i];
  dst[(size_t)e*2304 + 1536 + i] = bv[(size_t)e*srcStride + i];
}

// ---------------- split-f16 3-term MFMA GEMM, global_load_lds staging ----------------
template<int BMODE, int OMODE>
__global__ __launch_bounds__(256,2) void gemm_f16s_k(
    const _Float16* __restrict__ AH, const _Float16* __restrict__ AL,
    const _Float16* __restrict__ BH, const _Float16* __restrict__ BL,
    const float* __restrict__ bias, float* __restrict__ C,
    _Float16* __restrict__ Ch, _Float16* __restrict__ Cl,
    int N, int K, long estride, int bias_stride,
    const int* __restrict__ sel, const float* __restrict__ pm)
{
  __shared__ _Float16 AsH[128][32];
  __shared__ _Float16 AsL[128][32];
  __shared__ _Float16 BsH[128][32];
  __shared__ _Float16 BsL[128][32];
  const int tid = threadIdx.x;
  const int lane = tid & 63, wave = tid >> 6;
  const int wm = wave >> 1, wn = wave & 1;
  int bx, by; swz2d(bx, by);
  const int row0 = by * 128, col0 = bx * 128;
  const _Float16* bh = BH; const _Float16* bl = BL; const float* bp = bias;
  float cs = 1.0f;
  if constexpr (BMODE == 1){
    const int e = sel[row0 >> 9];
    bh += (size_t)e * estride; bl += (size_t)e * estride;
    bp += (size_t)e * bias_stride;
  }
  if constexpr (OMODE == 1) cs = pm[row0 >> 9];

  // DMA staging: tile 128x32 f16 = 8KB = 8 x 1KB instrs; wave w issues j=0,1 per tile.
  const int lr = lane >> 2, lk = (lane & 3) * 8;
  const _Float16 *pAH[2], *pAL[2], *pBH[2], *pBL[2];
  _Float16 *lAH[2], *lAL[2], *lBH[2], *lBL[2];
  #pragma unroll
  for (int j = 0; j < 2; j++){
    const int ia = wave*2 + j;
    pAH[j] = AH + (size_t)(row0 + ia*16 + lr)*K + lk;
    pAL[j] = AL + (size_t)(row0 + ia*16 + lr)*K + lk;
    pBH[j] = bh + (size_t)(col0 + ia*16 + lr)*K + lk;
    pBL[j] = bl + (size_t)(col0 + ia*16 + lr)*K + lk;
    lAH[j] = &AsH[0][0] + ia*512;
    lAL[j] = &AsL[0][0] + ia*512;
    lBH[j] = &BsH[0][0] + ia*512;
    lBL[j] = &BsL[0][0] + ia*512;
  }

  f32x4 acc[4][4];
  #pragma unroll
  for (int mi=0;mi<4;mi++)
    #pragma unroll
    for (int ni=0;ni<4;ni++) acc[mi][ni] = (f32x4){0.f,0.f,0.f,0.f};

  for (int k0 = 0; k0 < K; k0 += 32){
    __syncthreads();
    #pragma unroll
    for (int j = 0; j < 2; j++){
      gl_lds16(pAH[j] + k0, lAH[j]);
      gl_lds16(pAL[j] + k0, lAL[j]);
      gl_lds16(pBH[j] + k0, lBH[j]);
      gl_lds16(pBL[j] + k0, lBL[j]);
    }
    __syncthreads();
    f16x8 fah[4], fal[4], fbh[4], fbl[4];
    #pragma unroll
    for (int mi=0;mi<4;mi++){
      const int r = wm*64 + mi*16 + (lane&15), c = 8*(lane>>4);
      fah[mi] = __builtin_bit_cast(f16x8, *(const u32x4*)&AsH[r][c]);
      fal[mi] = __builtin_bit_cast(f16x8, *(const u32x4*)&AsL[r][c]);
    }
    #pragma unroll
    for (int ni=0;ni<4;ni++){
      const int r = wn*64 + ni*16 + (lane&15), c = 8*(lane>>4);
      fbh[ni] = __builtin_bit_cast(f16x8, *(const u32x4*)&BsH[r][c]);
      fbl[ni] = __builtin_bit_cast(f16x8, *(const u32x4*)&BsL[r][c]);
    }
    #pragma unroll
    for (int mi=0;mi<4;mi++)
      #pragma unroll
      for (int ni=0;ni<4;ni++){
        acc[mi][ni] = __builtin_amdgcn_mfma_f32_16x16x32_f16(fah[mi], fbh[ni], acc[mi][ni], 0, 0, 0);
        acc[mi][ni] = __builtin_amdgcn_mfma_f32_16x16x32_f16(fah[mi], fbl[ni], acc[mi][ni], 0, 0, 0);
        acc[mi][ni] = __builtin_amdgcn_mfma_f32_16x16x32_f16(fal[mi], fbh[ni], acc[mi][ni], 0, 0, 0);
      }
  }

  const float INV = 1.0f/1048576.0f;   // undo 1024*1024 scaling (exact pow2)
  const int erow = 4*(lane >> 4);
  const int ecol = lane & 15;
  #pragma unroll
  for (int mi=0;mi<4;mi++)
    #pragma unroll
    for (int ni=0;ni<4;ni++){
      const int c = col0 + wn*64 + ni*16 + ecol;
      const float bb = bp[c];
      #pragma unroll
      for (int r=0;r<4;r++){
        const int R = row0 + wm*64 + mi*16 + erow + r;
        const float v = acc[mi][ni][r]*INV + bb;
        if constexpr (OMODE == 0){
          C[(size_t)R*N + c] = v;
        } else if constexpr (OMODE == 1){
          C[(size_t)R*N + c] += cs*v;
        } else {
          const float vs = v * 1024.0f;
          const _Float16 hi = (_Float16)vs;
          Ch[(size_t)R*N + c] = hi;
          Cl[(size_t)R*N + c] = (_Float16)(vs - (float)hi);
        }
      }
    }
}

// ------- split-f16 MFMA attention (swapped-QK, in-register softmax) -------
__global__ __launch_bounds__(256,2) void attn_mfma_k(
    const _Float16* __restrict__ qkvH, const _Float16* __restrict__ qkvL,
    const float* __restrict__ mask,
    _Float16* __restrict__ ctxH, _Float16* __restrict__ ctxL)
{
  __shared__ _Float16 Kh[64][72], Kl[64][72];
  __shared__ _Float16 Vh[64][72], Vl[64][72];   // transposed: [d][k]
  __shared__ float msk[64];
  __shared__ float rsi[4][32];
  const int qb = blockIdx.x, h = blockIdx.y, b = blockIdx.z;
  const int tid = threadIdx.x;
  const int l = tid & 63, w = tid >> 6;
  const int l31 = l & 31, g5 = l >> 5;
  const float SC = 1.0f/8388608.0f;   // 2^-20 (split scale) * 1/8 (1/sqrt(64))

  u32x4 qfh[4], qfl[4];
  {
    const size_t qoff = (size_t)(b*Sq + qb*128 + w*32 + l31) * 2304 + h*DHq + g5*8;
    #pragma unroll
    for (int c = 0; c < 4; c++){
      qfh[c] = *(const u32x4*)(qkvH + qoff + c*16);
      qfl[c] = *(const u32x4*)(qkvL + qoff + c*16);
    }
  }
  f32x16 oacc[2];
  #pragma unroll
  for (int nt = 0; nt < 2; nt++)
    #pragma unroll
    for (int i = 0; i < 16; i++) oacc[nt][i] = 0.f;
  float rsl = 0.f;
  const float* mrow = mask + b*Sq;

  for (int kt = 0; kt < 8; kt++){
    __syncthreads();
    {
      const size_t krow = (size_t)(b*Sq + kt*64 + l) * 2304 + 768 + h*DHq;
      #pragma unroll
      for (int i = 0; i < 2; i++){
        const int ch = w + i*4;
        *(u32x4*)&Kh[l][ch*8] = *(const u32x4*)(qkvH + krow + ch*8);
        *(u32x4*)&Kl[l][ch*8] = *(const u32x4*)(qkvL + krow + ch*8);
      }
      const size_t vrow = krow + 768 + w*16;
      f16x8 v0 = __builtin_bit_cast(f16x8, *(const u32x4*)(qkvH + vrow));
      f16x8 v1 = __builtin_bit_cast(f16x8, *(const u32x4*)(qkvH + vrow + 8));
      f16x8 u0 = __builtin_bit_cast(f16x8, *(const u32x4*)(qkvL + vrow));
      f16x8 u1 = __builtin_bit_cast(f16x8, *(const u32x4*)(qkvL + vrow + 8));
      #pragma unroll
      for (int i = 0; i < 8; i++){
        Vh[w*16 + i][l] = v0[i]; Vh[w*16 + 8 + i][l] = v1[i];
        Vl[w*16 + i][l] = u0[i]; Vl[w*16 + 8 + i][l] = u1[i];
      }
      if (tid < 64) msk[tid] = mrow[kt*64 + tid] + 6.9314718055994531f; // + ln(1024)
    }
    __syncthreads();

    f32x16 sacc[2];
    #pragma unroll
    for (int mt = 0; mt < 2; mt++)
      #pragma unroll
      for (int i = 0; i < 16; i++) sacc[mt][i] = 0.f;
    #pragma unroll
    for (int mt = 0; mt < 2; mt++){
      #pragma unroll
      for (int c = 0; c < 4; c++){
        f16x8 kh = __builtin_bit_cast(f16x8, *(const u32x4*)&Kh[mt*32 + l31][c*16 + g5*8]);
        f16x8 kl = __builtin_bit_cast(f16x8, *(const u32x4*)&Kl[mt*32 + l31][c*16 + g5*8]);
        f16x8 qh = __builtin_bit_cast(f16x8, qfh[c]);
        f16x8 ql = __builtin_bit_cast(f16x8, qfl[c]);
        sacc[mt] = __builtin_amdgcn_mfma_f32_32x32x16_f16(kh, qh, sacc[mt], 0, 0, 0);
        sacc[mt] = __builtin_amdgcn_mfma_f32_32x32x16_f16(kh, ql, sacc[mt], 0, 0, 0);
        sacc[mt] = __builtin_amdgcn_mfma_f32_32x32x16_f16(kl, qh, sacc[mt], 0, 0, 0);
      }
    }

    unsigned int hP[2][4][2], lP[2][4][2];
    #pragma unroll
    for (int mt = 0; mt < 2; mt++){
      #pragma unroll
      for (int m = 0; m < 4; m++){
        f32x4 mk = *(const f32x4*)&msk[mt*32 + m*8 + g5*4];
        float p0 = __expf(fmaf(sacc[mt][4*m+0], SC, mk[0]));
        float p1 = __expf(fmaf(sacc[mt][4*m+1], SC, mk[1]));
        float p2 = __expf(fmaf(sacc[mt][4*m+2], SC, mk[2]));
        float p3 = __expf(fmaf(sacc[mt][4*m+3], SC, mk[3]));
        rsl += (p0 + p1) + (p2 + p3);
        f16x2 h0 = cvt_pk(p0, p1);
        f16x2 h1 = cvt_pk(p2, p3);
        f16x2 e0, e1;
        e0[0] = (_Float16)(p0 - (float)h0[0]); e0[1] = (_Float16)(p1 - (float)h0[1]);
        e1[0] = (_Float16)(p2 - (float)h1[0]); e1[1] = (_Float16)(p3 - (float)h1[1]);
        hP[mt][m][0] = __builtin_bit_cast(unsigned int, h0);
        hP[mt][m][1] = __builtin_bit_cast(unsigned int, h1);
        lP[mt][m][0] = __builtin_bit_cast(unsigned int, e0);
        lP[mt][m][1] = __builtin_bit_cast(unsigned int, e1);
      }
    }

    #pragma unroll
    for (int mt = 0; mt < 2; mt++){
      #pragma unroll
      for (int cc = 0; cc < 2; cc++){
        i32x2 sh0 = pl32swap(hP[mt][2*cc][0], hP[mt][2*cc+1][0]);
        i32x2 sh1 = pl32swap(hP[mt][2*cc][1], hP[mt][2*cc+1][1]);
        i32x2 sl0 = pl32swap(lP[mt][2*cc][0], lP[mt][2*cc+1][0]);
        i32x2 sl1 = pl32swap(lP[mt][2*cc][1], lP[mt][2*cc+1][1]);
        u32x4 pah = (u32x4){(unsigned)sh0[0], (unsigned)sh1[0], (unsigned)sh0[1], (unsigned)sh1[1]};
        u32x4 pal = (u32x4){(unsigned)sl0[0], (unsigned)sl1[0], (unsigned)sl0[1], (unsigned)sl1[1]};
        f16x8 ph = __builtin_bit_cast(f16x8, pah);
        f16x8 pe = __builtin_bit_cast(f16x8, pal);
        const int kof = (mt*2 + cc)*16 + g5*8;
        #pragma unroll
        for (int nt = 0; nt < 2; nt++){
          f16x8 vh = __builtin_bit_cast(f16x8, *(const u32x4*)&Vh[nt*32 + l31][kof]);
          f16x8 vl = __builtin_bit_cast(f16x8, *(const u32x4*)&Vl[nt*32 + l31][kof]);
          oacc[nt] = __builtin_amdgcn_mfma_f32_32x32x16_f16(ph, vh, oacc[nt], 0, 0, 0);
          oacc[nt] = __builtin_amdgcn_mfma_f32_32x32x16_f16(ph, vl, oacc[nt], 0, 0, 0);
          oacc[nt] = __builtin_amdgcn_mfma_f32_32x32x16_f16(pe, vh, oacc[nt], 0, 0, 0);
        }
      }
    }
  }

  {
    unsigned int rb = __builtin_bit_cast(unsigned int, rsl);
    i32x2 sw = pl32swap(rb, rb);
    float partner = __builtin_bit_cast(float, (l >= 32) ? sw[0] : sw[1]);
    float tot = rsl + partner;
    if (l < 32) rsi[w][l31] = 1.0f / tot;
  }
  __syncthreads();

  const size_t obase = (size_t)(b*Sq + qb*128 + w*32);
  #pragma unroll
  for (int nt = 0; nt < 2; nt++){
    const int col = h*DHq + nt*32 + l31;
    #pragma unroll
    for (int r = 0; r < 16; r++){
      const int q = (r&3) + 8*(r>>2) + 4*g5;
      const float v = oacc[nt][r] * rsi[w][q];
      const _Float16 hi = (_Float16)v;
      const size_t off = (obase + q)*Dq + col;
      ctxH[off] = hi;
      ctxL[off] = (_Float16)(v - (float)hi);
    }
  }
}

// ---------------- transpose + f32->bf16 (FFN weights -> [N][K] bf16) ----------------
__global__ void transpose_bf16_k(const float* __restrict__ src, unsigned short* __restrict__ dst,
                                 int K, int N)
{
  __shared__ float t[64][65];
  const int tid = threadIdx.x;
  const size_t mo = (size_t)blockIdx.z * K * N;
  const int k0 = blockIdx.y * 64, n0 = blockIdx.x * 64;
  const int r = tid >> 2, c0 = (tid & 3) * 16;
  const float* sp = src + mo + (size_t)(k0 + r) * N + n0 + c0;
  #pragma unroll
  for (int cc = 0; cc < 16; cc += 4){
    f32x4 v = *(const f32x4*)(sp + cc);
    t[r][c0+cc] = v[0]; t[r][c0+cc+1] = v[1]; t[r][c0+cc+2] = v[2]; t[r][c0+cc+3] = v[3];
  }
  __syncthreads();
  unsigned short* dp = dst + mo + (size_t)(n0 + r) * K + k0 + c0;
  u32x4 h0, h1v;
  #pragma unroll
  for (int i = 0; i < 4; i++) h0[i]  = pk2(t[c0+2*i  ][r], t[c0+2*i+1][r]);
  #pragma unroll
  for (int i = 0; i < 4; i++) h1v[i] = pk2(t[c0+8+2*i][r], t[c0+9+2*i][r]);
  *(u32x4*)(dp)     = h0;
  *(u32x4*)(dp + 8) = h1v;
}

// ---------------- bf16 MFMA GEMM (FFN path), global_load_lds staging ----------------
// MT: 128 or 64 row tile. AMODE: 0 f32 rows reg-staged; 1 f32 rows via tok_idx; 2 bf16 DMA
// OMODE: 0 bf16 store; 1 f32 write+bias; 2 f32 scatter add gate*(res+bias)
template<int MT, int AMODE, int OMODE, bool GELU_, bool GROUPED>
__global__ __launch_bounds__(256,2) void gemm_bf16_k(
    const void* __restrict__ Av, const unsigned short* __restrict__ BT,
    const float* __restrict__ bias, float* __restrict__ Cf, unsigned short* __restrict__ Cb,
    int N, int K,
    const int* __restrict__ tile_g, const int* __restrict__ tile_r0,
    const int* __restrict__ grp_off, const int* __restrict__ n_tiles,
    const int* __restrict__ tok_idx, const float* __restrict__ gate_s,
    size_t bstride, int bias_stride)
{
  constexpr int MI = MT / 32;            // acc rows per wave
  constexpr int AI = MT / 64;            // A DMA instrs per wave (AMODE==2)
  __shared__ unsigned short As[MT][32];
  __shared__ unsigned short Bs[128][32];
  const int tid = threadIdx.x;
  const int lane = tid & 63, wave = tid >> 6;
  const int wm = wave >> 1, wn = wave & 1;
  int col0, row0, gend = 1 << 30, g = 0;
  if constexpr (GROUPED){
    const int gx = gridDim.x;
    const int nb = gx * gridDim.y;
    const int bid = blockIdx.y * gx + blockIdx.x;
    int lb = bid;
    if ((nb & 7) == 0) lb = (bid & 7) * (nb >> 3) + (bid >> 3);
    const int t = lb / gx;
    col0 = (lb - t * gx) * 128;
    if (t >= *n_tiles) return;
    g = tile_g[t];
    row0 = grp_off[g] + tile_r0[t];
    gend = grp_off[g+1];
  } else {
    int bx, by; swz2d(bx, by);
    row0 = by * MT;
    col0 = bx * 128;
  }
  const unsigned short* Bp = BT + (size_t)g * bstride;
  const float* bp = bias + (size_t)g * bias_stride;

  const int lr = lane >> 2, lk8 = (lane & 3) * 8;
  // B staging: always DMA (2 x 1KB per wave)
  const unsigned short* pB[2]; unsigned short* lB[2];
  #pragma unroll
  for (int j = 0; j < 2; j++){
    const int ib = wave*2 + j;
    pB[j] = Bp + (size_t)(col0 + ib*16 + lr)*K + lk8;
    lB[j] = &Bs[0][0] + ib*512;
  }
  // A staging
  const unsigned short* pA2[AI]; unsigned short* lA2[AI];
  const float* afp = nullptr; int sa_r = 0, sa_k = 0;
  if constexpr (AMODE == 2){
    #pragma unroll
    for (int j = 0; j < AI; j++){
      int r = row0 + (wave*AI + j)*16 + lr;
      if constexpr (GROUPED) r = (r < gend - 1) ? r : (gend - 1);
      pA2[j] = (const unsigned short*)Av + (size_t)r*K + lk8;
      lA2[j] = &As[0][0] + (wave*AI + j)*512;
    }
  } else {
    sa_r = (MT == 128) ? (tid >> 1) : (tid >> 2);
    sa_k = (MT == 128) ? ((tid & 1) * 16) : ((tid & 3) * 8);
    int arow = row0 + sa_r;
    if constexpr (GROUPED) arow = (arow < gend - 1) ? arow : (gend - 1);
    if constexpr (AMODE == 1) arow = tok_idx[arow];
    afp = (const float*)Av + (size_t)arow * K + sa_k;
  }

  f32x4 acc[MI][4];
  #pragma unroll
  for (int mi=0;mi<MI;mi++)
    #pragma unroll
    for (int ni=0;ni<4;ni++) acc[mi][ni] = (f32x4){0.f,0.f,0.f,0.f};

  for (int k0 = 0; k0 < K; k0 += 32){
    u32x4 al0, al1;
    if constexpr (AMODE != 2){
      f32x4 f0 = *(const f32x4*)(afp + k0);
      f32x4 f1 = *(const f32x4*)(afp + k0 + 4);
      al0[0]=pk2(f0[0],f0[1]); al0[1]=pk2(f0[2],f0[3]); al0[2]=pk2(f1[0],f1[1]); al0[3]=pk2(f1[2],f1[3]);
      if constexpr (MT == 128){
        f32x4 f2 = *(const f32x4*)(afp + k0 + 8);
        f32x4 f3 = *(const f32x4*)(afp + k0 + 12);
        al1[0]=pk2(f2[0],f2[1]); al1[1]=pk2(f2[2],f2[3]); al1[2]=pk2(f3[0],f3[1]); al1[3]=pk2(f3[2],f3[3]);
      }
    }
    __syncthreads();
    if constexpr (AMODE == 2){
      #pragma unroll
      for (int j = 0; j < AI; j++) gl_lds16(pA2[j] + k0, lA2[j]);
    } else {
      *(u32x4*)&As[sa_r][sa_k] = al0;
      if constexpr (MT == 128) *(u32x4*)&As[sa_r][sa_k + 8] = al1;
    }
    gl_lds16(pB[0] + k0, lB[0]);
    gl_lds16(pB[1] + k0, lB[1]);
    __syncthreads();
    bf16x8 af[MI], bfr[4];
    #pragma unroll
    for (int mi=0;mi<MI;mi++){
      u32x4 t = *(const u32x4*)&As[wm*(MT/2) + mi*16 + (lane&15)][8*(lane>>4)];
      af[mi] = __builtin_bit_cast(bf16x8, t);
    }
    #pragma unroll
    for (int ni=0;ni<4;ni++){
      u32x4 t = *(const u32x4*)&Bs[wn*64 + ni*16 + (lane&15)][8*(lane>>4)];
      bfr[ni] = __builtin_bit_cast(bf16x8, t);
    }
    #pragma unroll
    for (int mi=0;mi<MI;mi++)
      #pragma unroll
      for (int ni=0;ni<4;ni++)
        acc[mi][ni] = __builtin_amdgcn_mfma_f32_16x16x32_bf16(af[mi], bfr[ni], acc[mi][ni], 0, 0, 0);
  }

  const int erow = 4*(lane >> 4);
  const int ecol = lane & 15;
  #pragma unroll
  for (int mi=0;mi<MI;mi++)
    #pragma unroll
    for (int ni=0;ni<4;ni++){
      const int c = col0 + wn*64 + ni*16 + ecol;
      const float bb = bp[c];
      #pragma unroll
      for (int r=0;r<4;r++){
        const int R = row0 + wm*(MT/2) + mi*16 + erow + r;
        if (GROUPED && R >= gend) continue;
        float v = acc[mi][ni][r] + bb;
        if (GELU_) v = 0.5f*v*(1.0f + erff(v*0.70710678118654752f));
        if constexpr (OMODE == 0){
          Cb[(size_t)R*N + c] = f2bf(v);
        } else if constexpr (OMODE == 1){
          Cf[(size_t)R*N + c] = v;
        } else {
          const int tok = tok_idx[R];
          const float gt = gate_s[R];
          float* p = Cf + (size_t)tok*N + c;
          *p += gt*v;
        }
      }
    }
}

// ---------------- token-level switch router (f32, one wave/token) ----------------
__global__ void token_router_k(const float* __restrict__ att, const int* __restrict__ sel,
    const float* __restrict__ sww, const float* __restrict__ swb,
    int* __restrict__ grp, float* __restrict__ gate, int* __restrict__ grp_cnt)
{
  const int t = blockIdx.x*4 + (threadIdx.x >> 6);
  const int lane = threadIdx.x & 63;
  const int e = sel[t >> 9];
  const float* x = att + (size_t)t * Dq;
  const float* w = sww + (size_t)e * Dq * 4;
  float a0=0.f, a1=0.f, a2=0.f, a3=0.f;
  #pragma unroll 4
  for (int i = 0; i < 12; i++){
    const int d = lane + i*64;
    const float xv = x[d];
    f32x4 wv = *(const f32x4*)&w[d*4];
    a0 += xv*wv[0]; a1 += xv*wv[1]; a2 += xv*wv[2]; a3 += xv*wv[3];
  }
  #pragma unroll
  for (int off = 32; off; off >>= 1){
    a0 += __shfl_xor(a0, off); a1 += __shfl_xor(a1, off);
    a2 += __shfl_xor(a2, off); a3 += __shfl_xor(a3, off);
  }
  if (lane == 0){
    const float l0 = a0 + swb[e*4+0], l1 = a1 + swb[e*4+1];
    const float l2 = a2 + swb[e*4+2], l3 = a3 + swb[e*4+3];
    const float mx = fmaxf(fmaxf(l0,l1), fmaxf(l2,l3));
    const float p0 = expf(l0-mx), p1 = expf(l1-mx), p2 = expf(l2-mx), p3 = expf(l3-mx);
    const float ssum = p0+p1+p2+p3;
    int am = 0; float bv = p0;
    if (p1 > bv){ bv=p1; am=1; }
    if (p2 > bv){ bv=p2; am=2; }
    if (p3 > bv){ bv=p3; am=3; }
    grp[t] = e*4 + am;
    gate[t] = bv/ssum;
    atomicAdd(&grp_cnt[e*4 + am], 1);
  }
}

__global__ void build_offsets_k(const int* __restrict__ grp_cnt, int* __restrict__ grp_off,
    int* __restrict__ tg128, int* __restrict__ tr128, int* __restrict__ nt128,
    int* __restrict__ tg64, int* __restrict__ tr64, int* __restrict__ nt64)
{
  int off = 0, n1 = 0, n2 = 0;
  for (int g = 0; g < 16; g++){
    grp_off[g] = off;
    const int c = grp_cnt[g];
    for (int r0 = 0; r0 < c; r0 += 128){ tg128[n1] = g; tr128[n1] = r0; n1++; }
    for (int r0 = 0; r0 < c; r0 += 64){  tg64[n2]  = g; tr64[n2]  = r0; n2++; }
    off += c;
  }
  grp_off[16] = off;
  *nt128 = n1; *nt64 = n2;
}

__global__ void scatter_k(const int* __restrict__ grp, const float* __restrict__ gate,
    const int* __restrict__ grp_off, int* __restrict__ fill,
    int* __restrict__ tok_idx, float* __restrict__ gate_s)
{
  const int t = blockIdx.x*256 + threadIdx.x;
  const int g = grp[t];
  const int pos = grp_off[g] + atomicAdd(&fill[g], 1);
  tok_idx[pos] = t;
  gate_s[pos] = gate[t];
}

// ---------------- final residual-add + LayerNorm ----------------
__global__ __launch_bounds__(256) void final_ln_k(const float* __restrict__ att,
    const float* __restrict__ acc, const float* __restrict__ lg,
    const float* __restrict__ lb, float* __restrict__ out)
{
  const int row = blockIdx.x, tid = threadIdx.x;
  const float* a = att + (size_t)row * Dq;
  const float* c = acc + (size_t)row * Dq;
  float x[3];
  #pragma unroll
  for (int i = 0; i < 3; i++) x[i] = a[tid + 256*i] + c[tid + 256*i];
  __shared__ float red[256];
  red[tid] = x[0] + x[1] + x[2];
  __syncthreads();
  for (int st = 128; st; st >>= 1){
    if (tid < st) red[tid] += red[tid + st];
    __syncthreads();
  }
  const float mu = red[0] * (1.0f/768.0f);
  __syncthreads();
  const float d0 = x[0]-mu, d1 = x[1]-mu, d2 = x[2]-mu;
  red[tid] = d0*d0 + d1*d1 + d2*d2;
  __syncthreads();
  for (int st = 128; st; st >>= 1){
    if (tid < st) red[tid] += red[tid + st];
    __syncthreads();
  }
  const float inv = 1.0f/sqrtf(red[0]*(1.0f/768.0f) + 1e-12f);
  #pragma unroll
  for (int i = 0; i < 3; i++){
    const int col = tid + 256*i;
    out[(size_t)row*Dq + col] = (x[i]-mu)*inv*lg[col] + lb[col];
  }
}

// ======================= launch =======================
extern "C" void kernel_launch(void* const* d_in, const int* in_sizes, int n_in,
                              void* d_out, int out_size, void* d_ws, size_t ws_size,
                              hipStream_t stream)
{
  (void)in_sizes; (void)n_in; (void)out_size; (void)ws_size;
  const float* hs    = (const float*)d_in[0];
  const float* amask = (const float*)d_in[1];
  const float* sw_enc_w = (const float*)d_in[3];
  const float* sw_enc_b = (const float*)d_in[4];
  const float* sw_w  = (const float*)d_in[5];
  const float* sw_b  = (const float*)d_in[6];
  const float* ca_wq = (const float*)d_in[7];
  const float* ca_bq = (const float*)d_in[8];
  const float* ca_wk = (const float*)d_in[9];
  const float* ca_bk = (const float*)d_in[10];
  const float* ca_wv = (const float*)d_in[11];
  const float* ca_bv = (const float*)d_in[12];
  const float* ca_wo = (const float*)d_in[13];
  const float* ca_bo = (const float*)d_in[14];
  const float* ua_wq = (const float*)d_in[15];
  const float* ua_bq = (const float*)d_in[16];
  const float* ua_wk = (const float*)d_in[17];
  const float* ua_bk = (const float*)d_in[18];
  const float* ua_wv = (const float*)d_in[19];
  const float* ua_bv = (const float*)d_in[20];
  const float* ua_wo = (const float*)d_in[21];
  const float* ua_bo = (const float*)d_in[22];
  const float* cf_w1 = (const float*)d_in[23];
  const float* cf_b1 = (const float*)d_in[24];
  const float* cf_w2 = (const float*)d_in[25];
  const float* cf_b2 = (const float*)d_in[26];
  const float* uf_sw_w = (const float*)d_in[27];
  const float* uf_sw_b = (const float*)d_in[28];
  const float* uf_w1 = (const float*)d_in[29];
  const float* uf_b1 = (const float*)d_in[30];
  const float* uf_w2 = (const float*)d_in[31];
  const float* uf_b2 = (const float*)d_in[32];
  const float* ln_g  = (const float*)d_in[33];
  const float* ln_b  = (const float*)d_in[34];
  float* out = (float*)d_out;

  char* W = (char*)d_ws;
  // control block
  int*   sel     = (int*)(W + 0);
  float* pm      = (float*)(W + 64);
  int*   grp_cnt = (int*)(W + 128);
  int*   fill    = (int*)(W + 192);
  int*   ntile   = (int*)(W + 256);
  int*   ntile64 = (int*)(W + 320);
  int*   grp_off = (int*)(W + 512);
  int*   tile_g  = (int*)(W + 1024);
  int*   tile_r  = (int*)(W + 2048);
  int*   tile_g64= (int*)(W + 3072);
  int*   tile_r64= (int*)(W + 4096);

  float* att  = (float*)(W + 8192);             // [8192][768] f32
  float* facc = (float*)(W + 25174016);         // [8192][768] f32
  const size_t X = 50339840;
  _Float16* hsH  = (_Float16*)(W + X);                 // 12,582,912
  _Float16* hsL  = (_Float16*)(W + X + 12582912);
  _Float16* qkvH = (_Float16*)(W + X + 25165824);      // 37,748,736
  _Float16* qkvL = (_Float16*)(W + X + 62914560);      // end X+100663296
  _Float16* ctxH = (_Float16*)(W + X + 100663296);     // 12,582,912
  _Float16* ctxL = (_Float16*)(W + X + 113246208);     // end X+125829120
  _Float16* wqkv_cH = (_Float16*)(W + X + 125829120);  // 3,538,944
  _Float16* wqkv_cL = (_Float16*)(W + X + 129368064);
  _Float16* wqkv_uH = (_Float16*)(W + X + 132907008);  // 14,155,776
  _Float16* wqkv_uL = (_Float16*)(W + X + 147062784);
  _Float16* wo_cH   = (_Float16*)(W + X + 161218560);  // 1,179,648
  _Float16* wo_cL   = (_Float16*)(W + X + 162398208);
  _Float16* wo_uH   = (_Float16*)(W + X + 163577856);  // 4,718,592
  _Float16* wo_uL   = (_Float16*)(W + X + 168296448);  // end X+173015040
  float* qkvb_c = (float*)(W + X + 173015040);         // 9,216
  float* qkvb_u = (float*)(W + X + 173024256);         // 36,864
  float* partb  = (float*)(W + X + 173061120);         // 196,608

  // phase B (after attention) reuses phase-A scratch:
  unsigned short* w1T = (unsigned short*)(W + X);              // 80,216,064
  unsigned short* w2T = (unsigned short*)(W + X + 80216064);   // end X+160432128
  unsigned short* h1  = (unsigned short*)(W + X + 160432128);  // 50,331,648
  int*   grp     = (int*)(W + 261103616);
  float* gate    = (float*)(W + 261136384);
  int*   tok_idx = (int*)(W + 261169152);
  float* gate_s  = (float*)(W + 261201920);

  hipMemsetAsync(W, 0, 512, stream);

  // ---- sequence router (exact f32) ----
  pooled_partial_k<<<dim3(Bq,3,4),256,0,stream>>>(hs, partb);
  router_seq_k<<<Bq,128,0,stream>>>(partb, sw_enc_w, sw_enc_b, sw_w, sw_b, sel, pm);

  // ---- prepare split-f16 operands ----
  split_f16_k<<<6144,256,0,stream>>>(hs, hsH, hsL, NTq*Dq/4);
  transpose_f16s_k<<<dim3(12,12,1),256,0,stream>>>(ca_wq, wqkv_cH, wqkv_cL, Dq, Dq, 0, 0, 0);
  transpose_f16s_k<<<dim3(12,12,1),256,0,stream>>>(ca_wk, wqkv_cH, wqkv_cL, Dq, Dq, 0, 0, 768);
  transpose_f16s_k<<<dim3(12,12,1),256,0,stream>>>(ca_wv, wqkv_cH, wqkv_cL, Dq, Dq, 0, 0, 1536);
  transpose_f16s_k<<<dim3(12,12,4),256,0,stream>>>(ua_wq, wqkv_uH, wqkv_uL, Dq, Dq, (long)Dq*Dq, (long)2304*768, 0);
  transpose_f16s_k<<<dim3(12,12,4),256,0,stream>>>(ua_wk, wqkv_uH, wqkv_uL, Dq, Dq, (long)Dq*Dq, (long)2304*768, 768);
  transpose_f16s_k<<<dim3(12,12,4),256,0,stream>>>(ua_wv, wqkv_uH, wqkv_uL, Dq, Dq, (long)Dq*Dq, (long)2304*768, 1536);
  transpose_f16s_k<<<dim3(12,12,1),256,0,stream>>>(ca_wo, wo_cH, wo_cL, Dq, Dq, 0, 0, 0);
  transpose_f16s_k<<<dim3(12,12,4),256,0,stream>>>(ua_wo, wo_uH, wo_uL, Dq, Dq, (long)Dq*Dq, (long)Dq*Dq, 0);
  concat_bias3_k<<<dim3(3,1),256,0,stream>>>(ca_bq, ca_bk, ca_bv, qkvb_c, 0);
  concat_bias3_k<<<dim3(3,4),256,0,stream>>>(ua_bq, ua_bk, ua_bv, qkvb_u, 768);

  // ---- common attention ----
  gemm_f16s_k<0,2><<<dim3(18,64),256,0,stream>>>(hsH, hsL, wqkv_cH, wqkv_cL, qkvb_c,
      nullptr, qkvH, qkvL, 2304, Dq, 0, 0, nullptr, nullptr);
  attn_mfma_k<<<dim3(4,Hq,Bq),256,0,stream>>>(qkvH, qkvL, amask, ctxH, ctxL);
  gemm_f16s_k<0,0><<<dim3(6,64),256,0,stream>>>(ctxH, ctxL, wo_cH, wo_cL, ca_bo,
      att, nullptr, nullptr, Dq, Dq, 0, 0, nullptr, nullptr);

  // ---- unique attention (selected expert), att += pm * result ----
  gemm_f16s_k<1,2><<<dim3(18,64),256,0,stream>>>(hsH, hsL, wqkv_uH, wqkv_uL, qkvb_u,
      nullptr, qkvH, qkvL, 2304, Dq, (long)2304*768, 2304, sel, nullptr);
  attn_mfma_k<<<dim3(4,Hq,Bq),256,0,stream>>>(qkvH, qkvL, amask, ctxH, ctxL);
  gemm_f16s_k<1,1><<<dim3(6,64),256,0,stream>>>(ctxH, ctxL, wo_uH, wo_uL, ua_bo,
      att, nullptr, nullptr, Dq, Dq, (long)Dq*Dq, Dq, sel, pm);

  // ---- FFN weights -> transposed bf16 (phase-A scratch now free) ----
  transpose_bf16_k<<<dim3(48,12,1), 256,0,stream>>>(cf_w1, w1T, Dq, Fq);
  transpose_bf16_k<<<dim3(48,12,16),256,0,stream>>>(uf_w1, w1T + 2359296, Dq, Fq);
  transpose_bf16_k<<<dim3(12,48,1), 256,0,stream>>>(cf_w2, w2T, Fq, Dq);
  transpose_bf16_k<<<dim3(12,48,16),256,0,stream>>>(uf_w2, w2T + 2359296, Fq, Dq);

  // ---- common FFN (bf16 MFMA) ----
  gemm_bf16_k<128,0,0,true,false><<<dim3(24,64),256,0,stream>>>((const void*)att, w1T, cf_b1, nullptr, h1,
      Fq, Dq, nullptr,nullptr,nullptr,nullptr,nullptr,nullptr, (size_t)0, 0);
  gemm_bf16_k<64,2,1,false,false><<<dim3(6,128),256,0,stream>>>((const void*)h1, w2T, cf_b2, facc, nullptr,
      Dq, Fq, nullptr,nullptr,nullptr,nullptr,nullptr,nullptr, (size_t)0, 0);

  // ---- token routing (f32, on accurate att) ----
  token_router_k<<<2048,256,0,stream>>>(att, sel, uf_sw_w, uf_sw_b, grp, gate, grp_cnt);
  build_offsets_k<<<1,1,0,stream>>>(grp_cnt, grp_off, tile_g, tile_r, ntile, tile_g64, tile_r64, ntile64);
  scatter_k<<<32,256,0,stream>>>(grp, gate, grp_off, fill, tok_idx, gate_s);

  // ---- unique FFN (grouped, top-1 inner expert, gated scatter-add) ----
  gemm_bf16_k<128,1,0,true,true><<<dim3(24,80),256,0,stream>>>((const void*)att, w1T + 2359296, uf_b1, nullptr, h1,
      Fq, Dq, tile_g, tile_r, grp_off, ntile, tok_idx, gate_s, (size_t)2359296, Fq);
  gemm_bf16_k<64,2,2,false,true><<<dim3(6,144),256,0,stream>>>((const void*)h1, w2T + 2359296, uf_b2, facc, nullptr,
      Dq, Fq, tile_g64, tile_r64, grp_off, ntile64, tok_idx, gate_s, (size_t)2359296, Dq);

  // ---- residual + LayerNorm ----
  final_ln_k<<<NTq,256,0,stream>>>(att, facc, ln_g, ln_b, out);
}